// Round 2
// baseline (873.541 us; speedup 1.0000x reference)
//
#include <hip/hip_runtime.h>
#include <cstdint>

using short8 = __attribute__((ext_vector_type(8))) short;
using f32x4  = __attribute__((ext_vector_type(4))) float;

#define H_    8
#define SLEN  1024
#define BSZ   32
#define INDIM 512
#define NQKV  1544   // H*(3*D+1)
#define NPAD  1664   // 13*128
#define MROWS 32768  // SLEN*BSZ

static __device__ __forceinline__ float bf2f(unsigned short s) {
    return __uint_as_float(((unsigned int)s) << 16);
}
static __device__ __forceinline__ unsigned short f2bf(float f) {
    unsigned int u = __float_as_uint(f);
    u += 0x7FFFu + ((u >> 16) & 1u);
    return (unsigned short)(u >> 16);
}

// ---------------- LayerNorm: x[32768][512] f32 -> h bf16 ----------------
__global__ __launch_bounds__(256) void ln_kernel(const float* __restrict__ x,
                                                 const float* __restrict__ gamma,
                                                 const float* __restrict__ betap,
                                                 unsigned short* __restrict__ h) {
    int row = blockIdx.x * 4 + (threadIdx.x >> 6);
    int l   = threadIdx.x & 63;
    const f32x4* xr = (const f32x4*)(x + (size_t)row * INDIM);
    f32x4 a = xr[l * 2], b = xr[l * 2 + 1];
    float s = 0.f, sq = 0.f;
    #pragma unroll
    for (int j = 0; j < 4; ++j) { s += a[j]; sq += a[j] * a[j]; }
    #pragma unroll
    for (int j = 0; j < 4; ++j) { s += b[j]; sq += b[j] * b[j]; }
    #pragma unroll
    for (int off = 32; off; off >>= 1) { s += __shfl_xor(s, off); sq += __shfl_xor(sq, off); }
    float mean = s * (1.f / 512.f);
    float var  = sq * (1.f / 512.f) - mean * mean;
    float rstd = rsqrtf(var + 1e-5f);
    const f32x4* g4 = (const f32x4*)gamma;
    const f32x4* b4 = (const f32x4*)betap;
    f32x4 g0 = g4[l * 2], g1 = g4[l * 2 + 1], e0 = b4[l * 2], e1 = b4[l * 2 + 1];
    short8 o;
    #pragma unroll
    for (int j = 0; j < 4; ++j) o[j]     = (short)f2bf((a[j] - mean) * rstd * g0[j] + e0[j]);
    #pragma unroll
    for (int j = 0; j < 4; ++j) o[4 + j] = (short)f2bf((b[j] - mean) * rstd * g1[j] + e1[j]);
    ((short8*)(h + (size_t)row * INDIM))[l] = o;
}

// ---------------- weight transpose+permute: wT[n][k], n grouped q|k|v|beta ----------------
__global__ __launch_bounds__(256) void cvt_wslow(const float* __restrict__ w,
                                                 unsigned short* __restrict__ wT) {
    int idx = blockIdx.x * 256 + threadIdx.x;   // NPAD*512
    int n = idx >> 9, k = idx & 511;
    int c;
    if (n < 512)       c = (n >> 6) * 193 + (n & 63);                 // q, head-major
    else if (n < 1024) c = ((n - 512) >> 6) * 193 + 64 + (n & 63);    // k
    else if (n < 1536) c = ((n - 1024) >> 6) * 193 + 128 + (n & 63);  // v
    else if (n < 1544) c = (n - 1536) * 193 + 192;                    // beta
    else               c = -1;                                         // pad
    wT[idx] = (c >= 0) ? f2bf(w[(size_t)k * NQKV + c]) : (unsigned short)0;
}
__global__ __launch_bounds__(256) void cvt_wout(const float* __restrict__ w,
                                                unsigned short* __restrict__ wT) {
    int idx = blockIdx.x * 256 + threadIdx.x;   // 512*512
    int n = idx >> 9, k = idx & 511;
    wT[idx] = f2bf(w[(size_t)k * 512 + n]);
}

// ---------------- GEMM1 fused: h @ wT^T -> elu+1/sumnorm q,k ; v ; sigmoid beta ----------------
__global__ __launch_bounds__(256) void gemm_qkv(const unsigned short* __restrict__ A,
                                                const unsigned short* __restrict__ BT,
                                                unsigned short* __restrict__ qn,
                                                unsigned short* __restrict__ kn,
                                                unsigned short* __restrict__ vn,
                                                float* __restrict__ bet) {
    __shared__ unsigned short As[128][72];
    __shared__ unsigned short Bs[128][72];
    const int t  = threadIdx.x;
    const int bx = blockIdx.x;
    const int n0 = bx * 128;
    const int m0 = blockIdx.y * 128;
    const int w = t >> 6, l = t & 63;
    const int wr = (w >> 1) * 64, wc = (w & 1) * 64;
    f32x4 acc[4][4] = {};
    for (int kt = 0; kt < INDIM; kt += 64) {
        __syncthreads();
        #pragma unroll
        for (int c = 0; c < 4; ++c) {
            int idx = c * 256 + t;
            int row = idx >> 3, kc = (idx & 7) * 8;
            *(short8*)&As[row][kc] = *(const short8*)(A  + (size_t)(m0 + row) * INDIM + kt + kc);
            *(short8*)&Bs[row][kc] = *(const short8*)(BT + (size_t)(n0 + row) * INDIM + kt + kc);
        }
        __syncthreads();
        #pragma unroll
        for (int kk = 0; kk < 2; ++kk) {
            const int kr = kk * 32 + (l >> 4) * 8;
            short8 af[4], bf[4];
            #pragma unroll
            for (int m = 0; m < 4; ++m) af[m] = *(const short8*)&As[wr + m * 16 + (l & 15)][kr];
            #pragma unroll
            for (int n = 0; n < 4; ++n) bf[n] = *(const short8*)&Bs[wc + n * 16 + (l & 15)][kr];
            #pragma unroll
            for (int m = 0; m < 4; ++m)
                #pragma unroll
                for (int n = 0; n < 4; ++n)
                    acc[m][n] = __builtin_amdgcn_mfma_f32_16x16x32_bf16(af[m], bf[n], acc[m][n], 0, 0, 0);
        }
    }
    const int g = l >> 4, cc = l & 15;
    const int colbase = n0 + wc;
    if (bx < 12) {
        const int reg  = colbase >> 9;            // 0=q, 1=k, 2=v (block-uniform)
        const int head = (colbase >> 6) & 7;      // wave-uniform
        unsigned short* dst = (reg == 0) ? qn : (reg == 1) ? kn : vn;
        #pragma unroll
        for (int m = 0; m < 4; ++m) {
            #pragma unroll
            for (int j = 0; j < 4; ++j) {
                int row = m0 + wr + m * 16 + g * 4 + j;
                int s = row >> 5, b = row & 31;
                size_t base = ((size_t)(b * H_ + head) * SLEN + s) * 64;
                float e0 = acc[m][0][j], e1 = acc[m][1][j], e2 = acc[m][2][j], e3 = acc[m][3][j];
                if (reg < 2) {
                    e0 = e0 > 0.f ? e0 + 1.f : __expf(e0);
                    e1 = e1 > 0.f ? e1 + 1.f : __expf(e1);
                    e2 = e2 > 0.f ? e2 + 1.f : __expf(e2);
                    e3 = e3 > 0.f ? e3 + 1.f : __expf(e3);
                    float ssum = (e0 + e1) + (e2 + e3);
                    ssum += __shfl_xor(ssum, 1);
                    ssum += __shfl_xor(ssum, 2);
                    ssum += __shfl_xor(ssum, 4);
                    ssum += __shfl_xor(ssum, 8);
                    float inv = 1.f / ssum;
                    e0 *= inv; e1 *= inv; e2 *= inv; e3 *= inv;
                }
                dst[base +  0 + cc] = f2bf(e0);
                dst[base + 16 + cc] = f2bf(e1);
                dst[base + 32 + cc] = f2bf(e2);
                dst[base + 48 + cc] = f2bf(e3);
            }
        }
    } else {
        // beta block: cols 1536..1543 live in wave strip wc==0, n==0, cc<8
        if (wc == 0 && cc < 8) {
            #pragma unroll
            for (int m = 0; m < 4; ++m)
                #pragma unroll
                for (int j = 0; j < 4; ++j) {
                    int row = m0 + wr + m * 16 + g * 4 + j;
                    int s = row >> 5, b = row & 31;
                    float v = acc[m][0][j];
                    bet[(size_t)(b * H_ + cc) * SLEN + s] = 1.f / (1.f + __expf(-v));
                }
        }
    }
}

// ---------------- GEMM2: out = x + outs @ woT^T ----------------
__global__ __launch_bounds__(256) void gemm_out(const unsigned short* __restrict__ A,
                                                const unsigned short* __restrict__ BT,
                                                const float* __restrict__ X,
                                                float* __restrict__ outf) {
    __shared__ unsigned short As[128][72];
    __shared__ unsigned short Bs[128][72];
    const int t  = threadIdx.x;
    const int n0 = blockIdx.x * 128;
    const int m0 = blockIdx.y * 128;
    const int w = t >> 6, l = t & 63;
    const int wr = (w >> 1) * 64, wc = (w & 1) * 64;
    f32x4 acc[4][4] = {};
    for (int kt = 0; kt < INDIM; kt += 64) {
        __syncthreads();
        #pragma unroll
        for (int c = 0; c < 4; ++c) {
            int idx = c * 256 + t;
            int row = idx >> 3, kc = (idx & 7) * 8;
            *(short8*)&As[row][kc] = *(const short8*)(A  + (size_t)(m0 + row) * INDIM + kt + kc);
            *(short8*)&Bs[row][kc] = *(const short8*)(BT + (size_t)(n0 + row) * INDIM + kt + kc);
        }
        __syncthreads();
        #pragma unroll
        for (int kk = 0; kk < 2; ++kk) {
            const int kr = kk * 32 + (l >> 4) * 8;
            short8 af[4], bf[4];
            #pragma unroll
            for (int m = 0; m < 4; ++m) af[m] = *(const short8*)&As[wr + m * 16 + (l & 15)][kr];
            #pragma unroll
            for (int n = 0; n < 4; ++n) bf[n] = *(const short8*)&Bs[wc + n * 16 + (l & 15)][kr];
            #pragma unroll
            for (int m = 0; m < 4; ++m)
                #pragma unroll
                for (int n = 0; n < 4; ++n)
                    acc[m][n] = __builtin_amdgcn_mfma_f32_16x16x32_bf16(af[m], bf[n], acc[m][n], 0, 0, 0);
        }
    }
    const int rb = (l >> 4) * 4, cc = l & 15;
    #pragma unroll
    for (int m = 0; m < 4; ++m)
        #pragma unroll
        for (int n = 0; n < 4; ++n)
            #pragma unroll
            for (int j = 0; j < 4; ++j) {
                int row = m0 + wr + m * 16 + rb + j;
                int col = n0 + wc + n * 16 + cc;
                size_t o = (size_t)row * 512 + col;
                outf[o] = X[o] + acc[m][n][j];
            }
}

// ---------------- delta-rule recurrence: one block per (b,h) ----------------
__global__ __launch_bounds__(256) void recur(const unsigned short* __restrict__ qn,
                                             const unsigned short* __restrict__ kn,
                                             const unsigned short* __restrict__ vn,
                                             const float* __restrict__ beta,
                                             unsigned short* __restrict__ outs) {
    const int bh = blockIdx.x;
    const int b = bh >> 3, h = bh & 7;
    const int t = threadIdx.x, w = t >> 6, l = t & 63;
    const int r = (w << 4) + (l >> 2), cb = l & 3;
    __shared__ float sk[2][64], sq[2][64], sv[2][64], sb[2];
    const unsigned short* kb = kn + (size_t)bh * SLEN * 64;
    const unsigned short* qb = qn + (size_t)bh * SLEN * 64;
    const unsigned short* vb = vn + (size_t)bh * SLEN * 64;
    const float* bb = beta + (size_t)bh * SLEN;
    float W[16];
    #pragma unroll
    for (int j = 0; j < 16; ++j) W[j] = 0.f;
    if (t < 64)       sk[0][t]       = bf2f(kb[t]);
    else if (t < 128) sq[0][t - 64]  = bf2f(qb[t - 64]);
    else if (t < 192) sv[0][t - 128] = bf2f(vb[t - 128]);
    else if (t == 192) sb[0] = bb[0];
    for (int st = 0; st < SLEN; ++st) {
        const int cur = st & 1;
        __syncthreads();
        if (st + 1 < SLEN) {
            const int nx = cur ^ 1;
            const size_t off = (size_t)(st + 1) * 64;
            if (t < 64)       sk[nx][t]       = bf2f(kb[off + t]);
            else if (t < 128) sq[nx][t - 64]  = bf2f(qb[off + t - 64]);
            else if (t < 192) sv[nx][t - 128] = bf2f(vb[off + t - 128]);
            else if (t == 192) sb[nx] = bb[st + 1];
        }
        const f32x4* k4 = (const f32x4*)sk[cur];
        const f32x4* q4 = (const f32x4*)sq[cur];
        f32x4 kk[4], qq[4];
        #pragma unroll
        for (int i = 0; i < 4; ++i) { kk[i] = k4[cb * 4 + i]; qq[i] = q4[cb * 4 + i]; }
        float pa0 = 0.f, pa1 = 0.f, pa2 = 0.f, pa3 = 0.f;
        #pragma unroll
        for (int i = 0; i < 4; ++i) {
            pa0 = fmaf(W[i * 4 + 0], kk[i][0], pa0);
            pa1 = fmaf(W[i * 4 + 1], kk[i][1], pa1);
            pa2 = fmaf(W[i * 4 + 2], kk[i][2], pa2);
            pa3 = fmaf(W[i * 4 + 3], kk[i][3], pa3);
        }
        float p = (pa0 + pa1) + (pa2 + pa3);
        p += __shfl_xor(p, 1);
        p += __shfl_xor(p, 2);
        const float upd = sb[cur] * (sv[cur][r] - p);
        float oa0 = 0.f, oa1 = 0.f, oa2 = 0.f, oa3 = 0.f;
        #pragma unroll
        for (int i = 0; i < 4; ++i) {
            W[i * 4 + 0] = fmaf(upd, kk[i][0], W[i * 4 + 0]);
            W[i * 4 + 1] = fmaf(upd, kk[i][1], W[i * 4 + 1]);
            W[i * 4 + 2] = fmaf(upd, kk[i][2], W[i * 4 + 2]);
            W[i * 4 + 3] = fmaf(upd, kk[i][3], W[i * 4 + 3]);
            oa0 = fmaf(W[i * 4 + 0], qq[i][0], oa0);
            oa1 = fmaf(W[i * 4 + 1], qq[i][1], oa1);
            oa2 = fmaf(W[i * 4 + 2], qq[i][2], oa2);
            oa3 = fmaf(W[i * 4 + 3], qq[i][3], oa3);
        }
        float o = (oa0 + oa1) + (oa2 + oa3);
        o += __shfl_xor(o, 1);
        o += __shfl_xor(o, 2);
        if (cb == 0) outs[((size_t)st * BSZ + b) * 512 + h * 64 + r] = f2bf(o);
    }
}

// ---------------- launch ----------------
extern "C" void kernel_launch(void* const* d_in, const int* in_sizes, int n_in,
                              void* d_out, int out_size, void* d_ws, size_t ws_size,
                              hipStream_t stream) {
    const float* x      = (const float*)d_in[0];
    const float* g      = (const float*)d_in[1];
    const float* be     = (const float*)d_in[2];
    const float* w_slow = (const float*)d_in[3];
    const float* w_out  = (const float*)d_in[4];
    float* out = (float*)d_out;
    char* ws = (char*)d_ws;

    // workspace layout (total 137,494,528 bytes)
    unsigned short* h    = (unsigned short*)(ws);                 // 33,554,432 (reused as outs)
    unsigned short* outs = (unsigned short*)(ws);                 // alias: h dead after gemm1
    unsigned short* qn   = (unsigned short*)(ws + 33554432);      // 33,554,432
    unsigned short* kn   = (unsigned short*)(ws + 67108864);      // 33,554,432
    unsigned short* vn   = (unsigned short*)(ws + 100663296);     // 33,554,432
    float*          bet  = (float*)         (ws + 134217728);     //  1,048,576
    unsigned short* wsT  = (unsigned short*)(ws + 135266304);     //  1,703,936
    unsigned short* woT  = (unsigned short*)(ws + 136970240);     //    524,288

    if (ws_size < 137494528) return;   // fail readable (absmax) instead of faulting

    ln_kernel<<<8192, 256, 0, stream>>>(x, g, be, h);
    cvt_wslow<<<(NPAD * 512) / 256, 256, 0, stream>>>(w_slow, wsT);
    cvt_wout<<<(512 * 512) / 256, 256, 0, stream>>>(w_out, woT);
    gemm_qkv<<<dim3(13, MROWS / 128), 256, 0, stream>>>(h, wsT, qn, kn, vn, bet);
    recur<<<BSZ * H_, 256, 0, stream>>>(qn, kn, vn, bet, outs);
    gemm_out<<<dim3(4, MROWS / 128), 256, 0, stream>>>(outs, woT, x, out);
}

// Round 3
// 800.260 us; speedup vs baseline: 1.0916x; 1.0916x over previous
//
#include <hip/hip_runtime.h>
#include <cstdint>

using short8  = __attribute__((ext_vector_type(8))) short;
using ushort8 = __attribute__((ext_vector_type(8))) unsigned short;
using f32x4   = __attribute__((ext_vector_type(4))) float;

#define H_    8
#define SLEN  1024
#define BSZ   32
#define INDIM 512
#define NQKV  1544   // H*(3*D+1)
#define NPAD  1664   // 13*128
#define MROWS 32768  // SLEN*BSZ

static __device__ __forceinline__ float bf2f(unsigned short s) {
    return __uint_as_float(((unsigned int)s) << 16);
}
static __device__ __forceinline__ unsigned short f2bf(float f) {
    unsigned int u = __float_as_uint(f);
    u += 0x7FFFu + ((u >> 16) & 1u);
    return (unsigned short)(u >> 16);
}

// ---------------- LayerNorm: x[32768][512] f32 -> h bf16 ----------------
__global__ __launch_bounds__(256) void ln_kernel(const float* __restrict__ x,
                                                 const float* __restrict__ gamma,
                                                 const float* __restrict__ betap,
                                                 unsigned short* __restrict__ h) {
    int row = blockIdx.x * 4 + (threadIdx.x >> 6);
    int l   = threadIdx.x & 63;
    const f32x4* xr = (const f32x4*)(x + (size_t)row * INDIM);
    f32x4 a = xr[l * 2], b = xr[l * 2 + 1];
    float s = 0.f, sq = 0.f;
    #pragma unroll
    for (int j = 0; j < 4; ++j) { s += a[j]; sq += a[j] * a[j]; }
    #pragma unroll
    for (int j = 0; j < 4; ++j) { s += b[j]; sq += b[j] * b[j]; }
    #pragma unroll
    for (int off = 32; off; off >>= 1) { s += __shfl_xor(s, off); sq += __shfl_xor(sq, off); }
    float mean = s * (1.f / 512.f);
    float var  = sq * (1.f / 512.f) - mean * mean;
    float rstd = rsqrtf(var + 1e-5f);
    const f32x4* g4 = (const f32x4*)gamma;
    const f32x4* b4 = (const f32x4*)betap;
    f32x4 g0 = g4[l * 2], g1 = g4[l * 2 + 1], e0 = b4[l * 2], e1 = b4[l * 2 + 1];
    short8 o;
    #pragma unroll
    for (int j = 0; j < 4; ++j) o[j]     = (short)f2bf((a[j] - mean) * rstd * g0[j] + e0[j]);
    #pragma unroll
    for (int j = 0; j < 4; ++j) o[4 + j] = (short)f2bf((b[j] - mean) * rstd * g1[j] + e1[j]);
    ((short8*)(h + (size_t)row * INDIM))[l] = o;
}

// ---------------- weight transpose+permute: wT[n][k], n grouped q|k|v|beta ----------------
__global__ __launch_bounds__(256) void cvt_wslow(const float* __restrict__ w,
                                                 unsigned short* __restrict__ wT) {
    int idx = blockIdx.x * 256 + threadIdx.x;   // NPAD*512
    int n = idx >> 9, k = idx & 511;
    int c;
    if (n < 512)       c = (n >> 6) * 193 + (n & 63);                 // q, head-major
    else if (n < 1024) c = ((n - 512) >> 6) * 193 + 64 + (n & 63);    // k
    else if (n < 1536) c = ((n - 1024) >> 6) * 193 + 128 + (n & 63);  // v
    else if (n < 1544) c = (n - 1536) * 193 + 192;                    // beta
    else               c = -1;                                         // pad
    wT[idx] = (c >= 0) ? f2bf(w[(size_t)k * NQKV + c]) : (unsigned short)0;
}
__global__ __launch_bounds__(256) void cvt_wout(const float* __restrict__ w,
                                                unsigned short* __restrict__ wT) {
    int idx = blockIdx.x * 256 + threadIdx.x;   // 512*512
    int n = idx >> 9, k = idx & 511;
    wT[idx] = f2bf(w[(size_t)k * 512 + n]);
}

// ---------------- GEMM1 fused: h @ wT^T -> elu+1/sumnorm q,k ; v ; sigmoid beta ----------------
__global__ __launch_bounds__(256) void gemm_qkv(const unsigned short* __restrict__ A,
                                                const unsigned short* __restrict__ BT,
                                                unsigned short* __restrict__ qn,
                                                unsigned short* __restrict__ kn,
                                                unsigned short* __restrict__ vn,
                                                float* __restrict__ bet) {
    __shared__ unsigned short As[128][72];
    __shared__ unsigned short Bs[128][72];
    const int t  = threadIdx.x;
    const int bx = blockIdx.x;
    const int n0 = bx * 128;
    const int m0 = blockIdx.y * 128;
    const int w = t >> 6, l = t & 63;
    const int wr = (w >> 1) * 64, wc = (w & 1) * 64;
    f32x4 acc[4][4] = {};
    for (int kt = 0; kt < INDIM; kt += 64) {
        __syncthreads();
        #pragma unroll
        for (int c = 0; c < 4; ++c) {
            int idx = c * 256 + t;
            int row = idx >> 3, kc = (idx & 7) * 8;
            *(short8*)&As[row][kc] = *(const short8*)(A  + (size_t)(m0 + row) * INDIM + kt + kc);
            *(short8*)&Bs[row][kc] = *(const short8*)(BT + (size_t)(n0 + row) * INDIM + kt + kc);
        }
        __syncthreads();
        #pragma unroll
        for (int kk = 0; kk < 2; ++kk) {
            const int kr = kk * 32 + (l >> 4) * 8;
            short8 af[4], bf[4];
            #pragma unroll
            for (int m = 0; m < 4; ++m) af[m] = *(const short8*)&As[wr + m * 16 + (l & 15)][kr];
            #pragma unroll
            for (int n = 0; n < 4; ++n) bf[n] = *(const short8*)&Bs[wc + n * 16 + (l & 15)][kr];
            #pragma unroll
            for (int m = 0; m < 4; ++m)
                #pragma unroll
                for (int n = 0; n < 4; ++n)
                    acc[m][n] = __builtin_amdgcn_mfma_f32_16x16x32_bf16(af[m], bf[n], acc[m][n], 0, 0, 0);
        }
    }
    const int g = l >> 4, cc = l & 15;
    const int colbase = n0 + wc;
    if (bx < 12) {
        const int reg  = colbase >> 9;            // 0=q, 1=k, 2=v (block-uniform)
        const int head = (colbase >> 6) & 7;      // wave-uniform
        unsigned short* dst = (reg == 0) ? qn : (reg == 1) ? kn : vn;
        #pragma unroll
        for (int m = 0; m < 4; ++m) {
            #pragma unroll
            for (int j = 0; j < 4; ++j) {
                int row = m0 + wr + m * 16 + g * 4 + j;
                int s = row >> 5, b = row & 31;
                size_t base = ((size_t)(b * H_ + head) * SLEN + s) * 64;
                float e0 = acc[m][0][j], e1 = acc[m][1][j], e2 = acc[m][2][j], e3 = acc[m][3][j];
                if (reg < 2) {
                    e0 = e0 > 0.f ? e0 + 1.f : __expf(e0);
                    e1 = e1 > 0.f ? e1 + 1.f : __expf(e1);
                    e2 = e2 > 0.f ? e2 + 1.f : __expf(e2);
                    e3 = e3 > 0.f ? e3 + 1.f : __expf(e3);
                    float ssum = (e0 + e1) + (e2 + e3);
                    ssum += __shfl_xor(ssum, 1);
                    ssum += __shfl_xor(ssum, 2);
                    ssum += __shfl_xor(ssum, 4);
                    ssum += __shfl_xor(ssum, 8);
                    float inv = 1.f / ssum;
                    e0 *= inv; e1 *= inv; e2 *= inv; e3 *= inv;
                }
                dst[base +  0 + cc] = f2bf(e0);
                dst[base + 16 + cc] = f2bf(e1);
                dst[base + 32 + cc] = f2bf(e2);
                dst[base + 48 + cc] = f2bf(e3);
            }
        }
    } else {
        // beta block: cols 1536..1543 live in wave strip wc==0, n==0, cc<8
        if (wc == 0 && cc < 8) {
            #pragma unroll
            for (int m = 0; m < 4; ++m)
                #pragma unroll
                for (int j = 0; j < 4; ++j) {
                    int row = m0 + wr + m * 16 + g * 4 + j;
                    int s = row >> 5, b = row & 31;
                    float v = acc[m][0][j];
                    bet[(size_t)(b * H_ + cc) * SLEN + s] = 1.f / (1.f + __expf(-v));
                }
        }
    }
}

// ---------------- GEMM2: out = x + outs @ woT^T ----------------
__global__ __launch_bounds__(256) void gemm_out(const unsigned short* __restrict__ A,
                                                const unsigned short* __restrict__ BT,
                                                const float* __restrict__ X,
                                                float* __restrict__ outf) {
    __shared__ unsigned short As[128][72];
    __shared__ unsigned short Bs[128][72];
    const int t  = threadIdx.x;
    const int n0 = blockIdx.x * 128;
    const int m0 = blockIdx.y * 128;
    const int w = t >> 6, l = t & 63;
    const int wr = (w >> 1) * 64, wc = (w & 1) * 64;
    f32x4 acc[4][4] = {};
    for (int kt = 0; kt < INDIM; kt += 64) {
        __syncthreads();
        #pragma unroll
        for (int c = 0; c < 4; ++c) {
            int idx = c * 256 + t;
            int row = idx >> 3, kc = (idx & 7) * 8;
            *(short8*)&As[row][kc] = *(const short8*)(A  + (size_t)(m0 + row) * INDIM + kt + kc);
            *(short8*)&Bs[row][kc] = *(const short8*)(BT + (size_t)(n0 + row) * INDIM + kt + kc);
        }
        __syncthreads();
        #pragma unroll
        for (int kk = 0; kk < 2; ++kk) {
            const int kr = kk * 32 + (l >> 4) * 8;
            short8 af[4], bf[4];
            #pragma unroll
            for (int m = 0; m < 4; ++m) af[m] = *(const short8*)&As[wr + m * 16 + (l & 15)][kr];
            #pragma unroll
            for (int n = 0; n < 4; ++n) bf[n] = *(const short8*)&Bs[wc + n * 16 + (l & 15)][kr];
            #pragma unroll
            for (int m = 0; m < 4; ++m)
                #pragma unroll
                for (int n = 0; n < 4; ++n)
                    acc[m][n] = __builtin_amdgcn_mfma_f32_16x16x32_bf16(af[m], bf[n], acc[m][n], 0, 0, 0);
        }
    }
    const int rb = (l >> 4) * 4, cc = l & 15;
    #pragma unroll
    for (int m = 0; m < 4; ++m)
        #pragma unroll
        for (int n = 0; n < 4; ++n)
            #pragma unroll
            for (int j = 0; j < 4; ++j) {
                int row = m0 + wr + m * 16 + rb + j;
                int col = n0 + wc + n * 16 + cc;
                size_t o = (size_t)row * 512 + col;
                outf[o] = X[o] + acc[m][n][j];
            }
}

// ---------------- delta-rule recurrence v3: barrier-free, rows-in-registers ----------------
// grid: 2048 blocks x 64 threads. block = (bh, wv): bh = blockIdx.x>>3, wave-slice wv = blockIdx.x&7.
// Wave wv owns rows [wv*8, wv*8+8). lane l: row = wv*8 + (l>>3), cols (l&7)*8 .. +8 in 8 VGPRs.
// Cross-lane traffic: two 3-step __shfl_xor reduces per step (within 8-lane row group). No LDS, no barriers.
// Depth-4 register ring prefetch of k/q/v/beta hides global-load latency.
__global__ __launch_bounds__(64) void recur3(const unsigned short* __restrict__ qn,
                                             const unsigned short* __restrict__ kn,
                                             const unsigned short* __restrict__ vn,
                                             const float* __restrict__ beta,
                                             unsigned short* __restrict__ outs) {
    const int gb = blockIdx.x;
    const int bh = gb >> 3, wv = gb & 7;
    const int b = bh >> 3, h = bh & 7;
    const int l = threadIdx.x;
    const int rg = l >> 3;             // row within slice
    const int cs = l & 7;              // col segment
    const int row = wv * 8 + rg;
    const int c0 = cs * 8;
    const unsigned short* kb = kn + (size_t)bh * SLEN * 64;
    const unsigned short* qb = qn + (size_t)bh * SLEN * 64;
    const unsigned short* vb = vn + (size_t)bh * SLEN * 64;
    const float* bb = beta + (size_t)bh * SLEN;
    unsigned short* ob = outs + (size_t)b * 512 + h * 64 + row;   // + t*16384 per step

    float W[8];
    #pragma unroll
    for (int j = 0; j < 8; ++j) W[j] = 0.f;

    ushort8 krg[4], qrg[4];
    unsigned short vrg[4];
    float brg[4];
    #pragma unroll
    for (int s = 0; s < 4; ++s) {
        krg[s] = *(const ushort8*)(kb + (size_t)s * 64 + c0);
        qrg[s] = *(const ushort8*)(qb + (size_t)s * 64 + c0);
        vrg[s] = vb[(size_t)s * 64 + row];
        brg[s] = bb[s];
    }

    for (int t0 = 0; t0 < SLEN; t0 += 4) {
        #pragma unroll
        for (int s = 0; s < 4; ++s) {
            const int t = t0 + s;
            float kf[8], qf[8];
            #pragma unroll
            for (int j = 0; j < 8; ++j) {
                kf[j] = bf2f((unsigned short)krg[s][j]);
                qf[j] = bf2f((unsigned short)qrg[s][j]);
            }
            const float vcur = bf2f(vrg[s]);
            const float bcur = brg[s];
            // prefetch step t+4 into slot s (uniform guard, no divergence)
            if (t + 4 < SLEN) {
                krg[s] = *(const ushort8*)(kb + (size_t)(t + 4) * 64 + c0);
                qrg[s] = *(const ushort8*)(qb + (size_t)(t + 4) * 64 + c0);
                vrg[s] = vb[(size_t)(t + 4) * 64 + row];
                brg[s] = bb[t + 4];
            }
            // v_old[row] = W[row,:] . k  (partial over 8 cols, reduce over 8 lanes)
            float p0 = 0.f, p1 = 0.f;
            #pragma unroll
            for (int j = 0; j < 4; ++j) {
                p0 = fmaf(W[j],     kf[j],     p0);
                p1 = fmaf(W[4 + j], kf[4 + j], p1);
            }
            float p = p0 + p1;
            p += __shfl_xor(p, 1);
            p += __shfl_xor(p, 2);
            p += __shfl_xor(p, 4);
            const float upd = bcur * (vcur - p);
            // W[row,:] += upd*k ; o = W_new[row,:] . q
            float o0 = 0.f, o1 = 0.f;
            #pragma unroll
            for (int j = 0; j < 4; ++j) {
                W[j]     = fmaf(upd, kf[j],     W[j]);
                o0       = fmaf(W[j],     qf[j],     o0);
                W[4 + j] = fmaf(upd, kf[4 + j], W[4 + j]);
                o1       = fmaf(W[4 + j], qf[4 + j], o1);
            }
            float o = o0 + o1;
            o += __shfl_xor(o, 1);
            o += __shfl_xor(o, 2);
            o += __shfl_xor(o, 4);
            if (cs == 0) ob[(size_t)t * (BSZ * 512)] = f2bf(o);
        }
    }
}

// ---------------- launch ----------------
extern "C" void kernel_launch(void* const* d_in, const int* in_sizes, int n_in,
                              void* d_out, int out_size, void* d_ws, size_t ws_size,
                              hipStream_t stream) {
    const float* x      = (const float*)d_in[0];
    const float* g      = (const float*)d_in[1];
    const float* be     = (const float*)d_in[2];
    const float* w_slow = (const float*)d_in[3];
    const float* w_out  = (const float*)d_in[4];
    float* out = (float*)d_out;
    char* ws = (char*)d_ws;

    // workspace layout (total 137,494,528 bytes)
    unsigned short* h    = (unsigned short*)(ws);                 // 33,554,432 (reused as outs)
    unsigned short* outs = (unsigned short*)(ws);                 // alias: h dead after gemm1
    unsigned short* qn   = (unsigned short*)(ws + 33554432);      // 33,554,432
    unsigned short* kn   = (unsigned short*)(ws + 67108864);      // 33,554,432
    unsigned short* vn   = (unsigned short*)(ws + 100663296);     // 33,554,432
    float*          bet  = (float*)         (ws + 134217728);     //  1,048,576
    unsigned short* wsT  = (unsigned short*)(ws + 135266304);     //  1,703,936
    unsigned short* woT  = (unsigned short*)(ws + 136970240);     //    524,288

    if (ws_size < 137494528) return;   // fail readable (absmax) instead of faulting

    ln_kernel<<<8192, 256, 0, stream>>>(x, g, be, h);
    cvt_wslow<<<(NPAD * 512) / 256, 256, 0, stream>>>(w_slow, wsT);
    cvt_wout<<<(512 * 512) / 256, 256, 0, stream>>>(w_out, woT);
    gemm_qkv<<<dim3(13, MROWS / 128), 256, 0, stream>>>(h, wsT, qn, kn, vn, bet);
    recur3<<<BSZ * H_ * 8, 64, 0, stream>>>(qn, kn, vn, bet, outs);
    gemm_out<<<dim3(4, MROWS / 128), 256, 0, stream>>>(outs, woT, x, out);
}

// Round 4
// 528.887 us; speedup vs baseline: 1.6517x; 1.5131x over previous
//
#include <hip/hip_runtime.h>
#include <cstdint>

using short8  = __attribute__((ext_vector_type(8))) short;
using ushort8 = __attribute__((ext_vector_type(8))) unsigned short;
using short4v = __attribute__((ext_vector_type(4))) short;
using f32x4   = __attribute__((ext_vector_type(4))) float;

#define H_    8
#define SLEN  1024
#define BSZ   32
#define INDIM 512
#define NQKV  1544   // H*(3*D+1)
#define NPAD  1664   // 13*128
#define MROWS 32768  // SLEN*BSZ
#define PB    72     // bf16 LDS pad (stride 144B, 16B-aligned rows)
#define PF    68     // f32  LDS pad (stride 272B, 16B-aligned rows)

static __device__ __forceinline__ float bf2f(unsigned short s) {
    return __uint_as_float(((unsigned int)s) << 16);
}
static __device__ __forceinline__ unsigned short f2bf(float f) {
    unsigned int u = __float_as_uint(f);
    u += 0x7FFFu + ((u >> 16) & 1u);
    return (unsigned short)(u >> 16);
}

// ---------------- LayerNorm: x[32768][512] f32 -> h bf16 ----------------
__global__ __launch_bounds__(256) void ln_kernel(const float* __restrict__ x,
                                                 const float* __restrict__ gamma,
                                                 const float* __restrict__ betap,
                                                 unsigned short* __restrict__ h) {
    int row = blockIdx.x * 4 + (threadIdx.x >> 6);
    int l   = threadIdx.x & 63;
    const f32x4* xr = (const f32x4*)(x + (size_t)row * INDIM);
    f32x4 a = xr[l * 2], b = xr[l * 2 + 1];
    float s = 0.f, sq = 0.f;
    #pragma unroll
    for (int j = 0; j < 4; ++j) { s += a[j]; sq += a[j] * a[j]; }
    #pragma unroll
    for (int j = 0; j < 4; ++j) { s += b[j]; sq += b[j] * b[j]; }
    #pragma unroll
    for (int off = 32; off; off >>= 1) { s += __shfl_xor(s, off); sq += __shfl_xor(sq, off); }
    float mean = s * (1.f / 512.f);
    float var  = sq * (1.f / 512.f) - mean * mean;
    float rstd = rsqrtf(var + 1e-5f);
    const f32x4* g4 = (const f32x4*)gamma;
    const f32x4* b4 = (const f32x4*)betap;
    f32x4 g0 = g4[l * 2], g1 = g4[l * 2 + 1], e0 = b4[l * 2], e1 = b4[l * 2 + 1];
    short8 o;
    #pragma unroll
    for (int j = 0; j < 4; ++j) o[j]     = (short)f2bf((a[j] - mean) * rstd * g0[j] + e0[j]);
    #pragma unroll
    for (int j = 0; j < 4; ++j) o[4 + j] = (short)f2bf((b[j] - mean) * rstd * g1[j] + e1[j]);
    ((short8*)(h + (size_t)row * INDIM))[l] = o;
}

// ---------------- weight transpose+permute: wT[n][k], n grouped q|k|v|beta ----------------
__global__ __launch_bounds__(256) void cvt_wslow(const float* __restrict__ w,
                                                 unsigned short* __restrict__ wT) {
    int idx = blockIdx.x * 256 + threadIdx.x;   // NPAD*512
    int n = idx >> 9, k = idx & 511;
    int c;
    if (n < 512)       c = (n >> 6) * 193 + (n & 63);                 // q, head-major
    else if (n < 1024) c = ((n - 512) >> 6) * 193 + 64 + (n & 63);    // k
    else if (n < 1536) c = ((n - 1024) >> 6) * 193 + 128 + (n & 63);  // v
    else if (n < 1544) c = (n - 1536) * 193 + 192;                    // beta
    else               c = -1;                                         // pad
    wT[idx] = (c >= 0) ? f2bf(w[(size_t)k * NQKV + c]) : (unsigned short)0;
}
__global__ __launch_bounds__(256) void cvt_wout(const float* __restrict__ w,
                                                unsigned short* __restrict__ wT) {
    int idx = blockIdx.x * 256 + threadIdx.x;   // 512*512
    int n = idx >> 9, k = idx & 511;
    wT[idx] = f2bf(w[(size_t)k * 512 + n]);
}

// ---------------- GEMM1 fused: h @ wT^T -> elu+1/sumnorm q,k ; v ; sigmoid beta ----------------
__global__ __launch_bounds__(256) void gemm_qkv(const unsigned short* __restrict__ A,
                                                const unsigned short* __restrict__ BT,
                                                unsigned short* __restrict__ qn,
                                                unsigned short* __restrict__ kn,
                                                unsigned short* __restrict__ vn,
                                                float* __restrict__ bet) {
    __shared__ unsigned short As[128][72];
    __shared__ unsigned short Bs[128][72];
    const int t  = threadIdx.x;
    const int bx = blockIdx.x;
    const int n0 = bx * 128;
    const int m0 = blockIdx.y * 128;
    const int w = t >> 6, l = t & 63;
    const int wr = (w >> 1) * 64, wc = (w & 1) * 64;
    f32x4 acc[4][4] = {};
    for (int kt = 0; kt < INDIM; kt += 64) {
        __syncthreads();
        #pragma unroll
        for (int c = 0; c < 4; ++c) {
            int idx = c * 256 + t;
            int row = idx >> 3, kc = (idx & 7) * 8;
            *(short8*)&As[row][kc] = *(const short8*)(A  + (size_t)(m0 + row) * INDIM + kt + kc);
            *(short8*)&Bs[row][kc] = *(const short8*)(BT + (size_t)(n0 + row) * INDIM + kt + kc);
        }
        __syncthreads();
        #pragma unroll
        for (int kk = 0; kk < 2; ++kk) {
            const int kr = kk * 32 + (l >> 4) * 8;
            short8 af[4], bf[4];
            #pragma unroll
            for (int m = 0; m < 4; ++m) af[m] = *(const short8*)&As[wr + m * 16 + (l & 15)][kr];
            #pragma unroll
            for (int n = 0; n < 4; ++n) bf[n] = *(const short8*)&Bs[wc + n * 16 + (l & 15)][kr];
            #pragma unroll
            for (int m = 0; m < 4; ++m)
                #pragma unroll
                for (int n = 0; n < 4; ++n)
                    acc[m][n] = __builtin_amdgcn_mfma_f32_16x16x32_bf16(af[m], bf[n], acc[m][n], 0, 0, 0);
        }
    }
    const int g = l >> 4, cc = l & 15;
    const int colbase = n0 + wc;
    if (bx < 12) {
        const int reg  = colbase >> 9;            // 0=q, 1=k, 2=v (block-uniform)
        const int head = (colbase >> 6) & 7;      // wave-uniform
        unsigned short* dst = (reg == 0) ? qn : (reg == 1) ? kn : vn;
        #pragma unroll
        for (int m = 0; m < 4; ++m) {
            #pragma unroll
            for (int j = 0; j < 4; ++j) {
                int row = m0 + wr + m * 16 + g * 4 + j;
                int s = row >> 5, b = row & 31;
                size_t base = ((size_t)(b * H_ + head) * SLEN + s) * 64;
                float e0 = acc[m][0][j], e1 = acc[m][1][j], e2 = acc[m][2][j], e3 = acc[m][3][j];
                if (reg < 2) {
                    e0 = e0 > 0.f ? e0 + 1.f : __expf(e0);
                    e1 = e1 > 0.f ? e1 + 1.f : __expf(e1);
                    e2 = e2 > 0.f ? e2 + 1.f : __expf(e2);
                    e3 = e3 > 0.f ? e3 + 1.f : __expf(e3);
                    float ssum = (e0 + e1) + (e2 + e3);
                    ssum += __shfl_xor(ssum, 1);
                    ssum += __shfl_xor(ssum, 2);
                    ssum += __shfl_xor(ssum, 4);
                    ssum += __shfl_xor(ssum, 8);
                    float inv = 1.f / ssum;
                    e0 *= inv; e1 *= inv; e2 *= inv; e3 *= inv;
                }
                dst[base +  0 + cc] = f2bf(e0);
                dst[base + 16 + cc] = f2bf(e1);
                dst[base + 32 + cc] = f2bf(e2);
                dst[base + 48 + cc] = f2bf(e3);
            }
        }
    } else {
        if (wc == 0 && cc < 8) {
            #pragma unroll
            for (int m = 0; m < 4; ++m)
                #pragma unroll
                for (int j = 0; j < 4; ++j) {
                    int row = m0 + wr + m * 16 + g * 4 + j;
                    int s = row >> 5, b = row & 31;
                    float v = acc[m][0][j];
                    bet[(size_t)(b * H_ + cc) * SLEN + s] = 1.f / (1.f + __expf(-v));
                }
        }
    }
}

// ---------------- GEMM2: out = x + outs @ woT^T ----------------
__global__ __launch_bounds__(256) void gemm_out(const unsigned short* __restrict__ A,
                                                const unsigned short* __restrict__ BT,
                                                const float* __restrict__ X,
                                                float* __restrict__ outf) {
    __shared__ unsigned short As[128][72];
    __shared__ unsigned short Bs[128][72];
    const int t  = threadIdx.x;
    const int n0 = blockIdx.x * 128;
    const int m0 = blockIdx.y * 128;
    const int w = t >> 6, l = t & 63;
    const int wr = (w >> 1) * 64, wc = (w & 1) * 64;
    f32x4 acc[4][4] = {};
    for (int kt = 0; kt < INDIM; kt += 64) {
        __syncthreads();
        #pragma unroll
        for (int c = 0; c < 4; ++c) {
            int idx = c * 256 + t;
            int row = idx >> 3, kc = (idx & 7) * 8;
            *(short8*)&As[row][kc] = *(const short8*)(A  + (size_t)(m0 + row) * INDIM + kt + kc);
            *(short8*)&Bs[row][kc] = *(const short8*)(BT + (size_t)(n0 + row) * INDIM + kt + kc);
        }
        __syncthreads();
        #pragma unroll
        for (int kk = 0; kk < 2; ++kk) {
            const int kr = kk * 32 + (l >> 4) * 8;
            short8 af[4], bf[4];
            #pragma unroll
            for (int m = 0; m < 4; ++m) af[m] = *(const short8*)&As[wr + m * 16 + (l & 15)][kr];
            #pragma unroll
            for (int n = 0; n < 4; ++n) bf[n] = *(const short8*)&Bs[wc + n * 16 + (l & 15)][kr];
            #pragma unroll
            for (int m = 0; m < 4; ++m)
                #pragma unroll
                for (int n = 0; n < 4; ++n)
                    acc[m][n] = __builtin_amdgcn_mfma_f32_16x16x32_bf16(af[m], bf[n], acc[m][n], 0, 0, 0);
        }
    }
    const int rb = (l >> 4) * 4, cc = l & 15;
    #pragma unroll
    for (int m = 0; m < 4; ++m)
        #pragma unroll
        for (int n = 0; n < 4; ++n)
            #pragma unroll
            for (int j = 0; j < 4; ++j) {
                int row = m0 + wr + m * 16 + rb + j;
                int col = n0 + wc + n * 16 + cc;
                size_t o = (size_t)row * 512 + col;
                outf[o] = X[o] + acc[m][n][j];
            }
}

// ---------------- delta-rule recurrence v4: chunked WY form, MFMA, 1 wave / (b,h) ----------------
// Per chunk (C=64): A[t,s] = -b_t (k_t.k_s) [s<t, stored NEGATED];
//   Z = RHS = diag(b)(V - K W0^T); Z <- Z + A^p Z for p = 1,2,4,8,16,32 (nilpotent inverse);
//   O = Q W0^T + tril(Q K^T, incl) U;  W <- W0 + U^T K.
// All 64x64x64 products via mfma_f32_16x16x32_bf16 (verified layouts). No barriers (single wave).
__global__ __launch_bounds__(64) void recur4(const unsigned short* __restrict__ qn,
                                             const unsigned short* __restrict__ kn,
                                             const unsigned short* __restrict__ vn,
                                             const float* __restrict__ beta,
                                             unsigned short* __restrict__ outs) {
    __shared__ unsigned short Kx[64 * PB], Ktr[64 * PB], Qx[64 * PB], Vtr[64 * PB],
                              Ax[64 * PB], Atr[64 * PB], Pw[64 * PB], Pwtr[64 * PB], Wb[64 * PB];
    __shared__ float Wf[64 * PF], Zb0[64 * PF], Zb1[64 * PF], bv[64];

    const int bh = blockIdx.x;
    const int b = bh >> 3, h = bh & 7;
    const int l = threadIdx.x;
    const int lr = l & 15;          // operand row-in-tile / C col
    const int lk = (l >> 4) << 3;   // operand k offset
    const int rb = (l >> 4) << 2;   // C row base
    const unsigned short* kb = kn + (size_t)bh * (SLEN * 64);
    const unsigned short* qb = qn + (size_t)bh * (SLEN * 64);
    const unsigned short* vb = vn + (size_t)bh * (SLEN * 64);
    const float* bb = beta + (size_t)bh * SLEN;

    for (int i = l; i < 64 * PF; i += 64) Wf[i] = 0.f;
    for (int i = l; i < 64 * PB; i += 64) Wb[i] = 0;

    // fragment loaders (verified 16x16x32 layouts)
    auto ldb = [&](const unsigned short* M, int m, int kk) -> short8 {
        return *(const short8*)&M[(m * 16 + lr) * PB + kk * 32 + lk];
    };
    auto ldf = [&](const float* M, int m, int kk) -> short8 {
        const float* p = &M[(m * 16 + lr) * PF + kk * 32 + lk];
        f32x4 a = *(const f32x4*)p, c = *(const f32x4*)(p + 4);
        short8 r;
        r[0] = (short)f2bf(a[0]); r[1] = (short)f2bf(a[1]);
        r[2] = (short)f2bf(a[2]); r[3] = (short)f2bf(a[3]);
        r[4] = (short)f2bf(c[0]); r[5] = (short)f2bf(c[1]);
        r[6] = (short)f2bf(c[2]); r[7] = (short)f2bf(c[3]);
        return r;
    };

    // Z <- Zsrc + Xpow * Zsrc   (Xpow bf16, zero unless t-s>=p; Z fp32, tr layout)
    auto zprod = [&](const unsigned short* Xb, int p, const float* Zsrc, float* Zdst) {
        short8 xf[4][2], yf[4][2];
        #pragma unroll
        for (int m = 0; m < 4; ++m)
            #pragma unroll
            for (int kk = 0; kk < 2; ++kk)
                if (16 * m + 15 - 32 * kk >= p) xf[m][kk] = ldb(Xb, m, kk);
        #pragma unroll
        for (int n = 0; n < 4; ++n)
            #pragma unroll
            for (int kk = 0; kk < 2; ++kk)
                if (63 - 32 * kk >= p) yf[n][kk] = ldf(Zsrc, n, kk);
        #pragma unroll
        for (int m = 0; m < 4; ++m)
            #pragma unroll
            for (int n = 0; n < 4; ++n) {
                f32x4 a = *(const f32x4*)&Zsrc[(16 * n + lr) * PF + 16 * m + rb];
                #pragma unroll
                for (int kk = 0; kk < 2; ++kk)
                    if (16 * m + 15 - 32 * kk >= p)
                        a = __builtin_amdgcn_mfma_f32_16x16x32_bf16(xf[m][kk], yf[n][kk], a, 0, 0, 0);
                *(f32x4*)&Zdst[(16 * n + lr) * PF + 16 * m + rb] = a;
            }
    };

    // Pd = Ps * Ps  (both zero unless t-s>=p; result zero unless t-s>=2p); writes row+tr
    auto powprod = [&](const unsigned short* Ps, const unsigned short* Pstr, int p,
                       unsigned short* Pd, unsigned short* Pdtr) {
        short8 xf[4][2], yf[4][2];
        #pragma unroll
        for (int m = 0; m < 4; ++m)
            #pragma unroll
            for (int kk = 0; kk < 2; ++kk)
                if (16 * m + 15 - 32 * kk >= p) xf[m][kk] = ldb(Ps, m, kk);
        #pragma unroll
        for (int n = 0; n < 4; ++n)
            #pragma unroll
            for (int kk = 0; kk < 2; ++kk)
                if (32 * kk + 31 - 16 * n >= p) yf[n][kk] = ldb(Pstr, n, kk);
        #pragma unroll
        for (int m = 0; m < 4; ++m)
            #pragma unroll
            for (int n = 0; n < 4; ++n) {
                f32x4 a = {};
                #pragma unroll
                for (int kk = 0; kk < 2; ++kk)
                    if (16 * m + 15 - 32 * kk >= p && 32 * kk + 31 - 16 * n >= p)
                        a = __builtin_amdgcn_mfma_f32_16x16x32_bf16(xf[m][kk], yf[n][kk], a, 0, 0, 0);
                short4v pk;
                #pragma unroll
                for (int j = 0; j < 4; ++j) {
                    unsigned short v = f2bf(a[j]);
                    Pd[(16 * m + rb + j) * PB + 16 * n + lr] = v;
                    pk[j] = (short)v;
                }
                *(short4v*)&Pdtr[(16 * n + lr) * PB + 16 * m + rb] = pk;
            }
    };

    for (int c = 0; c < 16; ++c) {
        const int c0 = c * 64;
        // ---- stage chunk: K (row+tr), Q (row), V (tr), b ----
        {
            const int tl = l >> 3, d0 = (l & 7) * 8;
            #pragma unroll
            for (int it = 0; it < 8; ++it) {
                int tt = it * 8 + tl;
                ushort8 kv = *(const ushort8*)(kb + (size_t)(c0 + tt) * 64 + d0);
                ushort8 qv = *(const ushort8*)(qb + (size_t)(c0 + tt) * 64 + d0);
                ushort8 vv = *(const ushort8*)(vb + (size_t)(c0 + tt) * 64 + d0);
                *(ushort8*)&Kx[tt * PB + d0] = kv;
                *(ushort8*)&Qx[tt * PB + d0] = qv;
                #pragma unroll
                for (int j = 0; j < 8; ++j) {
                    Ktr[(d0 + j) * PB + tt] = vv[j] * 0 + kv[j];
                    Vtr[(d0 + j) * PB + tt] = vv[j];
                }
            }
            bv[l] = bb[c0 + l];
        }

        short8 kf[4][2], qf[4][2];
        #pragma unroll
        for (int m = 0; m < 4; ++m)
            #pragma unroll
            for (int kk = 0; kk < 2; ++kk) { kf[m][kk] = ldb(Kx, m, kk); qf[m][kk] = ldb(Qx, m, kk); }

        // ---- 1: S = K K^T -> A = -b_t*S masked s<t (row + tr) ----
        {
            f32x4 acc[4][4] = {};
            #pragma unroll
            for (int m = 0; m < 4; ++m)
                #pragma unroll
                for (int n = 0; n < 4; ++n)
                    #pragma unroll
                    for (int kk = 0; kk < 2; ++kk)
                        acc[m][n] = __builtin_amdgcn_mfma_f32_16x16x32_bf16(kf[m][kk], kf[n][kk], acc[m][n], 0, 0, 0);
            #pragma unroll
            for (int m = 0; m < 4; ++m) {
                f32x4 btm = *(const f32x4*)&bv[16 * m + rb];
                #pragma unroll
                for (int n = 0; n < 4; ++n) {
                    short4v pk;
                    #pragma unroll
                    for (int j = 0; j < 4; ++j) {
                        int t = 16 * m + rb + j, s = 16 * n + lr;
                        float val = (s < t) ? (-btm[j] * acc[m][n][j]) : 0.f;
                        unsigned short v = f2bf(val);
                        Ax[t * PB + s] = v;
                        pk[j] = (short)v;
                    }
                    *(short4v*)&Atr[(16 * n + lr) * PB + 16 * m + rb] = pk;
                }
            }
        }

        // ---- 2: R0 = K W0^T -> Z0 = b(V - R0) (fp32 tr) ----
        {
            short8 wf[4][2];
            #pragma unroll
            for (int n = 0; n < 4; ++n)
                #pragma unroll
                for (int kk = 0; kk < 2; ++kk) wf[n][kk] = ldb(Wb, n, kk);
            f32x4 acc[4][4] = {};
            #pragma unroll
            for (int m = 0; m < 4; ++m)
                #pragma unroll
                for (int n = 0; n < 4; ++n)
                    #pragma unroll
                    for (int kk = 0; kk < 2; ++kk)
                        acc[m][n] = __builtin_amdgcn_mfma_f32_16x16x32_bf16(kf[m][kk], wf[n][kk], acc[m][n], 0, 0, 0);
            #pragma unroll
            for (int m = 0; m < 4; ++m) {
                f32x4 btm = *(const f32x4*)&bv[16 * m + rb];
                #pragma unroll
                for (int n = 0; n < 4; ++n) {
                    short4v vv4 = *(const short4v*)&Vtr[(16 * n + lr) * PB + 16 * m + rb];
                    f32x4 z;
                    #pragma unroll
                    for (int j = 0; j < 4; ++j)
                        z[j] = btm[j] * (bf2f((unsigned short)vv4[j]) - acc[m][n][j]);
                    *(f32x4*)&Zb0[(16 * n + lr) * PF + 16 * m + rb] = z;
                }
            }
        }

        // ---- 3..13: nilpotent solve, interleaving Z-updates and power squaring ----
        zprod(Ax, 1, Zb0, Zb1);                 // Z (I - A)
        powprod(Ax, Atr, 1, Pw, Pwtr);          // A^2
        zprod(Pw, 2, Zb1, Zb0);                 // (I + A^2)
        powprod(Pw, Pwtr, 2, Ax, Atr);          // A^4
        zprod(Ax, 4, Zb0, Zb1);                 // (I + A^4)
        powprod(Ax, Atr, 4, Pw, Pwtr);          // A^8
        zprod(Pw, 8, Zb1, Zb0);                 // (I + A^8)
        powprod(Pw, Pwtr, 8, Ax, Atr);          // A^16
        zprod(Ax, 16, Zb0, Zb1);                // (I + A^16)
        powprod(Ax, Atr, 16, Pw, Pwtr);         // A^32
        zprod(Pw, 32, Zb1, Zb0);                // (I + A^32)  -> U in Zb0

        // ---- 14: Pm = tril(Q K^T, incl) into Vtr (row-major, V dead) ----
        {
            f32x4 acc[4][4] = {};
            #pragma unroll
            for (int m = 0; m < 4; ++m)
                #pragma unroll
                for (int n = 0; n < 4; ++n)
                    #pragma unroll
                    for (int kk = 0; kk < 2; ++kk)
                        acc[m][n] = __builtin_amdgcn_mfma_f32_16x16x32_bf16(qf[m][kk], kf[n][kk], acc[m][n], 0, 0, 0);
            #pragma unroll
            for (int m = 0; m < 4; ++m)
                #pragma unroll
                for (int n = 0; n < 4; ++n)
                    #pragma unroll
                    for (int j = 0; j < 4; ++j) {
                        int t = 16 * m + rb + j, s = 16 * n + lr;
                        Vtr[t * PB + s] = (s <= t) ? f2bf(acc[m][n][j]) : (unsigned short)0;
                    }
        }

        // ---- 15: O = Q W0^T + Pm U -> global ----
        {
            short8 wf[4][2], uf[4][2], pf[4][2];
            #pragma unroll
            for (int n = 0; n < 4; ++n)
                #pragma unroll
                for (int kk = 0; kk < 2; ++kk) { wf[n][kk] = ldb(Wb, n, kk); uf[n][kk] = ldf(Zb0, n, kk); }
            #pragma unroll
            for (int m = 0; m < 4; ++m)
                #pragma unroll
                for (int kk = 0; kk < 2; ++kk)
                    if (16 * m + 15 - 32 * kk >= 0) pf[m][kk] = ldb(Vtr, m, kk);
            f32x4 acc[4][4] = {};
            #pragma unroll
            for (int m = 0; m < 4; ++m)
                #pragma unroll
                for (int n = 0; n < 4; ++n)
                    #pragma unroll
                    for (int kk = 0; kk < 2; ++kk) {
                        acc[m][n] = __builtin_amdgcn_mfma_f32_16x16x32_bf16(qf[m][kk], wf[n][kk], acc[m][n], 0, 0, 0);
                        if (16 * m + 15 - 32 * kk >= 0)
                            acc[m][n] = __builtin_amdgcn_mfma_f32_16x16x32_bf16(pf[m][kk], uf[n][kk], acc[m][n], 0, 0, 0);
                    }
            #pragma unroll
            for (int m = 0; m < 4; ++m)
                #pragma unroll
                for (int n = 0; n < 4; ++n)
                    #pragma unroll
                    for (int j = 0; j < 4; ++j) {
                        int t = c0 + 16 * m + rb + j;
                        outs[((size_t)t * BSZ + b) * 512 + h * 64 + 16 * n + lr] = f2bf(acc[m][n][j]);
                    }
        }

        // ---- 16: W <- W0 + U^T K (fp32 master + bf16 mirror) ----
        {
            short8 uf[4][2], ktf[4][2];
            #pragma unroll
            for (int m = 0; m < 4; ++m)
                #pragma unroll
                for (int kk = 0; kk < 2; ++kk) { uf[m][kk] = ldf(Zb0, m, kk); ktf[m][kk] = ldb(Ktr, m, kk); }
            f32x4 acc[4][4];
            #pragma unroll
            for (int m = 0; m < 4; ++m)
                #pragma unroll
                for (int n = 0; n < 4; ++n) {
                    #pragma unroll
                    for (int j = 0; j < 4; ++j) acc[m][n][j] = Wf[(16 * m + rb + j) * PF + 16 * n + lr];
                    #pragma unroll
                    for (int kk = 0; kk < 2; ++kk)
                        acc[m][n] = __builtin_amdgcn_mfma_f32_16x16x32_bf16(uf[m][kk], ktf[n][kk], acc[m][n], 0, 0, 0);
                    #pragma unroll
                    for (int j = 0; j < 4; ++j) {
                        Wf[(16 * m + rb + j) * PF + 16 * n + lr] = acc[m][n][j];
                        Wb[(16 * m + rb + j) * PB + 16 * n + lr] = f2bf(acc[m][n][j]);
                    }
                }
        }
    }
}

// ---------------- launch ----------------
extern "C" void kernel_launch(void* const* d_in, const int* in_sizes, int n_in,
                              void* d_out, int out_size, void* d_ws, size_t ws_size,
                              hipStream_t stream) {
    const float* x      = (const float*)d_in[0];
    const float* g      = (const float*)d_in[1];
    const float* be     = (const float*)d_in[2];
    const float* w_slow = (const float*)d_in[3];
    const float* w_out  = (const float*)d_in[4];
    float* out = (float*)d_out;
    char* ws = (char*)d_ws;

    unsigned short* h    = (unsigned short*)(ws);                 // 33,554,432 (reused as outs)
    unsigned short* outs = (unsigned short*)(ws);                 // alias: h dead after gemm1
    unsigned short* qn   = (unsigned short*)(ws + 33554432);
    unsigned short* kn   = (unsigned short*)(ws + 67108864);
    unsigned short* vn   = (unsigned short*)(ws + 100663296);
    float*          bet  = (float*)         (ws + 134217728);
    unsigned short* wsT  = (unsigned short*)(ws + 135266304);
    unsigned short* woT  = (unsigned short*)(ws + 136970240);

    if (ws_size < 137494528) return;

    ln_kernel<<<8192, 256, 0, stream>>>(x, g, be, h);
    cvt_wslow<<<(NPAD * 512) / 256, 256, 0, stream>>>(w_slow, wsT);
    cvt_wout<<<(512 * 512) / 256, 256, 0, stream>>>(w_out, woT);
    gemm_qkv<<<dim3(13, MROWS / 128), 256, 0, stream>>>(h, wsT, qn, kn, vn, bet);
    recur4<<<BSZ * H_, 64, 0, stream>>>(qn, kn, vn, bet, outs);
    gemm_out<<<dim3(4, MROWS / 128), 256, 0, stream>>>(outs, woT, x, out);
}

// Round 5
// 458.171 us; speedup vs baseline: 1.9066x; 1.1543x over previous
//
#include <hip/hip_runtime.h>
#include <cstdint>

using short8  = __attribute__((ext_vector_type(8))) short;
using ushort8 = __attribute__((ext_vector_type(8))) unsigned short;
using short4v = __attribute__((ext_vector_type(4))) short;
using f32x4   = __attribute__((ext_vector_type(4))) float;

#define H_    8
#define SLEN  1024
#define BSZ   32
#define INDIM 512
#define NQKV  1544   // H*(3*D+1)
#define NPAD  1664   // 13*128
#define MROWS 32768  // SLEN*BSZ
#define PB    72     // bf16 LDS pad stride

static __device__ __forceinline__ float bf2f(unsigned short s) {
    return __uint_as_float(((unsigned int)s) << 16);
}
static __device__ __forceinline__ unsigned short f2bf(float f) {
    unsigned int u = __float_as_uint(f);
    u += 0x7FFFu + ((u >> 16) & 1u);
    return (unsigned short)(u >> 16);
}

// ---------------- LayerNorm: x[32768][512] f32 -> h bf16 ----------------
__global__ __launch_bounds__(256) void ln_kernel(const float* __restrict__ x,
                                                 const float* __restrict__ gamma,
                                                 const float* __restrict__ betap,
                                                 unsigned short* __restrict__ h) {
    int row = blockIdx.x * 4 + (threadIdx.x >> 6);
    int l   = threadIdx.x & 63;
    const f32x4* xr = (const f32x4*)(x + (size_t)row * INDIM);
    f32x4 a = xr[l * 2], b = xr[l * 2 + 1];
    float s = 0.f, sq = 0.f;
    #pragma unroll
    for (int j = 0; j < 4; ++j) { s += a[j]; sq += a[j] * a[j]; }
    #pragma unroll
    for (int j = 0; j < 4; ++j) { s += b[j]; sq += b[j] * b[j]; }
    #pragma unroll
    for (int off = 32; off; off >>= 1) { s += __shfl_xor(s, off); sq += __shfl_xor(sq, off); }
    float mean = s * (1.f / 512.f);
    float var  = sq * (1.f / 512.f) - mean * mean;
    float rstd = rsqrtf(var + 1e-5f);
    const f32x4* g4 = (const f32x4*)gamma;
    const f32x4* b4 = (const f32x4*)betap;
    f32x4 g0 = g4[l * 2], g1 = g4[l * 2 + 1], e0 = b4[l * 2], e1 = b4[l * 2 + 1];
    short8 o;
    #pragma unroll
    for (int j = 0; j < 4; ++j) o[j]     = (short)f2bf((a[j] - mean) * rstd * g0[j] + e0[j]);
    #pragma unroll
    for (int j = 0; j < 4; ++j) o[4 + j] = (short)f2bf((b[j] - mean) * rstd * g1[j] + e1[j]);
    ((short8*)(h + (size_t)row * INDIM))[l] = o;
}

// ---------------- weight transpose+permute ----------------
__global__ __launch_bounds__(256) void cvt_wslow(const float* __restrict__ w,
                                                 unsigned short* __restrict__ wT) {
    int idx = blockIdx.x * 256 + threadIdx.x;
    int n = idx >> 9, k = idx & 511;
    int c;
    if (n < 512)       c = (n >> 6) * 193 + (n & 63);
    else if (n < 1024) c = ((n - 512) >> 6) * 193 + 64 + (n & 63);
    else if (n < 1536) c = ((n - 1024) >> 6) * 193 + 128 + (n & 63);
    else if (n < 1544) c = (n - 1536) * 193 + 192;
    else               c = -1;
    wT[idx] = (c >= 0) ? f2bf(w[(size_t)k * NQKV + c]) : (unsigned short)0;
}
__global__ __launch_bounds__(256) void cvt_wout(const float* __restrict__ w,
                                                unsigned short* __restrict__ wT) {
    int idx = blockIdx.x * 256 + threadIdx.x;
    int n = idx >> 9, k = idx & 511;
    wT[idx] = f2bf(w[(size_t)k * 512 + n]);
}

// ---------------- GEMM1 fused ----------------
__global__ __launch_bounds__(256) void gemm_qkv(const unsigned short* __restrict__ A,
                                                const unsigned short* __restrict__ BT,
                                                unsigned short* __restrict__ qn,
                                                unsigned short* __restrict__ kn,
                                                unsigned short* __restrict__ vn,
                                                float* __restrict__ bet) {
    __shared__ unsigned short As[128][72];
    __shared__ unsigned short Bs[128][72];
    const int t  = threadIdx.x;
    const int bx = blockIdx.x;
    const int n0 = bx * 128;
    const int m0 = blockIdx.y * 128;
    const int w = t >> 6, l = t & 63;
    const int wr = (w >> 1) * 64, wc = (w & 1) * 64;
    f32x4 acc[4][4] = {};
    for (int kt = 0; kt < INDIM; kt += 64) {
        __syncthreads();
        #pragma unroll
        for (int c = 0; c < 4; ++c) {
            int idx = c * 256 + t;
            int row = idx >> 3, kc = (idx & 7) * 8;
            *(short8*)&As[row][kc] = *(const short8*)(A  + (size_t)(m0 + row) * INDIM + kt + kc);
            *(short8*)&Bs[row][kc] = *(const short8*)(BT + (size_t)(n0 + row) * INDIM + kt + kc);
        }
        __syncthreads();
        #pragma unroll
        for (int kk = 0; kk < 2; ++kk) {
            const int kr = kk * 32 + (l >> 4) * 8;
            short8 af[4], bf[4];
            #pragma unroll
            for (int m = 0; m < 4; ++m) af[m] = *(const short8*)&As[wr + m * 16 + (l & 15)][kr];
            #pragma unroll
            for (int n = 0; n < 4; ++n) bf[n] = *(const short8*)&Bs[wc + n * 16 + (l & 15)][kr];
            #pragma unroll
            for (int m = 0; m < 4; ++m)
                #pragma unroll
                for (int n = 0; n < 4; ++n)
                    acc[m][n] = __builtin_amdgcn_mfma_f32_16x16x32_bf16(af[m], bf[n], acc[m][n], 0, 0, 0);
        }
    }
    const int g = l >> 4, cc = l & 15;
    const int colbase = n0 + wc;
    if (bx < 12) {
        const int reg  = colbase >> 9;
        const int head = (colbase >> 6) & 7;
        unsigned short* dst = (reg == 0) ? qn : (reg == 1) ? kn : vn;
        #pragma unroll
        for (int m = 0; m < 4; ++m) {
            #pragma unroll
            for (int j = 0; j < 4; ++j) {
                int row = m0 + wr + m * 16 + g * 4 + j;
                int s = row >> 5, b = row & 31;
                size_t base = ((size_t)(b * H_ + head) * SLEN + s) * 64;
                float e0 = acc[m][0][j], e1 = acc[m][1][j], e2 = acc[m][2][j], e3 = acc[m][3][j];
                if (reg < 2) {
                    e0 = e0 > 0.f ? e0 + 1.f : __expf(e0);
                    e1 = e1 > 0.f ? e1 + 1.f : __expf(e1);
                    e2 = e2 > 0.f ? e2 + 1.f : __expf(e2);
                    e3 = e3 > 0.f ? e3 + 1.f : __expf(e3);
                    float ssum = (e0 + e1) + (e2 + e3);
                    ssum += __shfl_xor(ssum, 1);
                    ssum += __shfl_xor(ssum, 2);
                    ssum += __shfl_xor(ssum, 4);
                    ssum += __shfl_xor(ssum, 8);
                    float inv = 1.f / ssum;
                    e0 *= inv; e1 *= inv; e2 *= inv; e3 *= inv;
                }
                dst[base +  0 + cc] = f2bf(e0);
                dst[base + 16 + cc] = f2bf(e1);
                dst[base + 32 + cc] = f2bf(e2);
                dst[base + 48 + cc] = f2bf(e3);
            }
        }
    } else {
        if (wc == 0 && cc < 8) {
            #pragma unroll
            for (int m = 0; m < 4; ++m)
                #pragma unroll
                for (int j = 0; j < 4; ++j) {
                    int row = m0 + wr + m * 16 + g * 4 + j;
                    int s = row >> 5, b = row & 31;
                    float v = acc[m][0][j];
                    bet[(size_t)(b * H_ + cc) * SLEN + s] = 1.f / (1.f + __expf(-v));
                }
        }
    }
}

// ---------------- GEMM2: out = x + outs @ woT^T ----------------
__global__ __launch_bounds__(256) void gemm_out(const unsigned short* __restrict__ A,
                                                const unsigned short* __restrict__ BT,
                                                const float* __restrict__ X,
                                                float* __restrict__ outf) {
    __shared__ unsigned short As[128][72];
    __shared__ unsigned short Bs[128][72];
    const int t  = threadIdx.x;
    const int n0 = blockIdx.x * 128;
    const int m0 = blockIdx.y * 128;
    const int w = t >> 6, l = t & 63;
    const int wr = (w >> 1) * 64, wc = (w & 1) * 64;
    f32x4 acc[4][4] = {};
    for (int kt = 0; kt < INDIM; kt += 64) {
        __syncthreads();
        #pragma unroll
        for (int c = 0; c < 4; ++c) {
            int idx = c * 256 + t;
            int row = idx >> 3, kc = (idx & 7) * 8;
            *(short8*)&As[row][kc] = *(const short8*)(A  + (size_t)(m0 + row) * INDIM + kt + kc);
            *(short8*)&Bs[row][kc] = *(const short8*)(BT + (size_t)(n0 + row) * INDIM + kt + kc);
        }
        __syncthreads();
        #pragma unroll
        for (int kk = 0; kk < 2; ++kk) {
            const int kr = kk * 32 + (l >> 4) * 8;
            short8 af[4], bf[4];
            #pragma unroll
            for (int m = 0; m < 4; ++m) af[m] = *(const short8*)&As[wr + m * 16 + (l & 15)][kr];
            #pragma unroll
            for (int n = 0; n < 4; ++n) bf[n] = *(const short8*)&Bs[wc + n * 16 + (l & 15)][kr];
            #pragma unroll
            for (int m = 0; m < 4; ++m)
                #pragma unroll
                for (int n = 0; n < 4; ++n)
                    acc[m][n] = __builtin_amdgcn_mfma_f32_16x16x32_bf16(af[m], bf[n], acc[m][n], 0, 0, 0);
        }
    }
    const int rb = (l >> 4) * 4, cc = l & 15;
    #pragma unroll
    for (int m = 0; m < 4; ++m)
        #pragma unroll
        for (int n = 0; n < 4; ++n)
            #pragma unroll
            for (int j = 0; j < 4; ++j) {
                int row = m0 + wr + m * 16 + rb + j;
                int col = n0 + wc + n * 16 + cc;
                size_t o = (size_t)row * 512 + col;
                outf[o] = X[o] + acc[m][n][j];
            }
}

// ---------------- phase 1: per-(bh,chunk) WY tile factors (4 waves m-split) ----------------
// Z = [bV | -bK] (tr, bf16); solve (I+A)^{-1} via nilpotent doubling;
// emit Mt = -K^T Bk, G = Q - P Bk, N = Bv^T K (bf16 tiles) and PBv -> outs (O-accumulator init).
__global__ __launch_bounds__(256, 2) void fwtiles(const unsigned short* __restrict__ qn,
                                                  const unsigned short* __restrict__ kn,
                                                  const unsigned short* __restrict__ vn,
                                                  const float* __restrict__ beta,
                                                  unsigned short* __restrict__ tiles,
                                                  unsigned short* __restrict__ outs) {
    __shared__ unsigned short Ax[64 * PB], Atr[64 * PB], Pw[64 * PB], Pwtr[64 * PB];
    __shared__ unsigned short Z0[128 * PB], Z1[128 * PB];
    __shared__ float bv[64];
    const int bx = blockIdx.x;
    const int bh = bx >> 4, c = bx & 15;
    const int b = bh >> 3, h = bh & 7;
    const int c0 = c * 64;
    const int tid = threadIdx.x;
    const int w = tid >> 6, l = tid & 63;
    const int lr = l & 15, lk = (l >> 4) << 3, rb = (l >> 4) << 2;
    const unsigned short* kc = kn + ((size_t)bh * SLEN + c0) * 64;
    const unsigned short* qc = qn + ((size_t)bh * SLEN + c0) * 64;
    const unsigned short* vc = vn + ((size_t)bh * SLEN + c0) * 64;
    const float* bb = beta + (size_t)bh * SLEN + c0;

    // ---- S0: stage Z0 = [bV | -bK]^T, bv; zero A/Atr ----
    {
        int t = tid >> 2, d0 = (tid & 3) * 16;
        float bt = bb[t];
        ushort8 v0 = *(const ushort8*)(vc + (size_t)t * 64 + d0);
        ushort8 v1 = *(const ushort8*)(vc + (size_t)t * 64 + d0 + 8);
        ushort8 k0 = *(const ushort8*)(kc + (size_t)t * 64 + d0);
        ushort8 k1 = *(const ushort8*)(kc + (size_t)t * 64 + d0 + 8);
        #pragma unroll
        for (int j = 0; j < 8; ++j) {
            Z0[(d0 + j) * PB + t]          = f2bf(bt * bf2f(v0[j]));
            Z0[(d0 + 8 + j) * PB + t]      = f2bf(bt * bf2f(v1[j]));
            Z0[(64 + d0 + j) * PB + t]     = f2bf(-bt * bf2f(k0[j]));
            Z0[(64 + d0 + 8 + j) * PB + t] = f2bf(-bt * bf2f(k1[j]));
        }
        if (tid < 64) bv[tid] = bb[tid];
        ushort8 z8 = {};
        for (int i = tid; i < (64 * PB) / 8; i += 256) {
            ((ushort8*)Ax)[i]  = z8;
            ((ushort8*)Atr)[i] = z8;
        }
    }
    __syncthreads();

    auto ldb = [&](const unsigned short* M, int m, int kk) -> short8 {
        return *(const short8*)&M[(m * 16 + lr) * PB + kk * 32 + lk];
    };
    auto gfrag = [&](const unsigned short* base, int m, int kk) -> short8 {
        return *(const short8*)(base + (size_t)(16 * m + lr) * 64 + kk * 32 + lk);
    };
    auto gtfrag = [&](const unsigned short* base, int idx, int kk) -> short8 {
        short8 r;
        #pragma unroll
        for (int j = 0; j < 8; ++j)
            r[j] = (short)base[(size_t)(kk * 32 + lk + j) * 64 + 16 * idx + lr];
        return r;
    };
    // Zd = Zs + X^p * Zs (bf16, tr layout; copy-through where masked)
    auto zprod = [&](const unsigned short* Xb, int p, const unsigned short* Zs, unsigned short* Zd) {
        const bool m0 = (16 * w + 15 >= p), m1 = (16 * w + 15 - 32 >= p);
        short8 xf0, xf1;
        if (m0) xf0 = ldb(Xb, w, 0);
        if (m1) xf1 = ldb(Xb, w, 1);
        #pragma unroll
        for (int n = 0; n < 8; ++n) {
            short4v zi = *(const short4v*)&Zs[(16 * n + lr) * PB + 16 * w + rb];
            f32x4 a;
            #pragma unroll
            for (int j = 0; j < 4; ++j) a[j] = bf2f((unsigned short)zi[j]);
            if (m0) a = __builtin_amdgcn_mfma_f32_16x16x32_bf16(xf0, ldb(Zs, n, 0), a, 0, 0, 0);
            if (m1) a = __builtin_amdgcn_mfma_f32_16x16x32_bf16(xf1, ldb(Zs, n, 1), a, 0, 0, 0);
            short4v zo;
            #pragma unroll
            for (int j = 0; j < 4; ++j) zo[j] = (short)f2bf(a[j]);
            *(short4v*)&Zd[(16 * n + lr) * PB + 16 * w + rb] = zo;
        }
    };
    // Pd = Ps * Ps (writes row + tr, zeros included)
    auto powp = [&](const unsigned short* Ps, const unsigned short* Pstr, int p,
                    unsigned short* Pd, unsigned short* Pdtr) {
        const bool x0 = (16 * w + 15 >= p), x1 = (16 * w + 15 - 32 >= p);
        short8 xf0, xf1;
        if (x0) xf0 = ldb(Ps, w, 0);
        if (x1) xf1 = ldb(Ps, w, 1);
        #pragma unroll
        for (int n = 0; n < 4; ++n) {
            const bool y0 = (31 - 16 * n >= p), y1 = (63 - 16 * n >= p);
            f32x4 a = {};
            if (x0 && y0) a = __builtin_amdgcn_mfma_f32_16x16x32_bf16(xf0, ldb(Pstr, n, 0), a, 0, 0, 0);
            if (x1 && y1) a = __builtin_amdgcn_mfma_f32_16x16x32_bf16(xf1, ldb(Pstr, n, 1), a, 0, 0, 0);
            short4v pk;
            #pragma unroll
            for (int j = 0; j < 4; ++j) {
                unsigned short v = f2bf(a[j]);
                Pd[(16 * w + rb + j) * PB + 16 * n + lr] = v;
                pk[j] = (short)v;
            }
            *(short4v*)&Pdtr[(16 * n + lr) * PB + 16 * w + rb] = pk;
        }
    };

    // ---- S1: A = -b_t * tril(K K^T, s<t) ----
    {
        short8 ka0 = gfrag(kc, w, 0), ka1 = gfrag(kc, w, 1);
        f32x4 btm = *(const f32x4*)&bv[16 * w + rb];
        for (int n = 0; n <= w; ++n) {
            f32x4 a = {};
            a = __builtin_amdgcn_mfma_f32_16x16x32_bf16(ka0, gfrag(kc, n, 0), a, 0, 0, 0);
            a = __builtin_amdgcn_mfma_f32_16x16x32_bf16(ka1, gfrag(kc, n, 1), a, 0, 0, 0);
            short4v pk;
            #pragma unroll
            for (int j = 0; j < 4; ++j) {
                int t = 16 * w + rb + j, s = 16 * n + lr;
                unsigned short v = (s < t) ? f2bf(-btm[j] * a[j]) : (unsigned short)0;
                Ax[t * PB + s] = v;
                pk[j] = (short)v;
            }
            *(short4v*)&Atr[(16 * n + lr) * PB + 16 * w + rb] = pk;
        }
    }
    __syncthreads();

    // ---- nilpotent solve: Z <- (I+A^32)(I+A^16)(I+A^8)(I+A^4)(I+A^2)(I-A) Z ----
    zprod(Ax, 1, Z0, Z1);  powp(Ax, Atr, 1, Pw, Pwtr);  __syncthreads();
    zprod(Pw, 2, Z1, Z0);  powp(Pw, Pwtr, 2, Ax, Atr);  __syncthreads();
    zprod(Ax, 4, Z0, Z1);  powp(Ax, Atr, 4, Pw, Pwtr);  __syncthreads();
    zprod(Pw, 8, Z1, Z0);  powp(Pw, Pwtr, 8, Ax, Atr);  __syncthreads();
    zprod(Ax, 16, Z0, Z1); powp(Ax, Atr, 16, Pw, Pwtr); __syncthreads();
    zprod(Pw, 32, Z1, Z0); __syncthreads();
    // Z0 rows 0..63 = Bv^T, rows 64..127 = (-Bk)^T

    // ---- S8: P = tril(Q K^T, incl) -> Ax rows own (zeros above diag) ----
    short8 qa0 = gfrag(qc, w, 0), qa1 = gfrag(qc, w, 1);
    #pragma unroll
    for (int n = 0; n < 4; ++n) {
        f32x4 a = {};
        a = __builtin_amdgcn_mfma_f32_16x16x32_bf16(qa0, gfrag(kc, n, 0), a, 0, 0, 0);
        a = __builtin_amdgcn_mfma_f32_16x16x32_bf16(qa1, gfrag(kc, n, 1), a, 0, 0, 0);
        #pragma unroll
        for (int j = 0; j < 4; ++j) {
            int t = 16 * w + rb + j, s = 16 * n + lr;
            Ax[t * PB + s] = (s <= t) ? f2bf(a[j]) : (unsigned short)0;
        }
    }

    // ---- S9: outputs ----
    unsigned short* tb = tiles + ((size_t)bh * 16 + c) * 12288;  // Mt | G | N
    short8 pA0 = ldb(Ax, w, 0), pA1 = ldb(Ax, w, 1);
    short8 zA0 = ldb(Z0, w, 0), zA1 = ldb(Z0, w, 1);        // Bv^T rows own
    short8 kt0 = gtfrag(kc, w, 0), kt1 = gtfrag(kc, w, 1);  // K^T rows own
    #pragma unroll
    for (int n = 0; n < 4; ++n) {
        // N[d,e] = sum_t Bv[t,d] K[t,e]
        f32x4 aN = {};
        aN = __builtin_amdgcn_mfma_f32_16x16x32_bf16(zA0, gtfrag(kc, n, 0), aN, 0, 0, 0);
        aN = __builtin_amdgcn_mfma_f32_16x16x32_bf16(zA1, gtfrag(kc, n, 1), aN, 0, 0, 0);
        // Mt[e,f] = -sum_t K[t,e] Bk[t,f]
        f32x4 aM = {};
        aM = __builtin_amdgcn_mfma_f32_16x16x32_bf16(kt0, ldb(Z0, 4 + n, 0), aM, 0, 0, 0);
        aM = __builtin_amdgcn_mfma_f32_16x16x32_bf16(kt1, ldb(Z0, 4 + n, 1), aM, 0, 0, 0);
        // G[t,e] = Q[t,e] - (P Bk)[t,e]
        f32x4 aG;
        #pragma unroll
        for (int j = 0; j < 4; ++j) aG[j] = bf2f(qc[(size_t)(16 * w + rb + j) * 64 + 16 * n + lr]);
        aG = __builtin_amdgcn_mfma_f32_16x16x32_bf16(pA0, ldb(Z0, 4 + n, 0), aG, 0, 0, 0);
        aG = __builtin_amdgcn_mfma_f32_16x16x32_bf16(pA1, ldb(Z0, 4 + n, 1), aG, 0, 0, 0);
        // PBv[t,d] -> outs (O accumulator init)
        f32x4 aP = {};
        aP = __builtin_amdgcn_mfma_f32_16x16x32_bf16(pA0, ldb(Z0, n, 0), aP, 0, 0, 0);
        aP = __builtin_amdgcn_mfma_f32_16x16x32_bf16(pA1, ldb(Z0, n, 1), aP, 0, 0, 0);
        #pragma unroll
        for (int j = 0; j < 4; ++j) {
            int r = 16 * w + rb + j, cl = 16 * n + lr;
            tb[8192 + r * 64 + cl] = f2bf(aN[j]);
            tb[r * 64 + cl]        = f2bf(aM[j]);
            tb[4096 + r * 64 + cl] = f2bf(aG[j]);
            outs[((size_t)(c0 + r) * BSZ + b) * 512 + h * 64 + cl] = f2bf(aP[j]);
        }
    }
}

// ---------------- phase 2: W scan + O finalize (4 independent waves, no barriers) ----------------
__global__ __launch_bounds__(256) void fwscan(const unsigned short* __restrict__ tiles,
                                              unsigned short* __restrict__ outs) {
    __shared__ float Wf[64 * 68];
    const int bh = blockIdx.x;
    const int b = bh >> 3, h = bh & 7;
    const int tid = threadIdx.x;
    const int w = tid >> 6, l = tid & 63;
    const int lr = l & 15, lk = (l >> 4) << 3, rb = (l >> 4) << 2;
    #pragma unroll
    for (int j = 0; j < 16; ++j) Wf[(16 * w + j) * 68 + l] = 0.f;   // own rows

    for (int c = 0; c < 16; ++c) {
        const int c0 = c * 64;
        const unsigned short* tb = tiles + ((size_t)bh * 16 + c) * 12288;
        // W0 frags (rows own, k = full 64), fp32 LDS -> bf16
        short8 wf0, wf1;
        {
            const float* p0 = &Wf[(16 * w + lr) * 68 + lk];
            f32x4 a0 = *(const f32x4*)p0, b0 = *(const f32x4*)(p0 + 4);
            f32x4 a1 = *(const f32x4*)(p0 + 32), b1 = *(const f32x4*)(p0 + 36);
            #pragma unroll
            for (int j = 0; j < 4; ++j) {
                wf0[j] = (short)f2bf(a0[j]); wf0[4 + j] = (short)f2bf(b0[j]);
                wf1[j] = (short)f2bf(a1[j]); wf1[4 + j] = (short)f2bf(b1[j]);
            }
        }
        // O-step: O[t, d_own] = PBv(in outs) + sum_e G[t,e] W0[d,e]
        #pragma unroll
        for (int m = 0; m < 4; ++m) {
            short8 g0 = *(const short8*)(tb + 4096 + (size_t)(16 * m + lr) * 64 + lk);
            short8 g1 = *(const short8*)(tb + 4096 + (size_t)(16 * m + lr) * 64 + 32 + lk);
            size_t ob = ((size_t)(c0 + 16 * m + rb) * BSZ + b) * 512 + h * 64 + 16 * w + lr;
            f32x4 a;
            #pragma unroll
            for (int j = 0; j < 4; ++j) a[j] = bf2f(outs[ob + (size_t)j * 16384]);
            a = __builtin_amdgcn_mfma_f32_16x16x32_bf16(g0, wf0, a, 0, 0, 0);
            a = __builtin_amdgcn_mfma_f32_16x16x32_bf16(g1, wf1, a, 0, 0, 0);
            #pragma unroll
            for (int j = 0; j < 4; ++j) outs[ob + (size_t)j * 16384] = f2bf(a[j]);
        }
        // W-step: W1[d_own, e] = W0 + N + sum_f W0[d,f] Mt[e,f]
        #pragma unroll
        for (int n = 0; n < 4; ++n) {
            short8 m0 = *(const short8*)(tb + (size_t)(16 * n + lr) * 64 + lk);
            short8 m1 = *(const short8*)(tb + (size_t)(16 * n + lr) * 64 + 32 + lk);
            f32x4 a;
            #pragma unroll
            for (int j = 0; j < 4; ++j)
                a[j] = Wf[(16 * w + rb + j) * 68 + 16 * n + lr]
                     + bf2f(tb[8192 + (size_t)(16 * w + rb + j) * 64 + 16 * n + lr]);
            a = __builtin_amdgcn_mfma_f32_16x16x32_bf16(wf0, m0, a, 0, 0, 0);
            a = __builtin_amdgcn_mfma_f32_16x16x32_bf16(wf1, m1, a, 0, 0, 0);
            #pragma unroll
            for (int j = 0; j < 4; ++j) Wf[(16 * w + rb + j) * 68 + 16 * n + lr] = a[j];
        }
    }
}

// ---------------- launch ----------------
extern "C" void kernel_launch(void* const* d_in, const int* in_sizes, int n_in,
                              void* d_out, int out_size, void* d_ws, size_t ws_size,
                              hipStream_t stream) {
    const float* x      = (const float*)d_in[0];
    const float* g      = (const float*)d_in[1];
    const float* be     = (const float*)d_in[2];
    const float* w_slow = (const float*)d_in[3];
    const float* w_out  = (const float*)d_in[4];
    float* out = (float*)d_out;
    char* ws = (char*)d_ws;

    unsigned short* h    = (unsigned short*)(ws);                 // 33.5 MB (dead after gemm_qkv)
    unsigned short* outs = (unsigned short*)(ws);                 // alias h
    unsigned short* qn   = (unsigned short*)(ws + 33554432);
    unsigned short* kn   = (unsigned short*)(ws + 67108864);
    unsigned short* vn   = (unsigned short*)(ws + 100663296);
    float*          bet  = (float*)         (ws + 134217728);
    unsigned short* wsT  = (unsigned short*)(ws + 135266304);
    unsigned short* woT  = (unsigned short*)(ws + 136970240);
    unsigned short* tiles= (unsigned short*)(ws + 137494528);     // 4096 * 24KB = 100.7 MB

    if (ws_size < 238157824) return;   // readable fail instead of fault

    ln_kernel<<<8192, 256, 0, stream>>>(x, g, be, h);
    cvt_wslow<<<(NPAD * 512) / 256, 256, 0, stream>>>(w_slow, wsT);
    cvt_wout<<<(512 * 512) / 256, 256, 0, stream>>>(w_out, woT);
    gemm_qkv<<<dim3(13, MROWS / 128), 256, 0, stream>>>(h, wsT, qn, kn, vn, bet);
    fwtiles<<<BSZ * H_ * 16, 256, 0, stream>>>(qn, kn, vn, bet, tiles, outs);
    fwscan<<<BSZ * H_, 256, 0, stream>>>(tiles, outs);
    gemm_out<<<dim3(4, MROWS / 128), 256, 0, stream>>>(outs, woT, x, out);
}

// Round 6
// 448.288 us; speedup vs baseline: 1.9486x; 1.0220x over previous
//
#include <hip/hip_runtime.h>
#include <cstdint>

using short8  = __attribute__((ext_vector_type(8))) short;
using ushort8 = __attribute__((ext_vector_type(8))) unsigned short;
using short4v = __attribute__((ext_vector_type(4))) short;
using f32x4   = __attribute__((ext_vector_type(4))) float;

#define H_    8
#define SLEN  1024
#define BSZ   32
#define INDIM 512
#define NQKV  1544   // H*(3*D+1)
#define NPAD  1664   // 13*128
#define MROWS 32768  // SLEN*BSZ
#define PB    72     // bf16 LDS pad stride

#define GLOAD16(gp, lp) __builtin_amdgcn_global_load_lds( \
    (const __attribute__((address_space(1))) void*)(gp),  \
    (__attribute__((address_space(3))) void*)(lp), 16, 0, 0)

static __device__ __forceinline__ float bf2f(unsigned short s) {
    return __uint_as_float(((unsigned int)s) << 16);
}
static __device__ __forceinline__ unsigned short f2bf(float f) {
    unsigned int u = __float_as_uint(f);
    u += 0x7FFFu + ((u >> 16) & 1u);
    return (unsigned short)(u >> 16);
}

// ---------------- LayerNorm: x[32768][512] f32 -> h bf16 ----------------
__global__ __launch_bounds__(256) void ln_kernel(const float* __restrict__ x,
                                                 const float* __restrict__ gamma,
                                                 const float* __restrict__ betap,
                                                 unsigned short* __restrict__ h) {
    int row = blockIdx.x * 4 + (threadIdx.x >> 6);
    int l   = threadIdx.x & 63;
    const f32x4* xr = (const f32x4*)(x + (size_t)row * INDIM);
    f32x4 a = xr[l * 2], b = xr[l * 2 + 1];
    float s = 0.f, sq = 0.f;
    #pragma unroll
    for (int j = 0; j < 4; ++j) { s += a[j]; sq += a[j] * a[j]; }
    #pragma unroll
    for (int j = 0; j < 4; ++j) { s += b[j]; sq += b[j] * b[j]; }
    #pragma unroll
    for (int off = 32; off; off >>= 1) { s += __shfl_xor(s, off); sq += __shfl_xor(sq, off); }
    float mean = s * (1.f / 512.f);
    float var  = sq * (1.f / 512.f) - mean * mean;
    float rstd = rsqrtf(var + 1e-5f);
    const f32x4* g4 = (const f32x4*)gamma;
    const f32x4* b4 = (const f32x4*)betap;
    f32x4 g0 = g4[l * 2], g1 = g4[l * 2 + 1], e0 = b4[l * 2], e1 = b4[l * 2 + 1];
    short8 o;
    #pragma unroll
    for (int j = 0; j < 4; ++j) o[j]     = (short)f2bf((a[j] - mean) * rstd * g0[j] + e0[j]);
    #pragma unroll
    for (int j = 0; j < 4; ++j) o[4 + j] = (short)f2bf((b[j] - mean) * rstd * g1[j] + e1[j]);
    ((short8*)(h + (size_t)row * INDIM))[l] = o;
}

// ---------------- weight transpose+permute ----------------
__global__ __launch_bounds__(256) void cvt_wslow(const float* __restrict__ w,
                                                 unsigned short* __restrict__ wT) {
    int idx = blockIdx.x * 256 + threadIdx.x;
    int n = idx >> 9, k = idx & 511;
    int c;
    if (n < 512)       c = (n >> 6) * 193 + (n & 63);
    else if (n < 1024) c = ((n - 512) >> 6) * 193 + 64 + (n & 63);
    else if (n < 1536) c = ((n - 1024) >> 6) * 193 + 128 + (n & 63);
    else if (n < 1544) c = (n - 1536) * 193 + 192;
    else               c = -1;
    wT[idx] = (c >= 0) ? f2bf(w[(size_t)k * NQKV + c]) : (unsigned short)0;
}
__global__ __launch_bounds__(256) void cvt_wout(const float* __restrict__ w,
                                                unsigned short* __restrict__ wT) {
    int idx = blockIdx.x * 256 + threadIdx.x;
    int n = idx >> 9, k = idx & 511;
    wT[idx] = f2bf(w[(size_t)k * 512 + n]);
}

// ---------------- GEMM1 fused: h @ wT^T -> elu+1/sumnorm q,k ; v ; sigmoid beta ----------------
__global__ __launch_bounds__(256) void gemm_qkv(const unsigned short* __restrict__ A,
                                                const unsigned short* __restrict__ BT,
                                                unsigned short* __restrict__ qn,
                                                unsigned short* __restrict__ kn,
                                                unsigned short* __restrict__ vn,
                                                float* __restrict__ bet) {
    __shared__ unsigned short As[128 * 64];
    __shared__ unsigned short Bs[128 * 64];
    const int t  = threadIdx.x;
    const int bx = blockIdx.x;
    const int n0 = bx * 128;
    const int m0 = blockIdx.y * 128;
    const int w = t >> 6, l = t & 63;
    const int wr = (w >> 1) * 64, wc = (w & 1) * 64;
    f32x4 acc[4][4] = {};
    for (int kt = 0; kt < INDIM; kt += 64) {
        __syncthreads();
        #pragma unroll
        for (int c = 0; c < 4; ++c) {
            int idx = c * 256 + t;
            int row = idx >> 3, kc2 = (idx & 7) * 8;
            int lb = (c * 256 + (t & 192)) * 8;   // wave-uniform LDS base (elements)
            GLOAD16(A  + (size_t)(m0 + row) * INDIM + kt + kc2, &As[lb]);
            GLOAD16(BT + (size_t)(n0 + row) * INDIM + kt + kc2, &Bs[lb]);
        }
        __syncthreads();
        #pragma unroll
        for (int kk = 0; kk < 2; ++kk) {
            const int kr = kk * 32 + (l >> 4) * 8;
            short8 af[4], bf[4];
            #pragma unroll
            for (int m = 0; m < 4; ++m) af[m] = *(const short8*)&As[(wr + m * 16 + (l & 15)) * 64 + kr];
            #pragma unroll
            for (int n = 0; n < 4; ++n) bf[n] = *(const short8*)&Bs[(wc + n * 16 + (l & 15)) * 64 + kr];
            #pragma unroll
            for (int m = 0; m < 4; ++m)
                #pragma unroll
                for (int n = 0; n < 4; ++n)
                    acc[m][n] = __builtin_amdgcn_mfma_f32_16x16x32_bf16(af[m], bf[n], acc[m][n], 0, 0, 0);
        }
    }
    const int g = l >> 4, cc = l & 15;
    const int colbase = n0 + wc;
    if (bx < 12) {
        const int reg  = colbase >> 9;
        const int head = (colbase >> 6) & 7;
        unsigned short* dst = (reg == 0) ? qn : (reg == 1) ? kn : vn;
        #pragma unroll
        for (int m = 0; m < 4; ++m) {
            #pragma unroll
            for (int j = 0; j < 4; ++j) {
                int row = m0 + wr + m * 16 + g * 4 + j;
                int s = row >> 5, b = row & 31;
                size_t base = ((size_t)(b * H_ + head) * SLEN + s) * 64;
                float e0 = acc[m][0][j], e1 = acc[m][1][j], e2 = acc[m][2][j], e3 = acc[m][3][j];
                if (reg < 2) {
                    e0 = e0 > 0.f ? e0 + 1.f : __expf(e0);
                    e1 = e1 > 0.f ? e1 + 1.f : __expf(e1);
                    e2 = e2 > 0.f ? e2 + 1.f : __expf(e2);
                    e3 = e3 > 0.f ? e3 + 1.f : __expf(e3);
                    float ssum = (e0 + e1) + (e2 + e3);
                    ssum += __shfl_xor(ssum, 1);
                    ssum += __shfl_xor(ssum, 2);
                    ssum += __shfl_xor(ssum, 4);
                    ssum += __shfl_xor(ssum, 8);
                    float inv = 1.f / ssum;
                    e0 *= inv; e1 *= inv; e2 *= inv; e3 *= inv;
                }
                dst[base +  0 + cc] = f2bf(e0);
                dst[base + 16 + cc] = f2bf(e1);
                dst[base + 32 + cc] = f2bf(e2);
                dst[base + 48 + cc] = f2bf(e3);
            }
        }
    } else {
        if (wc == 0 && cc < 8) {
            #pragma unroll
            for (int m = 0; m < 4; ++m)
                #pragma unroll
                for (int j = 0; j < 4; ++j) {
                    int row = m0 + wr + m * 16 + g * 4 + j;
                    int s = row >> 5, b = row & 31;
                    float v = acc[m][0][j];
                    bet[(size_t)(b * H_ + cc) * SLEN + s] = 1.f / (1.f + __expf(-v));
                }
        }
    }
}

// ---------------- GEMM2: out = x + outs @ woT^T ----------------
__global__ __launch_bounds__(256) void gemm_out(const unsigned short* __restrict__ A,
                                                const unsigned short* __restrict__ BT,
                                                const float* __restrict__ X,
                                                float* __restrict__ outf) {
    __shared__ unsigned short As[128 * 64];
    __shared__ unsigned short Bs[128 * 64];
    const int t  = threadIdx.x;
    const int n0 = blockIdx.x * 128;
    const int m0 = blockIdx.y * 128;
    const int w = t >> 6, l = t & 63;
    const int wr = (w >> 1) * 64, wc = (w & 1) * 64;
    f32x4 acc[4][4] = {};
    for (int kt = 0; kt < INDIM; kt += 64) {
        __syncthreads();
        #pragma unroll
        for (int c = 0; c < 4; ++c) {
            int idx = c * 256 + t;
            int row = idx >> 3, kc2 = (idx & 7) * 8;
            int lb = (c * 256 + (t & 192)) * 8;
            GLOAD16(A  + (size_t)(m0 + row) * INDIM + kt + kc2, &As[lb]);
            GLOAD16(BT + (size_t)(n0 + row) * INDIM + kt + kc2, &Bs[lb]);
        }
        __syncthreads();
        #pragma unroll
        for (int kk = 0; kk < 2; ++kk) {
            const int kr = kk * 32 + (l >> 4) * 8;
            short8 af[4], bf[4];
            #pragma unroll
            for (int m = 0; m < 4; ++m) af[m] = *(const short8*)&As[(wr + m * 16 + (l & 15)) * 64 + kr];
            #pragma unroll
            for (int n = 0; n < 4; ++n) bf[n] = *(const short8*)&Bs[(wc + n * 16 + (l & 15)) * 64 + kr];
            #pragma unroll
            for (int m = 0; m < 4; ++m)
                #pragma unroll
                for (int n = 0; n < 4; ++n)
                    acc[m][n] = __builtin_amdgcn_mfma_f32_16x16x32_bf16(af[m], bf[n], acc[m][n], 0, 0, 0);
        }
    }
    const int rb = (l >> 4) * 4, cc = l & 15;
    #pragma unroll
    for (int m = 0; m < 4; ++m)
        #pragma unroll
        for (int n = 0; n < 4; ++n)
            #pragma unroll
            for (int j = 0; j < 4; ++j) {
                int row = m0 + wr + m * 16 + rb + j;
                int col = n0 + wc + n * 16 + cc;
                size_t o = (size_t)row * 512 + col;
                outf[o] = X[o] + acc[m][n][j];
            }
}

// ---------------- phase 1 v2: per-(bh,chunk) WY tile factors, 8 waves ----------------
// Z = [bV | -bK]^T (tr, bf16); nilpotent-doubling solve of (I+A)^{-1};
// emit Mt = -K^T Bk, G = Q - P Bk, N = Bv^T K (bf16 tiles) and PBv -> outs (O-acc init).
__global__ __launch_bounds__(512, 4) void fwtiles(const unsigned short* __restrict__ qn,
                                                  const unsigned short* __restrict__ kn,
                                                  const unsigned short* __restrict__ vn,
                                                  const float* __restrict__ beta,
                                                  unsigned short* __restrict__ tiles,
                                                  unsigned short* __restrict__ outs) {
    __shared__ unsigned short Ax[64 * PB], Atr[64 * PB], Pw[64 * PB], Pwtr[64 * PB];
    __shared__ unsigned short Z0[128 * PB], Z1[128 * PB];
    __shared__ float bv[64];
    const int bx = blockIdx.x;
    const int bh = bx >> 4, c = bx & 15;
    const int b = bh >> 3, h = bh & 7;
    const int c0 = c * 64;
    const int tid = threadIdx.x;
    const int w = tid >> 6, l = tid & 63;
    const int mw = w & 3, nh = w >> 2;
    const int lr = l & 15, lk = (l >> 4) << 3, rb = (l >> 4) << 2;
    const unsigned short* kc = kn + ((size_t)bh * SLEN + c0) * 64;
    const unsigned short* qc = qn + ((size_t)bh * SLEN + c0) * 64;
    const unsigned short* vc = vn + ((size_t)bh * SLEN + c0) * 64;
    const float* bb = beta + (size_t)bh * SLEN + c0;

    // ---- Part A: Z1 <- [V rows 0..63 | K rows 64..127] row-major (coalesced); bv; zero Ax/Atr ----
    {
        #pragma unroll
        for (int i = 0; i < 2; ++i) {
            int idx = i * 512 + tid;          // 0..1023
            int row = idx >> 3, seg = idx & 7;
            const unsigned short* src = (row < 64) ? (vc + (size_t)row * 64 + seg * 8)
                                                   : (kc + (size_t)(row - 64) * 64 + seg * 8);
            *(ushort8*)&Z1[row * PB + seg * 8] = *(const ushort8*)src;
        }
        if (tid < 64) bv[tid] = bb[tid];
        ushort8 z8 = {};
        for (int i = tid; i < 576; i += 512) { ((ushort8*)Ax)[i] = z8; ((ushort8*)Atr)[i] = z8; }
    }
    __syncthreads();

    auto ldb = [&](const unsigned short* M, int m, int kk) -> short8 {
        return *(const short8*)&M[(m * 16 + lr) * PB + kk * 32 + lk];
    };

    // ---- Part B: Z0 <- scaled transpose of Z1 ----
    {
        int dz = tid >> 2, seg = tid & 3;
        int dcol = dz & 63;
        int zoff = (dz & 64) ? 64 : 0;
        float sgn = (dz & 64) ? -1.f : 1.f;
        ushort8 o0, o1;
        #pragma unroll
        for (int j = 0; j < 8; ++j) {
            int tt = seg * 16 + j;
            o0[j] = f2bf(sgn * bv[tt] * bf2f(Z1[(zoff + tt) * PB + dcol]));
        }
        #pragma unroll
        for (int j = 8; j < 16; ++j) {
            int tt = seg * 16 + j;
            o1[j - 8] = f2bf(sgn * bv[tt] * bf2f(Z1[(zoff + tt) * PB + dcol]));
        }
        *(ushort8*)&Z0[dz * PB + seg * 16]     = o0;
        *(ushort8*)&Z0[dz * PB + seg * 16 + 8] = o1;
    }
    // ---- S1: A = -b_t * tril(K K^T, s<t) from Z1 K-rows (10 pairs over 8 waves) ----
    {
        const int pm[10] = {0, 1, 1, 2, 2, 2, 3, 3, 3, 3};
        const int pn[10] = {0, 0, 1, 0, 1, 2, 0, 1, 2, 3};
        for (int pi = w; pi < 10; pi += 8) {
            int m = pm[pi], n = pn[pi];
            short8 ka0 = *(const short8*)&Z1[(64 + 16 * m + lr) * PB + lk];
            short8 ka1 = *(const short8*)&Z1[(64 + 16 * m + lr) * PB + 32 + lk];
            short8 kb0 = *(const short8*)&Z1[(64 + 16 * n + lr) * PB + lk];
            short8 kb1 = *(const short8*)&Z1[(64 + 16 * n + lr) * PB + 32 + lk];
            f32x4 a = {};
            a = __builtin_amdgcn_mfma_f32_16x16x32_bf16(ka0, kb0, a, 0, 0, 0);
            a = __builtin_amdgcn_mfma_f32_16x16x32_bf16(ka1, kb1, a, 0, 0, 0);
            f32x4 btm = *(const f32x4*)&bv[16 * m + rb];
            short4v pk;
            #pragma unroll
            for (int j = 0; j < 4; ++j) {
                int tt = 16 * m + rb + j, s = 16 * n + lr;
                unsigned short v = (s < tt) ? f2bf(-btm[j] * a[j]) : (unsigned short)0;
                Ax[tt * PB + s] = v;
                pk[j] = (short)v;
            }
            *(short4v*)&Atr[(16 * n + lr) * PB + 16 * m + rb] = pk;
        }
    }
    __syncthreads();

    // Zd = Zs + X^p * Zs  (wave: m-quad mw, n-rows nh*4..+3)
    auto zprod = [&](const unsigned short* Xb, int p, const unsigned short* Zs, unsigned short* Zd) {
        const bool msk0 = (16 * mw + 15 >= p), msk1 = (16 * mw + 15 - 32 >= p);
        short8 xf0, xf1;
        if (msk0) xf0 = ldb(Xb, mw, 0);
        if (msk1) xf1 = ldb(Xb, mw, 1);
        #pragma unroll
        for (int ni = 0; ni < 4; ++ni) {
            int n = nh * 4 + ni;
            short4v zi = *(const short4v*)&Zs[(16 * n + lr) * PB + 16 * mw + rb];
            f32x4 a;
            #pragma unroll
            for (int j = 0; j < 4; ++j) a[j] = bf2f((unsigned short)zi[j]);
            if (msk0) a = __builtin_amdgcn_mfma_f32_16x16x32_bf16(xf0, ldb(Zs, n, 0), a, 0, 0, 0);
            if (msk1) a = __builtin_amdgcn_mfma_f32_16x16x32_bf16(xf1, ldb(Zs, n, 1), a, 0, 0, 0);
            short4v zo;
            #pragma unroll
            for (int j = 0; j < 4; ++j) zo[j] = (short)f2bf(a[j]);
            *(short4v*)&Zd[(16 * n + lr) * PB + 16 * mw + rb] = zo;
        }
    };
    // Pd = Ps * Ps  (wave: m = mw, n = nh*2 + {0,1}); writes row + tr incl. zeros
    auto powp = [&](const unsigned short* Ps, const unsigned short* Pstr, int p,
                    unsigned short* Pd, unsigned short* Pdtr) {
        const bool x0 = (16 * mw + 15 >= p), x1 = (16 * mw + 15 - 32 >= p);
        short8 xf0, xf1;
        if (x0) xf0 = ldb(Ps, mw, 0);
        if (x1) xf1 = ldb(Ps, mw, 1);
        #pragma unroll
        for (int ni = 0; ni < 2; ++ni) {
            int n = nh * 2 + ni;
            const bool y0 = (31 - 16 * n >= p), y1 = (63 - 16 * n >= p);
            f32x4 a = {};
            if (x0 && y0) a = __builtin_amdgcn_mfma_f32_16x16x32_bf16(xf0, ldb(Pstr, n, 0), a, 0, 0, 0);
            if (x1 && y1) a = __builtin_amdgcn_mfma_f32_16x16x32_bf16(xf1, ldb(Pstr, n, 1), a, 0, 0, 0);
            short4v pk;
            #pragma unroll
            for (int j = 0; j < 4; ++j) {
                unsigned short v = f2bf(a[j]);
                Pd[(16 * mw + rb + j) * PB + 16 * n + lr] = v;
                pk[j] = (short)v;
            }
            *(short4v*)&Pdtr[(16 * n + lr) * PB + 16 * mw + rb] = pk;
        }
    };

    zprod(Ax, 1, Z0, Z1);  powp(Ax, Atr, 1, Pw, Pwtr);  __syncthreads();
    zprod(Pw, 2, Z1, Z0);  powp(Pw, Pwtr, 2, Ax, Atr);  __syncthreads();
    zprod(Ax, 4, Z0, Z1);  powp(Ax, Atr, 4, Pw, Pwtr);  __syncthreads();
    zprod(Pw, 8, Z1, Z0);  powp(Pw, Pwtr, 8, Ax, Atr);  __syncthreads();
    zprod(Ax, 16, Z0, Z1); powp(Ax, Atr, 16, Pw, Pwtr); __syncthreads();
    zprod(Pw, 32, Z1, Z0);
    __syncthreads();
    // Z0 rows 0..63 = Bv^T, rows 64..127 = (-Bk)^T

    // ---- re-stage Z1 <- [Q rows 0..63 | K rows 64..127] row-major (L2-hot) ----
    {
        #pragma unroll
        for (int i = 0; i < 2; ++i) {
            int idx = i * 512 + tid;
            int row = idx >> 3, seg = idx & 7;
            const unsigned short* src = (row < 64) ? (qc + (size_t)row * 64 + seg * 8)
                                                   : (kc + (size_t)(row - 64) * 64 + seg * 8);
            *(ushort8*)&Z1[row * PB + seg * 8] = *(const ushort8*)src;
        }
    }
    __syncthreads();

    // ---- S8: P = tril(Q K^T, incl) -> Ax ----
    {
        short8 qa0 = *(const short8*)&Z1[(16 * mw + lr) * PB + lk];
        short8 qa1 = *(const short8*)&Z1[(16 * mw + lr) * PB + 32 + lk];
        #pragma unroll
        for (int ni = 0; ni < 2; ++ni) {
            int n = nh * 2 + ni;
            short8 kb0 = *(const short8*)&Z1[(64 + 16 * n + lr) * PB + lk];
            short8 kb1 = *(const short8*)&Z1[(64 + 16 * n + lr) * PB + 32 + lk];
            f32x4 a = {};
            a = __builtin_amdgcn_mfma_f32_16x16x32_bf16(qa0, kb0, a, 0, 0, 0);
            a = __builtin_amdgcn_mfma_f32_16x16x32_bf16(qa1, kb1, a, 0, 0, 0);
            #pragma unroll
            for (int j = 0; j < 4; ++j) {
                int tt = 16 * mw + rb + j, s = 16 * n + lr;
                Ax[tt * PB + s] = (s <= tt) ? f2bf(a[j]) : (unsigned short)0;
            }
        }
    }
    __syncthreads();

    // ---- S9: outputs (Mt | G | N -> tiles; PBv -> outs) ----
    {
        unsigned short* tb = tiles + ((size_t)bh * 16 + c) * 12288;
        auto ktr = [&](int e, int kk) -> short8 {   // K^T rows e-block, k = t (LDS gather, ~4-way)
            short8 r;
            #pragma unroll
            for (int j = 0; j < 8; ++j)
                r[j] = (short)Z1[(64 + kk * 32 + lk + j) * PB + 16 * e + lr];
            return r;
        };
        short8 pA0 = ldb(Ax, mw, 0), pA1 = ldb(Ax, mw, 1);
        short8 zA0 = ldb(Z0, mw, 0), zA1 = ldb(Z0, mw, 1);
        short8 kt0 = ktr(mw, 0), kt1 = ktr(mw, 1);
        #pragma unroll
        for (int ni = 0; ni < 2; ++ni) {
            int n = nh * 2 + ni;
            f32x4 aN = {};
            aN = __builtin_amdgcn_mfma_f32_16x16x32_bf16(zA0, ktr(n, 0), aN, 0, 0, 0);
            aN = __builtin_amdgcn_mfma_f32_16x16x32_bf16(zA1, ktr(n, 1), aN, 0, 0, 0);
            f32x4 aM = {};
            aM = __builtin_amdgcn_mfma_f32_16x16x32_bf16(kt0, ldb(Z0, 4 + n, 0), aM, 0, 0, 0);
            aM = __builtin_amdgcn_mfma_f32_16x16x32_bf16(kt1, ldb(Z0, 4 + n, 1), aM, 0, 0, 0);
            f32x4 aG;
            #pragma unroll
            for (int j = 0; j < 4; ++j) aG[j] = bf2f(Z1[(16 * mw + rb + j) * PB + 16 * n + lr]);
            aG = __builtin_amdgcn_mfma_f32_16x16x32_bf16(pA0, ldb(Z0, 4 + n, 0), aG, 0, 0, 0);
            aG = __builtin_amdgcn_mfma_f32_16x16x32_bf16(pA1, ldb(Z0, 4 + n, 1), aG, 0, 0, 0);
            f32x4 aP = {};
            aP = __builtin_amdgcn_mfma_f32_16x16x32_bf16(pA0, ldb(Z0, n, 0), aP, 0, 0, 0);
            aP = __builtin_amdgcn_mfma_f32_16x16x32_bf16(pA1, ldb(Z0, n, 1), aP, 0, 0, 0);
            #pragma unroll
            for (int j = 0; j < 4; ++j) {
                int r = 16 * mw + rb + j, cl = 16 * n + lr;
                tb[r * 64 + cl]        = f2bf(aM[j]);
                tb[4096 + r * 64 + cl] = f2bf(aG[j]);
                tb[8192 + r * 64 + cl] = f2bf(aN[j]);
                outs[((size_t)(c0 + r) * BSZ + b) * 512 + h * 64 + cl] = f2bf(aP[j]);
            }
        }
    }
}

// ---------------- phase 2: W scan + O finalize (4 independent waves, no barriers) ----------------
__global__ __launch_bounds__(256) void fwscan(const unsigned short* __restrict__ tiles,
                                              unsigned short* __restrict__ outs) {
    __shared__ float Wf[64 * 68];
    const int bh = blockIdx.x;
    const int b = bh >> 3, h = bh & 7;
    const int tid = threadIdx.x;
    const int w = tid >> 6, l = tid & 63;
    const int lr = l & 15, lk = (l >> 4) << 3, rb = (l >> 4) << 2;
    #pragma unroll
    for (int j = 0; j < 16; ++j) Wf[(16 * w + j) * 68 + l] = 0.f;

    for (int c = 0; c < 16; ++c) {
        const int c0 = c * 64;
        const unsigned short* tb = tiles + ((size_t)bh * 16 + c) * 12288;
        short8 wf0, wf1;
        {
            const float* p0 = &Wf[(16 * w + lr) * 68 + lk];
            f32x4 a0 = *(const f32x4*)p0, b0 = *(const f32x4*)(p0 + 4);
            f32x4 a1 = *(const f32x4*)(p0 + 32), b1 = *(const f32x4*)(p0 + 36);
            #pragma unroll
            for (int j = 0; j < 4; ++j) {
                wf0[j] = (short)f2bf(a0[j]); wf0[4 + j] = (short)f2bf(b0[j]);
                wf1[j] = (short)f2bf(a1[j]); wf1[4 + j] = (short)f2bf(b1[j]);
            }
        }
        #pragma unroll
        for (int m = 0; m < 4; ++m) {
            short8 g0 = *(const short8*)(tb + 4096 + (size_t)(16 * m + lr) * 64 + lk);
            short8 g1 = *(const short8*)(tb + 4096 + (size_t)(16 * m + lr) * 64 + 32 + lk);
            size_t ob = ((size_t)(c0 + 16 * m + rb) * BSZ + b) * 512 + h * 64 + 16 * w + lr;
            f32x4 a;
            #pragma unroll
            for (int j = 0; j < 4; ++j) a[j] = bf2f(outs[ob + (size_t)j * 16384]);
            a = __builtin_amdgcn_mfma_f32_16x16x32_bf16(g0, wf0, a, 0, 0, 0);
            a = __builtin_amdgcn_mfma_f32_16x16x32_bf16(g1, wf1, a, 0, 0, 0);
            #pragma unroll
            for (int j = 0; j < 4; ++j) outs[ob + (size_t)j * 16384] = f2bf(a[j]);
        }
        #pragma unroll
        for (int n = 0; n < 4; ++n) {
            short8 m0 = *(const short8*)(tb + (size_t)(16 * n + lr) * 64 + lk);
            short8 m1 = *(const short8*)(tb + (size_t)(16 * n + lr) * 64 + 32 + lk);
            f32x4 a;
            #pragma unroll
            for (int j = 0; j < 4; ++j)
                a[j] = Wf[(16 * w + rb + j) * 68 + 16 * n + lr]
                     + bf2f(tb[8192 + (size_t)(16 * w + rb + j) * 64 + 16 * n + lr]);
            a = __builtin_amdgcn_mfma_f32_16x16x32_bf16(wf0, m0, a, 0, 0, 0);
            a = __builtin_amdgcn_mfma_f32_16x16x32_bf16(wf1, m1, a, 0, 0, 0);
            #pragma unroll
            for (int j = 0; j < 4; ++j) Wf[(16 * w + rb + j) * 68 + 16 * n + lr] = a[j];
        }
    }
}

// ---------------- launch ----------------
extern "C" void kernel_launch(void* const* d_in, const int* in_sizes, int n_in,
                              void* d_out, int out_size, void* d_ws, size_t ws_size,
                              hipStream_t stream) {
    const float* x      = (const float*)d_in[0];
    const float* g      = (const float*)d_in[1];
    const float* be     = (const float*)d_in[2];
    const float* w_slow = (const float*)d_in[3];
    const float* w_out  = (const float*)d_in[4];
    float* out = (float*)d_out;
    char* ws = (char*)d_ws;

    unsigned short* h    = (unsigned short*)(ws);                 // 33.5 MB (dead after gemm_qkv)
    unsigned short* outs = (unsigned short*)(ws);                 // alias h
    unsigned short* qn   = (unsigned short*)(ws + 33554432);
    unsigned short* kn   = (unsigned short*)(ws + 67108864);
    unsigned short* vn   = (unsigned short*)(ws + 100663296);
    float*          bet  = (float*)         (ws + 134217728);
    unsigned short* wsT  = (unsigned short*)(ws + 135266304);
    unsigned short* woT  = (unsigned short*)(ws + 136970240);
    unsigned short* tiles= (unsigned short*)(ws + 137494528);     // 4096 * 24KB

    if (ws_size < 238157824) return;

    ln_kernel<<<8192, 256, 0, stream>>>(x, g, be, h);
    cvt_wslow<<<(NPAD * 512) / 256, 256, 0, stream>>>(w_slow, wsT);
    cvt_wout<<<(512 * 512) / 256, 256, 0, stream>>>(w_out, woT);
    gemm_qkv<<<dim3(13, MROWS / 128), 256, 0, stream>>>(h, wsT, qn, kn, vn, bet);
    fwtiles<<<BSZ * H_ * 16, 512, 0, stream>>>(qn, kn, vn, bet, tiles, outs);
    fwscan<<<BSZ * H_, 256, 0, stream>>>(tiles, outs);
    gemm_out<<<dim3(4, MROWS / 128), 256, 0, stream>>>(outs, woT, x, out);
}

// Round 8
// 362.988 us; speedup vs baseline: 2.4065x; 1.2350x over previous
//
#include <hip/hip_runtime.h>
#include <cstdint>

using short8  = __attribute__((ext_vector_type(8))) short;
using ushort8 = __attribute__((ext_vector_type(8))) unsigned short;
using short4v = __attribute__((ext_vector_type(4))) short;
using f32x4   = __attribute__((ext_vector_type(4))) float;

#define H_    8
#define SLEN  1024
#define BSZ   32
#define INDIM 512
#define NQKV  1544   // H*(3*D+1)
#define NPAD  1664   // 13*128
#define MROWS 32768  // SLEN*BSZ
#define PB    72     // bf16 LDS pad stride

#define GLOAD16(gp, lp) __builtin_amdgcn_global_load_lds( \
    (const __attribute__((address_space(1))) void*)(gp),  \
    (__attribute__((address_space(3))) void*)(lp), 16, 0, 0)

static __device__ __forceinline__ float bf2f(unsigned short s) {
    return __uint_as_float(((unsigned int)s) << 16);
}
static __device__ __forceinline__ unsigned short f2bf(float f) {
    unsigned int u = __float_as_uint(f);
    u += 0x7FFFu + ((u >> 16) & 1u);
    return (unsigned short)(u >> 16);
}

// ---------------- LayerNorm: x[32768][512] f32 -> h bf16 ----------------
__global__ __launch_bounds__(256) void ln_kernel(const float* __restrict__ x,
                                                 const float* __restrict__ gamma,
                                                 const float* __restrict__ betap,
                                                 unsigned short* __restrict__ h) {
    int row = blockIdx.x * 4 + (threadIdx.x >> 6);
    int l   = threadIdx.x & 63;
    const f32x4* xr = (const f32x4*)(x + (size_t)row * INDIM);
    f32x4 a = xr[l * 2], b = xr[l * 2 + 1];
    float s = 0.f, sq = 0.f;
    #pragma unroll
    for (int j = 0; j < 4; ++j) { s += a[j]; sq += a[j] * a[j]; }
    #pragma unroll
    for (int j = 0; j < 4; ++j) { s += b[j]; sq += b[j] * b[j]; }
    #pragma unroll
    for (int off = 32; off; off >>= 1) { s += __shfl_xor(s, off); sq += __shfl_xor(sq, off); }
    float mean = s * (1.f / 512.f);
    float var  = sq * (1.f / 512.f) - mean * mean;
    float rstd = rsqrtf(var + 1e-5f);
    const f32x4* g4 = (const f32x4*)gamma;
    const f32x4* b4 = (const f32x4*)betap;
    f32x4 g0 = g4[l * 2], g1 = g4[l * 2 + 1], e0 = b4[l * 2], e1 = b4[l * 2 + 1];
    short8 o;
    #pragma unroll
    for (int j = 0; j < 4; ++j) o[j]     = (short)f2bf((a[j] - mean) * rstd * g0[j] + e0[j]);
    #pragma unroll
    for (int j = 0; j < 4; ++j) o[4 + j] = (short)f2bf((b[j] - mean) * rstd * g1[j] + e1[j]);
    ((short8*)(h + (size_t)row * INDIM))[l] = o;
}

// ---------------- weight transpose+permute ----------------
__global__ __launch_bounds__(256) void cvt_wslow(const float* __restrict__ w,
                                                 unsigned short* __restrict__ wT) {
    int idx = blockIdx.x * 256 + threadIdx.x;
    int n = idx >> 9, k = idx & 511;
    int c;
    if (n < 512)       c = (n >> 6) * 193 + (n & 63);
    else if (n < 1024) c = ((n - 512) >> 6) * 193 + 64 + (n & 63);
    else if (n < 1536) c = ((n - 1024) >> 6) * 193 + 128 + (n & 63);
    else if (n < 1544) c = (n - 1536) * 193 + 192;
    else               c = -1;
    wT[idx] = (c >= 0) ? f2bf(w[(size_t)k * NQKV + c]) : (unsigned short)0;
}
__global__ __launch_bounds__(256) void cvt_wout(const float* __restrict__ w,
                                                unsigned short* __restrict__ wT) {
    int idx = blockIdx.x * 256 + threadIdx.x;
    int n = idx >> 9, k = idx & 511;
    wT[idx] = f2bf(w[(size_t)k * 512 + n]);
}

// ---------------- GEMM1 fused: h @ wT^T -> elu+1/sumnorm q,k ; v ; sigmoid beta ----------------
__global__ __launch_bounds__(256) void gemm_qkv(const unsigned short* __restrict__ A,
                                                const unsigned short* __restrict__ BT,
                                                unsigned short* __restrict__ qn,
                                                unsigned short* __restrict__ kn,
                                                unsigned short* __restrict__ vn,
                                                float* __restrict__ bet) {
    __shared__ unsigned short As[128 * 64];
    __shared__ unsigned short Bs[128 * 64];
    const int t  = threadIdx.x;
    const int bx = blockIdx.x;
    const int n0 = bx * 128;
    const int m0 = blockIdx.y * 128;
    const int w = t >> 6, l = t & 63;
    const int wr = (w >> 1) * 64, wc = (w & 1) * 64;
    f32x4 acc[4][4] = {};
    for (int kt = 0; kt < INDIM; kt += 64) {
        __syncthreads();
        #pragma unroll
        for (int c = 0; c < 4; ++c) {
            int idx = c * 256 + t;
            int row = idx >> 3, kc2 = (idx & 7) * 8;
            int lb = (c * 256 + (t & 192)) * 8;   // wave-uniform LDS base (elements)
            GLOAD16(A  + (size_t)(m0 + row) * INDIM + kt + kc2, &As[lb]);
            GLOAD16(BT + (size_t)(n0 + row) * INDIM + kt + kc2, &Bs[lb]);
        }
        __syncthreads();
        #pragma unroll
        for (int kk = 0; kk < 2; ++kk) {
            const int kr = kk * 32 + (l >> 4) * 8;
            short8 af[4], bf[4];
            #pragma unroll
            for (int m = 0; m < 4; ++m) af[m] = *(const short8*)&As[(wr + m * 16 + (l & 15)) * 64 + kr];
            #pragma unroll
            for (int n = 0; n < 4; ++n) bf[n] = *(const short8*)&Bs[(wc + n * 16 + (l & 15)) * 64 + kr];
            #pragma unroll
            for (int m = 0; m < 4; ++m)
                #pragma unroll
                for (int n = 0; n < 4; ++n)
                    acc[m][n] = __builtin_amdgcn_mfma_f32_16x16x32_bf16(af[m], bf[n], acc[m][n], 0, 0, 0);
        }
    }
    const int g = l >> 4, cc = l & 15;
    const int colbase = n0 + wc;
    if (bx < 12) {
        const int reg  = colbase >> 9;
        const int head = (colbase >> 6) & 7;
        unsigned short* dst = (reg == 0) ? qn : (reg == 1) ? kn : vn;
        #pragma unroll
        for (int m = 0; m < 4; ++m) {
            #pragma unroll
            for (int j = 0; j < 4; ++j) {
                int row = m0 + wr + m * 16 + g * 4 + j;
                int s = row >> 5, b = row & 31;
                size_t base = ((size_t)(b * H_ + head) * SLEN + s) * 64;
                float e0 = acc[m][0][j], e1 = acc[m][1][j], e2 = acc[m][2][j], e3 = acc[m][3][j];
                if (reg < 2) {
                    e0 = e0 > 0.f ? e0 + 1.f : __expf(e0);
                    e1 = e1 > 0.f ? e1 + 1.f : __expf(e1);
                    e2 = e2 > 0.f ? e2 + 1.f : __expf(e2);
                    e3 = e3 > 0.f ? e3 + 1.f : __expf(e3);
                    float ssum = (e0 + e1) + (e2 + e3);
                    ssum += __shfl_xor(ssum, 1);
                    ssum += __shfl_xor(ssum, 2);
                    ssum += __shfl_xor(ssum, 4);
                    ssum += __shfl_xor(ssum, 8);
                    float inv = 1.f / ssum;
                    e0 *= inv; e1 *= inv; e2 *= inv; e3 *= inv;
                }
                dst[base +  0 + cc] = f2bf(e0);
                dst[base + 16 + cc] = f2bf(e1);
                dst[base + 32 + cc] = f2bf(e2);
                dst[base + 48 + cc] = f2bf(e3);
            }
        }
    } else {
        if (wc == 0 && cc < 8) {
            #pragma unroll
            for (int m = 0; m < 4; ++m)
                #pragma unroll
                for (int j = 0; j < 4; ++j) {
                    int row = m0 + wr + m * 16 + g * 4 + j;
                    int s = row >> 5, b = row & 31;
                    float v = acc[m][0][j];
                    bet[(size_t)(b * H_ + cc) * SLEN + s] = 1.f / (1.f + __expf(-v));
                }
        }
    }
}

// ---------------- GEMM2: out = x + outs @ woT^T ----------------
__global__ __launch_bounds__(256) void gemm_out(const unsigned short* __restrict__ A,
                                                const unsigned short* __restrict__ BT,
                                                const float* __restrict__ X,
                                                float* __restrict__ outf) {
    __shared__ unsigned short As[128 * 64];
    __shared__ unsigned short Bs[128 * 64];
    const int t  = threadIdx.x;
    const int n0 = blockIdx.x * 128;
    const int m0 = blockIdx.y * 128;
    const int w = t >> 6, l = t & 63;
    const int wr = (w >> 1) * 64, wc = (w & 1) * 64;
    f32x4 acc[4][4] = {};
    for (int kt = 0; kt < INDIM; kt += 64) {
        __syncthreads();
        #pragma unroll
        for (int c = 0; c < 4; ++c) {
            int idx = c * 256 + t;
            int row = idx >> 3, kc2 = (idx & 7) * 8;
            int lb = (c * 256 + (t & 192)) * 8;
            GLOAD16(A  + (size_t)(m0 + row) * INDIM + kt + kc2, &As[lb]);
            GLOAD16(BT + (size_t)(n0 + row) * INDIM + kt + kc2, &Bs[lb]);
        }
        __syncthreads();
        #pragma unroll
        for (int kk = 0; kk < 2; ++kk) {
            const int kr = kk * 32 + (l >> 4) * 8;
            short8 af[4], bf[4];
            #pragma unroll
            for (int m = 0; m < 4; ++m) af[m] = *(const short8*)&As[(wr + m * 16 + (l & 15)) * 64 + kr];
            #pragma unroll
            for (int n = 0; n < 4; ++n) bf[n] = *(const short8*)&Bs[(wc + n * 16 + (l & 15)) * 64 + kr];
            #pragma unroll
            for (int m = 0; m < 4; ++m)
                #pragma unroll
                for (int n = 0; n < 4; ++n)
                    acc[m][n] = __builtin_amdgcn_mfma_f32_16x16x32_bf16(af[m], bf[n], acc[m][n], 0, 0, 0);
        }
    }
    const int rb = (l >> 4) * 4, cc = l & 15;
    #pragma unroll
    for (int m = 0; m < 4; ++m)
        #pragma unroll
        for (int n = 0; n < 4; ++n)
            #pragma unroll
            for (int j = 0; j < 4; ++j) {
                int row = m0 + wr + m * 16 + rb + j;
                int col = n0 + wc + n * 16 + cc;
                size_t o = (size_t)row * 512 + col;
                outf[o] = X[o] + acc[m][n][j];
            }
}

// ---------------- phase 1 v2: per-(bh,chunk) WY tile factors, 8 waves ----------------
__global__ __launch_bounds__(512, 4) void fwtiles(const unsigned short* __restrict__ qn,
                                                  const unsigned short* __restrict__ kn,
                                                  const unsigned short* __restrict__ vn,
                                                  const float* __restrict__ beta,
                                                  unsigned short* __restrict__ tiles,
                                                  unsigned short* __restrict__ outs) {
    __shared__ unsigned short Ax[64 * PB], Atr[64 * PB], Pw[64 * PB], Pwtr[64 * PB];
    __shared__ unsigned short Z0[128 * PB], Z1[128 * PB];
    __shared__ float bv[64];
    const int bx = blockIdx.x;
    const int bh = bx >> 4, c = bx & 15;
    const int b = bh >> 3, h = bh & 7;
    const int c0 = c * 64;
    const int tid = threadIdx.x;
    const int w = tid >> 6, l = tid & 63;
    const int mw = w & 3, nh = w >> 2;
    const int lr = l & 15, lk = (l >> 4) << 3, rb = (l >> 4) << 2;
    const unsigned short* kc = kn + ((size_t)bh * SLEN + c0) * 64;
    const unsigned short* qc = qn + ((size_t)bh * SLEN + c0) * 64;
    const unsigned short* vc = vn + ((size_t)bh * SLEN + c0) * 64;
    const float* bb = beta + (size_t)bh * SLEN + c0;

    {
        #pragma unroll
        for (int i = 0; i < 2; ++i) {
            int idx = i * 512 + tid;
            int row = idx >> 3, seg = idx & 7;
            const unsigned short* src = (row < 64) ? (vc + (size_t)row * 64 + seg * 8)
                                                   : (kc + (size_t)(row - 64) * 64 + seg * 8);
            *(ushort8*)&Z1[row * PB + seg * 8] = *(const ushort8*)src;
        }
        if (tid < 64) bv[tid] = bb[tid];
        ushort8 z8 = {};
        for (int i = tid; i < 576; i += 512) { ((ushort8*)Ax)[i] = z8; ((ushort8*)Atr)[i] = z8; }
    }
    __syncthreads();

    auto ldb = [&](const unsigned short* M, int m, int kk) -> short8 {
        return *(const short8*)&M[(m * 16 + lr) * PB + kk * 32 + lk];
    };

    {
        int dz = tid >> 2, seg = tid & 3;
        int dcol = dz & 63;
        int zoff = (dz & 64) ? 64 : 0;
        float sgn = (dz & 64) ? -1.f : 1.f;
        ushort8 o0, o1;
        #pragma unroll
        for (int j = 0; j < 8; ++j) {
            int tt = seg * 16 + j;
            o0[j] = f2bf(sgn * bv[tt] * bf2f(Z1[(zoff + tt) * PB + dcol]));
        }
        #pragma unroll
        for (int j = 8; j < 16; ++j) {
            int tt = seg * 16 + j;
            o1[j - 8] = f2bf(sgn * bv[tt] * bf2f(Z1[(zoff + tt) * PB + dcol]));
        }
        *(ushort8*)&Z0[dz * PB + seg * 16]     = o0;
        *(ushort8*)&Z0[dz * PB + seg * 16 + 8] = o1;
    }
    {
        const int pm[10] = {0, 1, 1, 2, 2, 2, 3, 3, 3, 3};
        const int pn[10] = {0, 0, 1, 0, 1, 2, 0, 1, 2, 3};
        for (int pi = w; pi < 10; pi += 8) {
            int m = pm[pi], n = pn[pi];
            short8 ka0 = *(const short8*)&Z1[(64 + 16 * m + lr) * PB + lk];
            short8 ka1 = *(const short8*)&Z1[(64 + 16 * m + lr) * PB + 32 + lk];
            short8 kb0 = *(const short8*)&Z1[(64 + 16 * n + lr) * PB + lk];
            short8 kb1 = *(const short8*)&Z1[(64 + 16 * n + lr) * PB + 32 + lk];
            f32x4 a = {};
            a = __builtin_amdgcn_mfma_f32_16x16x32_bf16(ka0, kb0, a, 0, 0, 0);
            a = __builtin_amdgcn_mfma_f32_16x16x32_bf16(ka1, kb1, a, 0, 0, 0);
            f32x4 btm = *(const f32x4*)&bv[16 * m + rb];
            short4v pk;
            #pragma unroll
            for (int j = 0; j < 4; ++j) {
                int tt = 16 * m + rb + j, s = 16 * n + lr;
                unsigned short v = (s < tt) ? f2bf(-btm[j] * a[j]) : (unsigned short)0;
                Ax[tt * PB + s] = v;
                pk[j] = (short)v;
            }
            *(short4v*)&Atr[(16 * n + lr) * PB + 16 * m + rb] = pk;
        }
    }
    __syncthreads();

    auto zprod = [&](const unsigned short* Xb, int p, const unsigned short* Zs, unsigned short* Zd) {
        const bool msk0 = (16 * mw + 15 >= p), msk1 = (16 * mw + 15 - 32 >= p);
        short8 xf0, xf1;
        if (msk0) xf0 = ldb(Xb, mw, 0);
        if (msk1) xf1 = ldb(Xb, mw, 1);
        #pragma unroll
        for (int ni = 0; ni < 4; ++ni) {
            int n = nh * 4 + ni;
            short4v zi = *(const short4v*)&Zs[(16 * n + lr) * PB + 16 * mw + rb];
            f32x4 a;
            #pragma unroll
            for (int j = 0; j < 4; ++j) a[j] = bf2f((unsigned short)zi[j]);
            if (msk0) a = __builtin_amdgcn_mfma_f32_16x16x32_bf16(xf0, ldb(Zs, n, 0), a, 0, 0, 0);
            if (msk1) a = __builtin_amdgcn_mfma_f32_16x16x32_bf16(xf1, ldb(Zs, n, 1), a, 0, 0, 0);
            short4v zo;
            #pragma unroll
            for (int j = 0; j < 4; ++j) zo[j] = (short)f2bf(a[j]);
            *(short4v*)&Zd[(16 * n + lr) * PB + 16 * mw + rb] = zo;
        }
    };
    auto powp = [&](const unsigned short* Ps, const unsigned short* Pstr, int p,
                    unsigned short* Pd, unsigned short* Pdtr) {
        const bool x0 = (16 * mw + 15 >= p), x1 = (16 * mw + 15 - 32 >= p);
        short8 xf0, xf1;
        if (x0) xf0 = ldb(Ps, mw, 0);
        if (x1) xf1 = ldb(Ps, mw, 1);
        #pragma unroll
        for (int ni = 0; ni < 2; ++ni) {
            int n = nh * 2 + ni;
            const bool y0 = (31 - 16 * n >= p), y1 = (63 - 16 * n >= p);
            f32x4 a = {};
            if (x0 && y0) a = __builtin_amdgcn_mfma_f32_16x16x32_bf16(xf0, ldb(Pstr, n, 0), a, 0, 0, 0);
            if (x1 && y1) a = __builtin_amdgcn_mfma_f32_16x16x32_bf16(xf1, ldb(Pstr, n, 1), a, 0, 0, 0);
            short4v pk;
            #pragma unroll
            for (int j = 0; j < 4; ++j) {
                unsigned short v = f2bf(a[j]);
                Pd[(16 * mw + rb + j) * PB + 16 * n + lr] = v;
                pk[j] = (short)v;
            }
            *(short4v*)&Pdtr[(16 * n + lr) * PB + 16 * mw + rb] = pk;
        }
    };

    zprod(Ax, 1, Z0, Z1);  powp(Ax, Atr, 1, Pw, Pwtr);  __syncthreads();
    zprod(Pw, 2, Z1, Z0);  powp(Pw, Pwtr, 2, Ax, Atr);  __syncthreads();
    zprod(Ax, 4, Z0, Z1);  powp(Ax, Atr, 4, Pw, Pwtr);  __syncthreads();
    zprod(Pw, 8, Z1, Z0);  powp(Pw, Pwtr, 8, Ax, Atr);  __syncthreads();
    zprod(Ax, 16, Z0, Z1); powp(Ax, Atr, 16, Pw, Pwtr); __syncthreads();
    zprod(Pw, 32, Z1, Z0);
    __syncthreads();

    {
        #pragma unroll
        for (int i = 0; i < 2; ++i) {
            int idx = i * 512 + tid;
            int row = idx >> 3, seg = idx & 7;
            const unsigned short* src = (row < 64) ? (qc + (size_t)row * 64 + seg * 8)
                                                   : (kc + (size_t)(row - 64) * 64 + seg * 8);
            *(ushort8*)&Z1[row * PB + seg * 8] = *(const ushort8*)src;
        }
    }
    __syncthreads();

    {
        short8 qa0 = *(const short8*)&Z1[(16 * mw + lr) * PB + lk];
        short8 qa1 = *(const short8*)&Z1[(16 * mw + lr) * PB + 32 + lk];
        #pragma unroll
        for (int ni = 0; ni < 2; ++ni) {
            int n = nh * 2 + ni;
            short8 kb0 = *(const short8*)&Z1[(64 + 16 * n + lr) * PB + lk];
            short8 kb1 = *(const short8*)&Z1[(64 + 16 * n + lr) * PB + 32 + lk];
            f32x4 a = {};
            a = __builtin_amdgcn_mfma_f32_16x16x32_bf16(qa0, kb0, a, 0, 0, 0);
            a = __builtin_amdgcn_mfma_f32_16x16x32_bf16(qa1, kb1, a, 0, 0, 0);
            #pragma unroll
            for (int j = 0; j < 4; ++j) {
                int tt = 16 * mw + rb + j, s = 16 * n + lr;
                Ax[tt * PB + s] = (s <= tt) ? f2bf(a[j]) : (unsigned short)0;
            }
        }
    }
    __syncthreads();

    {
        unsigned short* tb = tiles + ((size_t)bh * 16 + c) * 12288;
        auto ktr = [&](int e, int kk) -> short8 {
            short8 r;
            #pragma unroll
            for (int j = 0; j < 8; ++j)
                r[j] = (short)Z1[(64 + kk * 32 + lk + j) * PB + 16 * e + lr];
            return r;
        };
        short8 pA0 = ldb(Ax, mw, 0), pA1 = ldb(Ax, mw, 1);
        short8 zA0 = ldb(Z0, mw, 0), zA1 = ldb(Z0, mw, 1);
        short8 kt0 = ktr(mw, 0), kt1 = ktr(mw, 1);
        #pragma unroll
        for (int ni = 0; ni < 2; ++ni) {
            int n = nh * 2 + ni;
            f32x4 aN = {};
            aN = __builtin_amdgcn_mfma_f32_16x16x32_bf16(zA0, ktr(n, 0), aN, 0, 0, 0);
            aN = __builtin_amdgcn_mfma_f32_16x16x32_bf16(zA1, ktr(n, 1), aN, 0, 0, 0);
            f32x4 aM = {};
            aM = __builtin_amdgcn_mfma_f32_16x16x32_bf16(kt0, ldb(Z0, 4 + n, 0), aM, 0, 0, 0);
            aM = __builtin_amdgcn_mfma_f32_16x16x32_bf16(kt1, ldb(Z0, 4 + n, 1), aM, 0, 0, 0);
            f32x4 aG;
            #pragma unroll
            for (int j = 0; j < 4; ++j) aG[j] = bf2f(Z1[(16 * mw + rb + j) * PB + 16 * n + lr]);
            aG = __builtin_amdgcn_mfma_f32_16x16x32_bf16(pA0, ldb(Z0, 4 + n, 0), aG, 0, 0, 0);
            aG = __builtin_amdgcn_mfma_f32_16x16x32_bf16(pA1, ldb(Z0, 4 + n, 1), aG, 0, 0, 0);
            f32x4 aP = {};
            aP = __builtin_amdgcn_mfma_f32_16x16x32_bf16(pA0, ldb(Z0, n, 0), aP, 0, 0, 0);
            aP = __builtin_amdgcn_mfma_f32_16x16x32_bf16(pA1, ldb(Z0, n, 1), aP, 0, 0, 0);
            #pragma unroll
            for (int j = 0; j < 4; ++j) {
                int r = 16 * mw + rb + j, cl = 16 * n + lr;
                tb[r * 64 + cl]        = f2bf(aM[j]);
                tb[4096 + r * 64 + cl] = f2bf(aG[j]);
                tb[8192 + r * 64 + cl] = f2bf(aN[j]);
                outs[((size_t)(c0 + r) * BSZ + b) * 512 + h * 64 + cl] = f2bf(aP[j]);
            }
        }
    }
}

// ---------------- phase 2a: W-only scan with register prefetch; stores bf16 W checkpoints ----------------
// 4 independent row-split waves, zero barriers. wchk[bh][c] = W state BEFORE chunk c.
__global__ __launch_bounds__(256) void fwscan_w(const unsigned short* __restrict__ tiles,
                                                unsigned short* __restrict__ wchk) {
    __shared__ float Wf[64 * 68];
    const int bh = blockIdx.x;
    const int tid = threadIdx.x;
    const int w = tid >> 6, l = tid & 63;
    const int lr = l & 15, lk = (l >> 4) << 3, rb = (l >> 4) << 2;
    const int cr = l >> 3, cc8 = (l & 7) * 8;   // checkpoint-store lane map (8 rows x 64 cols per pass)
    #pragma unroll
    for (int j = 0; j < 16; ++j) Wf[(16 * w + j) * 68 + l] = 0.f;

    const unsigned short* tb0 = tiles + (size_t)bh * 16 * 12288;
    unsigned short* wc0 = wchk + (size_t)bh * 16 * 4096;

    auto loadc = [&](short8 (&MT)[4][2], unsigned short (&NV)[4][4], int c) {
        const unsigned short* tb = tb0 + (size_t)c * 12288;
        #pragma unroll
        for (int n = 0; n < 4; ++n) {
            MT[n][0] = *(const short8*)(tb + (size_t)(16 * n + lr) * 64 + lk);
            MT[n][1] = *(const short8*)(tb + (size_t)(16 * n + lr) * 64 + 32 + lk);
            #pragma unroll
            for (int j = 0; j < 4; ++j)
                NV[n][j] = tb[8192 + (size_t)(16 * w + rb + j) * 64 + 16 * n + lr];
        }
    };
    auto stepc = [&](short8 (&MT)[4][2], unsigned short (&NV)[4][4], int c) {
        // store pre-update checkpoint: BOTH 8-row halves of this wave's 16-row slice
        #pragma unroll
        for (int half = 0; half < 2; ++half) {
            int row = 16 * w + half * 8 + cr;
            const float* p = &Wf[row * 68 + cc8];
            f32x4 x0 = *(const f32x4*)p, x1 = *(const f32x4*)(p + 4);
            ushort8 o;
            #pragma unroll
            for (int j = 0; j < 4; ++j) { o[j] = f2bf(x0[j]); o[4 + j] = f2bf(x1[j]); }
            *(ushort8*)(wc0 + (size_t)c * 4096 + row * 64 + cc8) = o;
        }
        // W0 A-frags (own rows)
        short8 wf0, wf1;
        {
            const float* p0 = &Wf[(16 * w + lr) * 68 + lk];
            f32x4 a0 = *(const f32x4*)p0, b0 = *(const f32x4*)(p0 + 4);
            f32x4 a1 = *(const f32x4*)(p0 + 32), b1 = *(const f32x4*)(p0 + 36);
            #pragma unroll
            for (int j = 0; j < 4; ++j) {
                wf0[j] = (short)f2bf(a0[j]); wf0[4 + j] = (short)f2bf(b0[j]);
                wf1[j] = (short)f2bf(a1[j]); wf1[4 + j] = (short)f2bf(b1[j]);
            }
        }
        // W1 = W0 + N + W0·Mt
        #pragma unroll
        for (int n = 0; n < 4; ++n) {
            f32x4 a;
            #pragma unroll
            for (int j = 0; j < 4; ++j)
                a[j] = Wf[(16 * w + rb + j) * 68 + 16 * n + lr] + bf2f(NV[n][j]);
            a = __builtin_amdgcn_mfma_f32_16x16x32_bf16(wf0, MT[n][0], a, 0, 0, 0);
            a = __builtin_amdgcn_mfma_f32_16x16x32_bf16(wf1, MT[n][1], a, 0, 0, 0);
            #pragma unroll
            for (int j = 0; j < 4; ++j) Wf[(16 * w + rb + j) * 68 + 16 * n + lr] = a[j];
        }
    };

    short8 mtA[4][2], mtB[4][2];
    unsigned short nvA[4][4], nvB[4][4];
    loadc(mtA, nvA, 0);
    #pragma unroll 1
    for (int cc = 0; cc < 8; ++cc) {
        int c = 2 * cc;
        if (c + 1 < 16) loadc(mtB, nvB, c + 1);
        stepc(mtA, nvA, c);
        if (c + 2 < 16) loadc(mtA, nvA, c + 2);
        stepc(mtB, nvB, c + 1);
    }
}

// ---------------- phase 2b: O finalize, parallel over (chunk 1..15, bh) ----------------
// O_c = PBv_c (in outs) + G_c · W0_c^T ; chunk 0 already final (O_0 = PBv_0).
__global__ __launch_bounds__(256) void fw_o(const unsigned short* __restrict__ tiles,
                                            const unsigned short* __restrict__ wchk,
                                            unsigned short* __restrict__ outs) {
    __shared__ unsigned short Ot[64 * 72];
    const int c = blockIdx.x + 1;           // 1..15
    const int bh = blockIdx.y;
    const int b = bh >> 3, h = bh & 7;
    const int c0 = c * 64;
    const int tid = threadIdx.x;
    const int w = tid >> 6, l = tid & 63;
    const int lr = l & 15, lk = (l >> 4) << 3, rb = (l >> 4) << 2;
    const unsigned short* G  = tiles + ((size_t)bh * 16 + c) * 12288 + 4096;
    const unsigned short* W0 = wchk + ((size_t)bh * 16 + c) * 4096;

    // stage PBv tile coalesced
    #pragma unroll
    for (int i = 0; i < 2; ++i) {
        int idx = i * 256 + tid;
        int t = idx >> 3, d0 = (idx & 7) * 8;
        *(ushort8*)&Ot[t * 72 + d0] =
            *(const ushort8*)(outs + ((size_t)(c0 + t) * BSZ + b) * 512 + h * 64 + d0);
    }
    __syncthreads();

    short8 g0 = *(const short8*)(G + (size_t)(16 * w + lr) * 64 + lk);
    short8 g1 = *(const short8*)(G + (size_t)(16 * w + lr) * 64 + 32 + lk);
    #pragma unroll
    for (int n = 0; n < 4; ++n) {
        short8 wf0 = *(const short8*)(W0 + (size_t)(16 * n + lr) * 64 + lk);
        short8 wf1 = *(const short8*)(W0 + (size_t)(16 * n + lr) * 64 + 32 + lk);
        f32x4 a;
        #pragma unroll
        for (int j = 0; j < 4; ++j) a[j] = bf2f(Ot[(16 * w + rb + j) * 72 + 16 * n + lr]);
        a = __builtin_amdgcn_mfma_f32_16x16x32_bf16(g0, wf0, a, 0, 0, 0);
        a = __builtin_amdgcn_mfma_f32_16x16x32_bf16(g1, wf1, a, 0, 0, 0);
        #pragma unroll
        for (int j = 0; j < 4; ++j) Ot[(16 * w + rb + j) * 72 + 16 * n + lr] = f2bf(a[j]);
    }
    __syncthreads();

    // coalesced write-back
    #pragma unroll
    for (int i = 0; i < 2; ++i) {
        int idx = i * 256 + tid;
        int t = idx >> 3, d0 = (idx & 7) * 8;
        *(ushort8*)(outs + ((size_t)(c0 + t) * BSZ + b) * 512 + h * 64 + d0) =
            *(const ushort8*)&Ot[t * 72 + d0];
    }
}

// ---------------- launch ----------------
extern "C" void kernel_launch(void* const* d_in, const int* in_sizes, int n_in,
                              void* d_out, int out_size, void* d_ws, size_t ws_size,
                              hipStream_t stream) {
    const float* x      = (const float*)d_in[0];
    const float* g      = (const float*)d_in[1];
    const float* be     = (const float*)d_in[2];
    const float* w_slow = (const float*)d_in[3];
    const float* w_out  = (const float*)d_in[4];
    float* out = (float*)d_out;
    char* ws = (char*)d_ws;

    unsigned short* h    = (unsigned short*)(ws);                 // 33.5 MB (dead after gemm_qkv)
    unsigned short* outs = (unsigned short*)(ws);                 // alias h
    unsigned short* qn   = (unsigned short*)(ws + 33554432);
    unsigned short* wchk = (unsigned short*)(ws + 33554432);      // alias qn (dead after fwtiles), 33.5 MB
    unsigned short* kn   = (unsigned short*)(ws + 67108864);
    unsigned short* vn   = (unsigned short*)(ws + 100663296);
    float*          bet  = (float*)         (ws + 134217728);
    unsigned short* wsT  = (unsigned short*)(ws + 135266304);
    unsigned short* woT  = (unsigned short*)(ws + 136970240);
    unsigned short* tiles= (unsigned short*)(ws + 137494528);     // 4096 * 24KB

    if (ws_size < 238157824) return;

    ln_kernel<<<8192, 256, 0, stream>>>(x, g, be, h);
    cvt_wslow<<<(NPAD * 512) / 256, 256, 0, stream>>>(w_slow, wsT);
    cvt_wout<<<(512 * 512) / 256, 256, 0, stream>>>(w_out, woT);
    gemm_qkv<<<dim3(13, MROWS / 128), 256, 0, stream>>>(h, wsT, qn, kn, vn, bet);
    fwtiles<<<BSZ * H_ * 16, 512, 0, stream>>>(qn, kn, vn, bet, tiles, outs);
    fwscan_w<<<BSZ * H_, 256, 0, stream>>>(tiles, wchk);
    fw_o<<<dim3(15, BSZ * H_), 256, 0, stream>>>(tiles, wchk, outs);
    gemm_out<<<dim3(4, MROWS / 128), 256, 0, stream>>>(outs, woT, x, out);
}

// Round 9
// 354.113 us; speedup vs baseline: 2.4668x; 1.0251x over previous
//
#include <hip/hip_runtime.h>
#include <cstdint>

using short8  = __attribute__((ext_vector_type(8))) short;
using ushort8 = __attribute__((ext_vector_type(8))) unsigned short;
using short4v = __attribute__((ext_vector_type(4))) short;
using f32x4   = __attribute__((ext_vector_type(4))) float;

#define H_    8
#define SLEN  1024
#define BSZ   32
#define INDIM 512
#define NQKV  1544   // H*(3*D+1)
#define NPAD  1664   // 13*128
#define MROWS 32768  // SLEN*BSZ
#define PB    72     // bf16 LDS pad stride

#define GLOAD16(gp, lp) __builtin_amdgcn_global_load_lds( \
    (const __attribute__((address_space(1))) void*)(gp),  \
    (__attribute__((address_space(3))) void*)(lp), 16, 0, 0)

static __device__ __forceinline__ float bf2f(unsigned short s) {
    return __uint_as_float(((unsigned int)s) << 16);
}
static __device__ __forceinline__ unsigned short f2bf(float f) {
    unsigned int u = __float_as_uint(f);
    u += 0x7FFFu + ((u >> 16) & 1u);
    return (unsigned short)(u >> 16);
}

// ---------------- LayerNorm: x[32768][512] f32 -> h bf16 ----------------
__global__ __launch_bounds__(256) void ln_kernel(const float* __restrict__ x,
                                                 const float* __restrict__ gamma,
                                                 const float* __restrict__ betap,
                                                 unsigned short* __restrict__ h) {
    int row = blockIdx.x * 4 + (threadIdx.x >> 6);
    int l   = threadIdx.x & 63;
    const f32x4* xr = (const f32x4*)(x + (size_t)row * INDIM);
    f32x4 a = xr[l * 2], b = xr[l * 2 + 1];
    float s = 0.f, sq = 0.f;
    #pragma unroll
    for (int j = 0; j < 4; ++j) { s += a[j]; sq += a[j] * a[j]; }
    #pragma unroll
    for (int j = 0; j < 4; ++j) { s += b[j]; sq += b[j] * b[j]; }
    #pragma unroll
    for (int off = 32; off; off >>= 1) { s += __shfl_xor(s, off); sq += __shfl_xor(sq, off); }
    float mean = s * (1.f / 512.f);
    float var  = sq * (1.f / 512.f) - mean * mean;
    float rstd = rsqrtf(var + 1e-5f);
    const f32x4* g4 = (const f32x4*)gamma;
    const f32x4* b4 = (const f32x4*)betap;
    f32x4 g0 = g4[l * 2], g1 = g4[l * 2 + 1], e0 = b4[l * 2], e1 = b4[l * 2 + 1];
    short8 o;
    #pragma unroll
    for (int j = 0; j < 4; ++j) o[j]     = (short)f2bf((a[j] - mean) * rstd * g0[j] + e0[j]);
    #pragma unroll
    for (int j = 0; j < 4; ++j) o[4 + j] = (short)f2bf((b[j] - mean) * rstd * g1[j] + e1[j]);
    ((short8*)(h + (size_t)row * INDIM))[l] = o;
}

// ---------------- weight transpose+permute ----------------
__global__ __launch_bounds__(256) void cvt_wslow(const float* __restrict__ w,
                                                 unsigned short* __restrict__ wT) {
    int idx = blockIdx.x * 256 + threadIdx.x;
    int n = idx >> 9, k = idx & 511;
    int c;
    if (n < 512)       c = (n >> 6) * 193 + (n & 63);
    else if (n < 1024) c = ((n - 512) >> 6) * 193 + 64 + (n & 63);
    else if (n < 1536) c = ((n - 1024) >> 6) * 193 + 128 + (n & 63);
    else if (n < 1544) c = (n - 1536) * 193 + 192;
    else               c = -1;
    wT[idx] = (c >= 0) ? f2bf(w[(size_t)k * NQKV + c]) : (unsigned short)0;
}
__global__ __launch_bounds__(256) void cvt_wout(const float* __restrict__ w,
                                                unsigned short* __restrict__ wT) {
    int idx = blockIdx.x * 256 + threadIdx.x;
    int n = idx >> 9, k = idx & 511;
    wT[idx] = f2bf(w[(size_t)k * 512 + n]);
}

// ---------------- GEMM1 fused: h @ wT^T -> elu+1/sumnorm q,k ; v ; sigmoid beta ----------------
// XCD-chunked block swizzle: all 13 n-blocks of one A row-panel land on the same XCD.
__global__ __launch_bounds__(256) void gemm_qkv(const unsigned short* __restrict__ A,
                                                const unsigned short* __restrict__ BT,
                                                unsigned short* __restrict__ qn,
                                                unsigned short* __restrict__ kn,
                                                unsigned short* __restrict__ vn,
                                                float* __restrict__ bet) {
    __shared__ unsigned short As[128 * 64];
    __shared__ unsigned short Bs[128 * 64];
    const int t  = threadIdx.x;
    const int id = blockIdx.y * 13 + blockIdx.x;      // dispatch-order id (x fastest)
    const int newid = (id & 7) * 416 + (id >> 3);     // 3328 = 8 * 416, bijective
    const int bx = newid % 13;
    const int n0 = bx * 128;
    const int m0 = (newid / 13) * 128;
    const int w = t >> 6, l = t & 63;
    const int wr = (w >> 1) * 64, wc = (w & 1) * 64;
    f32x4 acc[4][4] = {};
    for (int kt = 0; kt < INDIM; kt += 64) {
        __syncthreads();
        #pragma unroll
        for (int c = 0; c < 4; ++c) {
            int idx = c * 256 + t;
            int row = idx >> 3, kc2 = (idx & 7) * 8;
            int lb = (c * 256 + (t & 192)) * 8;   // wave-uniform LDS base (elements)
            GLOAD16(A  + (size_t)(m0 + row) * INDIM + kt + kc2, &As[lb]);
            GLOAD16(BT + (size_t)(n0 + row) * INDIM + kt + kc2, &Bs[lb]);
        }
        __syncthreads();
        #pragma unroll
        for (int kk = 0; kk < 2; ++kk) {
            const int kr = kk * 32 + (l >> 4) * 8;
            short8 af[4], bf[4];
            #pragma unroll
            for (int m = 0; m < 4; ++m) af[m] = *(const short8*)&As[(wr + m * 16 + (l & 15)) * 64 + kr];
            #pragma unroll
            for (int n = 0; n < 4; ++n) bf[n] = *(const short8*)&Bs[(wc + n * 16 + (l & 15)) * 64 + kr];
            #pragma unroll
            for (int m = 0; m < 4; ++m)
                #pragma unroll
                for (int n = 0; n < 4; ++n)
                    acc[m][n] = __builtin_amdgcn_mfma_f32_16x16x32_bf16(af[m], bf[n], acc[m][n], 0, 0, 0);
        }
    }
    const int g = l >> 4, cc = l & 15;
    const int colbase = n0 + wc;
    if (bx < 12) {
        const int reg  = colbase >> 9;
        const int head = (colbase >> 6) & 7;
        unsigned short* dst = (reg == 0) ? qn : (reg == 1) ? kn : vn;
        #pragma unroll
        for (int m = 0; m < 4; ++m) {
            #pragma unroll
            for (int j = 0; j < 4; ++j) {
                int row = m0 + wr + m * 16 + g * 4 + j;
                int s = row >> 5, b = row & 31;
                size_t base = ((size_t)(b * H_ + head) * SLEN + s) * 64;
                float e0 = acc[m][0][j], e1 = acc[m][1][j], e2 = acc[m][2][j], e3 = acc[m][3][j];
                if (reg < 2) {
                    e0 = e0 > 0.f ? e0 + 1.f : __expf(e0);
                    e1 = e1 > 0.f ? e1 + 1.f : __expf(e1);
                    e2 = e2 > 0.f ? e2 + 1.f : __expf(e2);
                    e3 = e3 > 0.f ? e3 + 1.f : __expf(e3);
                    float ssum = (e0 + e1) + (e2 + e3);
                    ssum += __shfl_xor(ssum, 1);
                    ssum += __shfl_xor(ssum, 2);
                    ssum += __shfl_xor(ssum, 4);
                    ssum += __shfl_xor(ssum, 8);
                    float inv = 1.f / ssum;
                    e0 *= inv; e1 *= inv; e2 *= inv; e3 *= inv;
                }
                dst[base +  0 + cc] = f2bf(e0);
                dst[base + 16 + cc] = f2bf(e1);
                dst[base + 32 + cc] = f2bf(e2);
                dst[base + 48 + cc] = f2bf(e3);
            }
        }
    } else {
        if (wc == 0 && cc < 8) {
            #pragma unroll
            for (int m = 0; m < 4; ++m)
                #pragma unroll
                for (int j = 0; j < 4; ++j) {
                    int row = m0 + wr + m * 16 + g * 4 + j;
                    int s = row >> 5, b = row & 31;
                    float v = acc[m][0][j];
                    bet[(size_t)(b * H_ + cc) * SLEN + s] = 1.f / (1.f + __expf(-v));
                }
        }
    }
}

// ---------------- GEMM2: out = x + outs @ woT^T (XCD-chunked swizzle) ----------------
__global__ __launch_bounds__(256) void gemm_out(const unsigned short* __restrict__ A,
                                                const unsigned short* __restrict__ BT,
                                                const float* __restrict__ X,
                                                float* __restrict__ outf) {
    __shared__ unsigned short As[128 * 64];
    __shared__ unsigned short Bs[128 * 64];
    const int t  = threadIdx.x;
    const int id = blockIdx.y * 4 + blockIdx.x;       // dispatch-order id
    const int newid = (id & 7) * 128 + (id >> 3);     // 1024 = 8 * 128, bijective
    const int n0 = (newid % 4) * 128;
    const int m0 = (newid / 4) * 128;
    const int w = t >> 6, l = t & 63;
    const int wr = (w >> 1) * 64, wc = (w & 1) * 64;
    f32x4 acc[4][4] = {};
    for (int kt = 0; kt < INDIM; kt += 64) {
        __syncthreads();
        #pragma unroll
        for (int c = 0; c < 4; ++c) {
            int idx = c * 256 + t;
            int row = idx >> 3, kc2 = (idx & 7) * 8;
            int lb = (c * 256 + (t & 192)) * 8;
            GLOAD16(A  + (size_t)(m0 + row) * INDIM + kt + kc2, &As[lb]);
            GLOAD16(BT + (size_t)(n0 + row) * INDIM + kt + kc2, &Bs[lb]);
        }
        __syncthreads();
        #pragma unroll
        for (int kk = 0; kk < 2; ++kk) {
            const int kr = kk * 32 + (l >> 4) * 8;
            short8 af[4], bf[4];
            #pragma unroll
            for (int m = 0; m < 4; ++m) af[m] = *(const short8*)&As[(wr + m * 16 + (l & 15)) * 64 + kr];
            #pragma unroll
            for (int n = 0; n < 4; ++n) bf[n] = *(const short8*)&Bs[(wc + n * 16 + (l & 15)) * 64 + kr];
            #pragma unroll
            for (int m = 0; m < 4; ++m)
                #pragma unroll
                for (int n = 0; n < 4; ++n)
                    acc[m][n] = __builtin_amdgcn_mfma_f32_16x16x32_bf16(af[m], bf[n], acc[m][n], 0, 0, 0);
        }
    }
    const int rb = (l >> 4) * 4, cc = l & 15;
    #pragma unroll
    for (int m = 0; m < 4; ++m)
        #pragma unroll
        for (int n = 0; n < 4; ++n)
            #pragma unroll
            for (int j = 0; j < 4; ++j) {
                int row = m0 + wr + m * 16 + rb + j;
                int col = n0 + wc + n * 16 + cc;
                size_t o = (size_t)row * 512 + col;
                outf[o] = X[o] + acc[m][n][j];
            }
}

// ---------------- phase 1 v2: per-(bh,chunk) WY tile factors, 8 waves ----------------
__global__ __launch_bounds__(512, 4) void fwtiles(const unsigned short* __restrict__ qn,
                                                  const unsigned short* __restrict__ kn,
                                                  const unsigned short* __restrict__ vn,
                                                  const float* __restrict__ beta,
                                                  unsigned short* __restrict__ tiles,
                                                  unsigned short* __restrict__ outs) {
    __shared__ unsigned short Ax[64 * PB], Atr[64 * PB], Pw[64 * PB], Pwtr[64 * PB];
    __shared__ unsigned short Z0[128 * PB], Z1[128 * PB];
    __shared__ float bv[64];
    const int bx = blockIdx.x;
    const int bh = bx >> 4, c = bx & 15;
    const int b = bh >> 3, h = bh & 7;
    const int c0 = c * 64;
    const int tid = threadIdx.x;
    const int w = tid >> 6, l = tid & 63;
    const int mw = w & 3, nh = w >> 2;
    const int lr = l & 15, lk = (l >> 4) << 3, rb = (l >> 4) << 2;
    const unsigned short* kc = kn + ((size_t)bh * SLEN + c0) * 64;
    const unsigned short* qc = qn + ((size_t)bh * SLEN + c0) * 64;
    const unsigned short* vc = vn + ((size_t)bh * SLEN + c0) * 64;
    const float* bb = beta + (size_t)bh * SLEN + c0;

    {
        #pragma unroll
        for (int i = 0; i < 2; ++i) {
            int idx = i * 512 + tid;
            int row = idx >> 3, seg = idx & 7;
            const unsigned short* src = (row < 64) ? (vc + (size_t)row * 64 + seg * 8)
                                                   : (kc + (size_t)(row - 64) * 64 + seg * 8);
            *(ushort8*)&Z1[row * PB + seg * 8] = *(const ushort8*)src;
        }
        if (tid < 64) bv[tid] = bb[tid];
        ushort8 z8 = {};
        for (int i = tid; i < 576; i += 512) { ((ushort8*)Ax)[i] = z8; ((ushort8*)Atr)[i] = z8; }
    }
    __syncthreads();

    auto ldb = [&](const unsigned short* M, int m, int kk) -> short8 {
        return *(const short8*)&M[(m * 16 + lr) * PB + kk * 32 + lk];
    };

    {
        int dz = tid >> 2, seg = tid & 3;
        int dcol = dz & 63;
        int zoff = (dz & 64) ? 64 : 0;
        float sgn = (dz & 64) ? -1.f : 1.f;
        ushort8 o0, o1;
        #pragma unroll
        for (int j = 0; j < 8; ++j) {
            int tt = seg * 16 + j;
            o0[j] = f2bf(sgn * bv[tt] * bf2f(Z1[(zoff + tt) * PB + dcol]));
        }
        #pragma unroll
        for (int j = 8; j < 16; ++j) {
            int tt = seg * 16 + j;
            o1[j - 8] = f2bf(sgn * bv[tt] * bf2f(Z1[(zoff + tt) * PB + dcol]));
        }
        *(ushort8*)&Z0[dz * PB + seg * 16]     = o0;
        *(ushort8*)&Z0[dz * PB + seg * 16 + 8] = o1;
    }
    {
        const int pm[10] = {0, 1, 1, 2, 2, 2, 3, 3, 3, 3};
        const int pn[10] = {0, 0, 1, 0, 1, 2, 0, 1, 2, 3};
        for (int pi = w; pi < 10; pi += 8) {
            int m = pm[pi], n = pn[pi];
            short8 ka0 = *(const short8*)&Z1[(64 + 16 * m + lr) * PB + lk];
            short8 ka1 = *(const short8*)&Z1[(64 + 16 * m + lr) * PB + 32 + lk];
            short8 kb0 = *(const short8*)&Z1[(64 + 16 * n + lr) * PB + lk];
            short8 kb1 = *(const short8*)&Z1[(64 + 16 * n + lr) * PB + 32 + lk];
            f32x4 a = {};
            a = __builtin_amdgcn_mfma_f32_16x16x32_bf16(ka0, kb0, a, 0, 0, 0);
            a = __builtin_amdgcn_mfma_f32_16x16x32_bf16(ka1, kb1, a, 0, 0, 0);
            f32x4 btm = *(const f32x4*)&bv[16 * m + rb];
            short4v pk;
            #pragma unroll
            for (int j = 0; j < 4; ++j) {
                int tt = 16 * m + rb + j, s = 16 * n + lr;
                unsigned short v = (s < tt) ? f2bf(-btm[j] * a[j]) : (unsigned short)0;
                Ax[tt * PB + s] = v;
                pk[j] = (short)v;
            }
            *(short4v*)&Atr[(16 * n + lr) * PB + 16 * m + rb] = pk;
        }
    }
    __syncthreads();

    auto zprod = [&](const unsigned short* Xb, int p, const unsigned short* Zs, unsigned short* Zd) {
        const bool msk0 = (16 * mw + 15 >= p), msk1 = (16 * mw + 15 - 32 >= p);
        short8 xf0, xf1;
        if (msk0) xf0 = ldb(Xb, mw, 0);
        if (msk1) xf1 = ldb(Xb, mw, 1);
        #pragma unroll
        for (int ni = 0; ni < 4; ++ni) {
            int n = nh * 4 + ni;
            short4v zi = *(const short4v*)&Zs[(16 * n + lr) * PB + 16 * mw + rb];
            f32x4 a;
            #pragma unroll
            for (int j = 0; j < 4; ++j) a[j] = bf2f((unsigned short)zi[j]);
            if (msk0) a = __builtin_amdgcn_mfma_f32_16x16x32_bf16(xf0, ldb(Zs, n, 0), a, 0, 0, 0);
            if (msk1) a = __builtin_amdgcn_mfma_f32_16x16x32_bf16(xf1, ldb(Zs, n, 1), a, 0, 0, 0);
            short4v zo;
            #pragma unroll
            for (int j = 0; j < 4; ++j) zo[j] = (short)f2bf(a[j]);
            *(short4v*)&Zd[(16 * n + lr) * PB + 16 * mw + rb] = zo;
        }
    };
    auto powp = [&](const unsigned short* Ps, const unsigned short* Pstr, int p,
                    unsigned short* Pd, unsigned short* Pdtr) {
        const bool x0 = (16 * mw + 15 >= p), x1 = (16 * mw + 15 - 32 >= p);
        short8 xf0, xf1;
        if (x0) xf0 = ldb(Ps, mw, 0);
        if (x1) xf1 = ldb(Ps, mw, 1);
        #pragma unroll
        for (int ni = 0; ni < 2; ++ni) {
            int n = nh * 2 + ni;
            const bool y0 = (31 - 16 * n >= p), y1 = (63 - 16 * n >= p);
            f32x4 a = {};
            if (x0 && y0) a = __builtin_amdgcn_mfma_f32_16x16x32_bf16(xf0, ldb(Pstr, n, 0), a, 0, 0, 0);
            if (x1 && y1) a = __builtin_amdgcn_mfma_f32_16x16x32_bf16(xf1, ldb(Pstr, n, 1), a, 0, 0, 0);
            short4v pk;
            #pragma unroll
            for (int j = 0; j < 4; ++j) {
                unsigned short v = f2bf(a[j]);
                Pd[(16 * mw + rb + j) * PB + 16 * n + lr] = v;
                pk[j] = (short)v;
            }
            *(short4v*)&Pdtr[(16 * n + lr) * PB + 16 * mw + rb] = pk;
        }
    };

    zprod(Ax, 1, Z0, Z1);  powp(Ax, Atr, 1, Pw, Pwtr);  __syncthreads();
    zprod(Pw, 2, Z1, Z0);  powp(Pw, Pwtr, 2, Ax, Atr);  __syncthreads();
    zprod(Ax, 4, Z0, Z1);  powp(Ax, Atr, 4, Pw, Pwtr);  __syncthreads();
    zprod(Pw, 8, Z1, Z0);  powp(Pw, Pwtr, 8, Ax, Atr);  __syncthreads();
    zprod(Ax, 16, Z0, Z1); powp(Ax, Atr, 16, Pw, Pwtr); __syncthreads();
    zprod(Pw, 32, Z1, Z0);
    __syncthreads();

    {
        #pragma unroll
        for (int i = 0; i < 2; ++i) {
            int idx = i * 512 + tid;
            int row = idx >> 3, seg = idx & 7;
            const unsigned short* src = (row < 64) ? (qc + (size_t)row * 64 + seg * 8)
                                                   : (kc + (size_t)(row - 64) * 64 + seg * 8);
            *(ushort8*)&Z1[row * PB + seg * 8] = *(const ushort8*)src;
        }
    }
    __syncthreads();

    {
        short8 qa0 = *(const short8*)&Z1[(16 * mw + lr) * PB + lk];
        short8 qa1 = *(const short8*)&Z1[(16 * mw + lr) * PB + 32 + lk];
        #pragma unroll
        for (int ni = 0; ni < 2; ++ni) {
            int n = nh * 2 + ni;
            short8 kb0 = *(const short8*)&Z1[(64 + 16 * n + lr) * PB + lk];
            short8 kb1 = *(const short8*)&Z1[(64 + 16 * n + lr) * PB + 32 + lk];
            f32x4 a = {};
            a = __builtin_amdgcn_mfma_f32_16x16x32_bf16(qa0, kb0, a, 0, 0, 0);
            a = __builtin_amdgcn_mfma_f32_16x16x32_bf16(qa1, kb1, a, 0, 0, 0);
            #pragma unroll
            for (int j = 0; j < 4; ++j) {
                int tt = 16 * mw + rb + j, s = 16 * n + lr;
                Ax[tt * PB + s] = (s <= tt) ? f2bf(a[j]) : (unsigned short)0;
            }
        }
    }
    __syncthreads();

    {
        unsigned short* tb = tiles + ((size_t)bh * 16 + c) * 12288;
        auto ktr = [&](int e, int kk) -> short8 {
            short8 r;
            #pragma unroll
            for (int j = 0; j < 8; ++j)
                r[j] = (short)Z1[(64 + kk * 32 + lk + j) * PB + 16 * e + lr];
            return r;
        };
        short8 pA0 = ldb(Ax, mw, 0), pA1 = ldb(Ax, mw, 1);
        short8 zA0 = ldb(Z0, mw, 0), zA1 = ldb(Z0, mw, 1);
        short8 kt0 = ktr(mw, 0), kt1 = ktr(mw, 1);
        #pragma unroll
        for (int ni = 0; ni < 2; ++ni) {
            int n = nh * 2 + ni;
            f32x4 aN = {};
            aN = __builtin_amdgcn_mfma_f32_16x16x32_bf16(zA0, ktr(n, 0), aN, 0, 0, 0);
            aN = __builtin_amdgcn_mfma_f32_16x16x32_bf16(zA1, ktr(n, 1), aN, 0, 0, 0);
            f32x4 aM = {};
            aM = __builtin_amdgcn_mfma_f32_16x16x32_bf16(kt0, ldb(Z0, 4 + n, 0), aM, 0, 0, 0);
            aM = __builtin_amdgcn_mfma_f32_16x16x32_bf16(kt1, ldb(Z0, 4 + n, 1), aM, 0, 0, 0);
            f32x4 aG;
            #pragma unroll
            for (int j = 0; j < 4; ++j) aG[j] = bf2f(Z1[(16 * mw + rb + j) * PB + 16 * n + lr]);
            aG = __builtin_amdgcn_mfma_f32_16x16x32_bf16(pA0, ldb(Z0, 4 + n, 0), aG, 0, 0, 0);
            aG = __builtin_amdgcn_mfma_f32_16x16x32_bf16(pA1, ldb(Z0, 4 + n, 1), aG, 0, 0, 0);
            f32x4 aP = {};
            aP = __builtin_amdgcn_mfma_f32_16x16x32_bf16(pA0, ldb(Z0, n, 0), aP, 0, 0, 0);
            aP = __builtin_amdgcn_mfma_f32_16x16x32_bf16(pA1, ldb(Z0, n, 1), aP, 0, 0, 0);
            #pragma unroll
            for (int j = 0; j < 4; ++j) {
                int r = 16 * mw + rb + j, cl = 16 * n + lr;
                tb[r * 64 + cl]        = f2bf(aM[j]);
                tb[4096 + r * 64 + cl] = f2bf(aG[j]);
                tb[8192 + r * 64 + cl] = f2bf(aN[j]);
                outs[((size_t)(c0 + r) * BSZ + b) * 512 + h * 64 + cl] = f2bf(aP[j]);
            }
        }
    }
}

// ---------------- phase 2a: W-only scan with register prefetch; stores bf16 W checkpoints ----------------
__global__ __launch_bounds__(256) void fwscan_w(const unsigned short* __restrict__ tiles,
                                                unsigned short* __restrict__ wchk) {
    __shared__ float Wf[64 * 68];
    const int bh = blockIdx.x;
    const int tid = threadIdx.x;
    const int w = tid >> 6, l = tid & 63;
    const int lr = l & 15, lk = (l >> 4) << 3, rb = (l >> 4) << 2;
    const int cr = l >> 3, cc8 = (l & 7) * 8;
    #pragma unroll
    for (int j = 0; j < 16; ++j) Wf[(16 * w + j) * 68 + l] = 0.f;

    const unsigned short* tb0 = tiles + (size_t)bh * 16 * 12288;
    unsigned short* wc0 = wchk + (size_t)bh * 16 * 4096;

    auto loadc = [&](short8 (&MT)[4][2], unsigned short (&NV)[4][4], int c) {
        const unsigned short* tb = tb0 + (size_t)c * 12288;
        #pragma unroll
        for (int n = 0; n < 4; ++n) {
            MT[n][0] = *(const short8*)(tb + (size_t)(16 * n + lr) * 64 + lk);
            MT[n][1] = *(const short8*)(tb + (size_t)(16 * n + lr) * 64 + 32 + lk);
            #pragma unroll
            for (int j = 0; j < 4; ++j)
                NV[n][j] = tb[8192 + (size_t)(16 * w + rb + j) * 64 + 16 * n + lr];
        }
    };
    auto stepc = [&](short8 (&MT)[4][2], unsigned short (&NV)[4][4], int c) {
        #pragma unroll
        for (int half = 0; half < 2; ++half) {
            int row = 16 * w + half * 8 + cr;
            const float* p = &Wf[row * 68 + cc8];
            f32x4 x0 = *(const f32x4*)p, x1 = *(const f32x4*)(p + 4);
            ushort8 o;
            #pragma unroll
            for (int j = 0; j < 4; ++j) { o[j] = f2bf(x0[j]); o[4 + j] = f2bf(x1[j]); }
            *(ushort8*)(wc0 + (size_t)c * 4096 + row * 64 + cc8) = o;
        }
        short8 wf0, wf1;
        {
            const float* p0 = &Wf[(16 * w + lr) * 68 + lk];
            f32x4 a0 = *(const f32x4*)p0, b0 = *(const f32x4*)(p0 + 4);
            f32x4 a1 = *(const f32x4*)(p0 + 32), b1 = *(const f32x4*)(p0 + 36);
            #pragma unroll
            for (int j = 0; j < 4; ++j) {
                wf0[j] = (short)f2bf(a0[j]); wf0[4 + j] = (short)f2bf(b0[j]);
                wf1[j] = (short)f2bf(a1[j]); wf1[4 + j] = (short)f2bf(b1[j]);
            }
        }
        #pragma unroll
        for (int n = 0; n < 4; ++n) {
            f32x4 a;
            #pragma unroll
            for (int j = 0; j < 4; ++j)
                a[j] = Wf[(16 * w + rb + j) * 68 + 16 * n + lr] + bf2f(NV[n][j]);
            a = __builtin_amdgcn_mfma_f32_16x16x32_bf16(wf0, MT[n][0], a, 0, 0, 0);
            a = __builtin_amdgcn_mfma_f32_16x16x32_bf16(wf1, MT[n][1], a, 0, 0, 0);
            #pragma unroll
            for (int j = 0; j < 4; ++j) Wf[(16 * w + rb + j) * 68 + 16 * n + lr] = a[j];
        }
    };

    short8 mtA[4][2], mtB[4][2];
    unsigned short nvA[4][4], nvB[4][4];
    loadc(mtA, nvA, 0);
    #pragma unroll 1
    for (int cc = 0; cc < 8; ++cc) {
        int c = 2 * cc;
        if (c + 1 < 16) loadc(mtB, nvB, c + 1);
        stepc(mtA, nvA, c);
        if (c + 2 < 16) loadc(mtA, nvA, c + 2);
        stepc(mtB, nvB, c + 1);
    }
}

// ---------------- phase 2b: O finalize, parallel over (chunk 1..15, bh) ----------------
__global__ __launch_bounds__(256) void fw_o(const unsigned short* __restrict__ tiles,
                                            const unsigned short* __restrict__ wchk,
                                            unsigned short* __restrict__ outs) {
    __shared__ unsigned short Ot[64 * 72];
    const int c = blockIdx.x + 1;           // 1..15
    const int bh = blockIdx.y;
    const int b = bh >> 3, h = bh & 7;
    const int c0 = c * 64;
    const int tid = threadIdx.x;
    const int w = tid >> 6, l = tid & 63;
    const int lr = l & 15, lk = (l >> 4) << 3, rb = (l >> 4) << 2;
    const unsigned short* G  = tiles + ((size_t)bh * 16 + c) * 12288 + 4096;
    const unsigned short* W0 = wchk + ((size_t)bh * 16 + c) * 4096;

    #pragma unroll
    for (int i = 0; i < 2; ++i) {
        int idx = i * 256 + tid;
        int t = idx >> 3, d0 = (idx & 7) * 8;
        *(ushort8*)&Ot[t * 72 + d0] =
            *(const ushort8*)(outs + ((size_t)(c0 + t) * BSZ + b) * 512 + h * 64 + d0);
    }
    __syncthreads();

    short8 g0 = *(const short8*)(G + (size_t)(16 * w + lr) * 64 + lk);
    short8 g1 = *(const short8*)(G + (size_t)(16 * w + lr) * 64 + 32 + lk);
    #pragma unroll
    for (int n = 0; n < 4; ++n) {
        short8 wf0 = *(const short8*)(W0 + (size_t)(16 * n + lr) * 64 + lk);
        short8 wf1 = *(const short8*)(W0 + (size_t)(16 * n + lr) * 64 + 32 + lk);
        f32x4 a;
        #pragma unroll
        for (int j = 0; j < 4; ++j) a[j] = bf2f(Ot[(16 * w + rb + j) * 72 + 16 * n + lr]);
        a = __builtin_amdgcn_mfma_f32_16x16x32_bf16(g0, wf0, a, 0, 0, 0);
        a = __builtin_amdgcn_mfma_f32_16x16x32_bf16(g1, wf1, a, 0, 0, 0);
        #pragma unroll
        for (int j = 0; j < 4; ++j) Ot[(16 * w + rb + j) * 72 + 16 * n + lr] = f2bf(a[j]);
    }
    __syncthreads();

    #pragma unroll
    for (int i = 0; i < 2; ++i) {
        int idx = i * 256 + tid;
        int t = idx >> 3, d0 = (idx & 7) * 8;
        *(ushort8*)(outs + ((size_t)(c0 + t) * BSZ + b) * 512 + h * 64 + d0) =
            *(const ushort8*)&Ot[t * 72 + d0];
    }
}

// ---------------- launch ----------------
extern "C" void kernel_launch(void* const* d_in, const int* in_sizes, int n_in,
                              void* d_out, int out_size, void* d_ws, size_t ws_size,
                              hipStream_t stream) {
    const float* x      = (const float*)d_in[0];
    const float* g      = (const float*)d_in[1];
    const float* be     = (const float*)d_in[2];
    const float* w_slow = (const float*)d_in[3];
    const float* w_out  = (const float*)d_in[4];
    float* out = (float*)d_out;
    char* ws = (char*)d_ws;

    unsigned short* h    = (unsigned short*)(ws);                 // 33.5 MB (dead after gemm_qkv)
    unsigned short* outs = (unsigned short*)(ws);                 // alias h
    unsigned short* qn   = (unsigned short*)(ws + 33554432);
    unsigned short* wchk = (unsigned short*)(ws + 33554432);      // alias qn (dead after fwtiles)
    unsigned short* kn   = (unsigned short*)(ws + 67108864);
    unsigned short* vn   = (unsigned short*)(ws + 100663296);
    float*          bet  = (float*)         (ws + 134217728);
    unsigned short* wsT  = (unsigned short*)(ws + 135266304);
    unsigned short* woT  = (unsigned short*)(ws + 136970240);
    unsigned short* tiles= (unsigned short*)(ws + 137494528);     // 4096 * 24KB

    if (ws_size < 238157824) return;

    ln_kernel<<<8192, 256, 0, stream>>>(x, g, be, h);
    cvt_wslow<<<(NPAD * 512) / 256, 256, 0, stream>>>(w_slow, wsT);
    cvt_wout<<<(512 * 512) / 256, 256, 0, stream>>>(w_out, woT);
    gemm_qkv<<<dim3(13, MROWS / 128), 256, 0, stream>>>(h, wsT, qn, kn, vn, bet);
    fwtiles<<<BSZ * H_ * 16, 512, 0, stream>>>(qn, kn, vn, bet, tiles, outs);
    fwscan_w<<<BSZ * H_, 256, 0, stream>>>(tiles, wchk);
    fw_o<<<dim3(15, BSZ * H_), 256, 0, stream>>>(tiles, wchk, outs);
    gemm_out<<<dim3(4, MROWS / 128), 256, 0, stream>>>(outs, woT, x, out);
}

// Round 10
// 344.713 us; speedup vs baseline: 2.5341x; 1.0273x over previous
//
#include <hip/hip_runtime.h>
#include <cstdint>

using short8  = __attribute__((ext_vector_type(8))) short;
using ushort8 = __attribute__((ext_vector_type(8))) unsigned short;
using short4v = __attribute__((ext_vector_type(4))) short;
using f32x4   = __attribute__((ext_vector_type(4))) float;

#define H_    8
#define SLEN  1024
#define BSZ   32
#define INDIM 512
#define NQKV  1544   // H*(3*D+1)
#define NPAD  1664   // 13*128
#define MROWS 32768  // SLEN*BSZ
#define PB    72     // bf16 LDS pad stride

#define GLOAD16(gp, lp) __builtin_amdgcn_global_load_lds( \
    (const __attribute__((address_space(1))) void*)(gp),  \
    (__attribute__((address_space(3))) void*)(lp), 16, 0, 0)

static __device__ __forceinline__ float bf2f(unsigned short s) {
    return __uint_as_float(((unsigned int)s) << 16);
}
#if defined(__BF16_MANT_DIG__)
static __device__ __forceinline__ unsigned short f2bf(float f) {
    union { __bf16 b; unsigned short u; } cv;
    cv.b = (__bf16)f;            // hardware v_cvt (RNE) on gfx950
    return cv.u;
}
#else
static __device__ __forceinline__ unsigned short f2bf(float f) {
    unsigned int u = __float_as_uint(f);
    u += 0x7FFFu + ((u >> 16) & 1u);
    return (unsigned short)(u >> 16);
}
#endif

// ---------------- LayerNorm: x[32768][512] f32 -> h bf16 ----------------
__global__ __launch_bounds__(256) void ln_kernel(const float* __restrict__ x,
                                                 const float* __restrict__ gamma,
                                                 const float* __restrict__ betap,
                                                 unsigned short* __restrict__ h) {
    int row = blockIdx.x * 4 + (threadIdx.x >> 6);
    int l   = threadIdx.x & 63;
    const f32x4* xr = (const f32x4*)(x + (size_t)row * INDIM);
    f32x4 a = xr[l * 2], b = xr[l * 2 + 1];
    float s = 0.f, sq = 0.f;
    #pragma unroll
    for (int j = 0; j < 4; ++j) { s += a[j]; sq += a[j] * a[j]; }
    #pragma unroll
    for (int j = 0; j < 4; ++j) { s += b[j]; sq += b[j] * b[j]; }
    #pragma unroll
    for (int off = 32; off; off >>= 1) { s += __shfl_xor(s, off); sq += __shfl_xor(sq, off); }
    float mean = s * (1.f / 512.f);
    float var  = sq * (1.f / 512.f) - mean * mean;
    float rstd = rsqrtf(var + 1e-5f);
    const f32x4* g4 = (const f32x4*)gamma;
    const f32x4* b4 = (const f32x4*)betap;
    f32x4 g0 = g4[l * 2], g1 = g4[l * 2 + 1], e0 = b4[l * 2], e1 = b4[l * 2 + 1];
    short8 o;
    #pragma unroll
    for (int j = 0; j < 4; ++j) o[j]     = (short)f2bf((a[j] - mean) * rstd * g0[j] + e0[j]);
    #pragma unroll
    for (int j = 0; j < 4; ++j) o[4 + j] = (short)f2bf((b[j] - mean) * rstd * g1[j] + e1[j]);
    ((short8*)(h + (size_t)row * INDIM))[l] = o;
}

// ---------------- weight transpose+permute ----------------
__global__ __launch_bounds__(256) void cvt_wslow(const float* __restrict__ w,
                                                 unsigned short* __restrict__ wT) {
    int idx = blockIdx.x * 256 + threadIdx.x;
    int n = idx >> 9, k = idx & 511;
    int c;
    if (n < 512)       c = (n >> 6) * 193 + (n & 63);
    else if (n < 1024) c = ((n - 512) >> 6) * 193 + 64 + (n & 63);
    else if (n < 1536) c = ((n - 1024) >> 6) * 193 + 128 + (n & 63);
    else if (n < 1544) c = (n - 1536) * 193 + 192;
    else               c = -1;
    wT[idx] = (c >= 0) ? f2bf(w[(size_t)k * NQKV + c]) : (unsigned short)0;
}
__global__ __launch_bounds__(256) void cvt_wout(const float* __restrict__ w,
                                                unsigned short* __restrict__ wT) {
    int idx = blockIdx.x * 256 + threadIdx.x;
    int n = idx >> 9, k = idx & 511;
    wT[idx] = f2bf(w[(size_t)k * 512 + n]);
}

// ---------------- GEMM1 fused: h @ wT^T -> elu+1/sumnorm q,k ; v ; sigmoid beta ----------------
__global__ __launch_bounds__(256) void gemm_qkv(const unsigned short* __restrict__ A,
                                                const unsigned short* __restrict__ BT,
                                                unsigned short* __restrict__ qn,
                                                unsigned short* __restrict__ kn,
                                                unsigned short* __restrict__ vn,
                                                float* __restrict__ bet) {
    __shared__ unsigned short As[128 * 64];
    __shared__ unsigned short Bs[128 * 64];
    const int t  = threadIdx.x;
    const int id = blockIdx.y * 13 + blockIdx.x;
    const int newid = (id & 7) * 416 + (id >> 3);     // 3328 = 8*416, bijective
    const int bx = newid % 13;
    const int n0 = bx * 128;
    const int m0 = (newid / 13) * 128;
    const int w = t >> 6, l = t & 63;
    const int wr = (w >> 1) * 64, wc = (w & 1) * 64;
    f32x4 acc[4][4] = {};
    for (int kt = 0; kt < INDIM; kt += 64) {
        __syncthreads();
        #pragma unroll
        for (int c = 0; c < 4; ++c) {
            int idx = c * 256 + t;
            int row = idx >> 3, kc2 = (idx & 7) * 8;
            int lb = (c * 256 + (t & 192)) * 8;
            GLOAD16(A  + (size_t)(m0 + row) * INDIM + kt + kc2, &As[lb]);
            GLOAD16(BT + (size_t)(n0 + row) * INDIM + kt + kc2, &Bs[lb]);
        }
        __syncthreads();
        #pragma unroll
        for (int kk = 0; kk < 2; ++kk) {
            const int kr = kk * 32 + (l >> 4) * 8;
            short8 af[4], bf[4];
            #pragma unroll
            for (int m = 0; m < 4; ++m) af[m] = *(const short8*)&As[(wr + m * 16 + (l & 15)) * 64 + kr];
            #pragma unroll
            for (int n = 0; n < 4; ++n) bf[n] = *(const short8*)&Bs[(wc + n * 16 + (l & 15)) * 64 + kr];
            #pragma unroll
            for (int m = 0; m < 4; ++m)
                #pragma unroll
                for (int n = 0; n < 4; ++n)
                    acc[m][n] = __builtin_amdgcn_mfma_f32_16x16x32_bf16(af[m], bf[n], acc[m][n], 0, 0, 0);
        }
    }
    const int g = l >> 4, cc = l & 15;
    const int colbase = n0 + wc;
    if (bx < 12) {
        const int reg  = colbase >> 9;
        const int head = (colbase >> 6) & 7;
        unsigned short* dst = (reg == 0) ? qn : (reg == 1) ? kn : vn;
        #pragma unroll
        for (int m = 0; m < 4; ++m) {
            #pragma unroll
            for (int j = 0; j < 4; ++j) {
                int row = m0 + wr + m * 16 + g * 4 + j;
                int s = row >> 5, b = row & 31;
                size_t base = ((size_t)(b * H_ + head) * SLEN + s) * 64;
                float e0 = acc[m][0][j], e1 = acc[m][1][j], e2 = acc[m][2][j], e3 = acc[m][3][j];
                if (reg < 2) {
                    e0 = e0 > 0.f ? e0 + 1.f : __expf(e0);
                    e1 = e1 > 0.f ? e1 + 1.f : __expf(e1);
                    e2 = e2 > 0.f ? e2 + 1.f : __expf(e2);
                    e3 = e3 > 0.f ? e3 + 1.f : __expf(e3);
                    float ssum = (e0 + e1) + (e2 + e3);
                    ssum += __shfl_xor(ssum, 1);
                    ssum += __shfl_xor(ssum, 2);
                    ssum += __shfl_xor(ssum, 4);
                    ssum += __shfl_xor(ssum, 8);
                    float inv = 1.f / ssum;
                    e0 *= inv; e1 *= inv; e2 *= inv; e3 *= inv;
                }
                dst[base +  0 + cc] = f2bf(e0);
                dst[base + 16 + cc] = f2bf(e1);
                dst[base + 32 + cc] = f2bf(e2);
                dst[base + 48 + cc] = f2bf(e3);
            }
        }
    } else {
        if (wc == 0 && cc < 8) {
            #pragma unroll
            for (int m = 0; m < 4; ++m)
                #pragma unroll
                for (int j = 0; j < 4; ++j) {
                    int row = m0 + wr + m * 16 + g * 4 + j;
                    int s = row >> 5, b = row & 31;
                    float v = acc[m][0][j];
                    bet[(size_t)(b * H_ + cc) * SLEN + s] = 1.f / (1.f + __expf(-v));
                }
        }
    }
}

// ---------------- GEMM2: out = x + outs @ woT^T (XCD-chunked swizzle) ----------------
__global__ __launch_bounds__(256) void gemm_out(const unsigned short* __restrict__ A,
                                                const unsigned short* __restrict__ BT,
                                                const float* __restrict__ X,
                                                float* __restrict__ outf) {
    __shared__ unsigned short As[128 * 64];
    __shared__ unsigned short Bs[128 * 64];
    const int t  = threadIdx.x;
    const int id = blockIdx.y * 4 + blockIdx.x;
    const int newid = (id & 7) * 128 + (id >> 3);     // 1024 = 8*128, bijective
    const int n0 = (newid % 4) * 128;
    const int m0 = (newid / 4) * 128;
    const int w = t >> 6, l = t & 63;
    const int wr = (w >> 1) * 64, wc = (w & 1) * 64;
    f32x4 acc[4][4] = {};
    for (int kt = 0; kt < INDIM; kt += 64) {
        __syncthreads();
        #pragma unroll
        for (int c = 0; c < 4; ++c) {
            int idx = c * 256 + t;
            int row = idx >> 3, kc2 = (idx & 7) * 8;
            int lb = (c * 256 + (t & 192)) * 8;
            GLOAD16(A  + (size_t)(m0 + row) * INDIM + kt + kc2, &As[lb]);
            GLOAD16(BT + (size_t)(n0 + row) * INDIM + kt + kc2, &Bs[lb]);
        }
        __syncthreads();
        #pragma unroll
        for (int kk = 0; kk < 2; ++kk) {
            const int kr = kk * 32 + (l >> 4) * 8;
            short8 af[4], bf[4];
            #pragma unroll
            for (int m = 0; m < 4; ++m) af[m] = *(const short8*)&As[(wr + m * 16 + (l & 15)) * 64 + kr];
            #pragma unroll
            for (int n = 0; n < 4; ++n) bf[n] = *(const short8*)&Bs[(wc + n * 16 + (l & 15)) * 64 + kr];
            #pragma unroll
            for (int m = 0; m < 4; ++m)
                #pragma unroll
                for (int n = 0; n < 4; ++n)
                    acc[m][n] = __builtin_amdgcn_mfma_f32_16x16x32_bf16(af[m], bf[n], acc[m][n], 0, 0, 0);
        }
    }
    const int rb = (l >> 4) * 4, cc = l & 15;
    #pragma unroll
    for (int m = 0; m < 4; ++m)
        #pragma unroll
        for (int n = 0; n < 4; ++n)
            #pragma unroll
            for (int j = 0; j < 4; ++j) {
                int row = m0 + wr + m * 16 + rb + j;
                int col = n0 + wc + n * 16 + cc;
                size_t o = (size_t)row * 512 + col;
                outf[o] = X[o] + acc[m][n][j];
            }
}

// ---------------- phase 1 v3: per-(bh,chunk) WY tile factors, 8 waves, conflict-fixed ----------------
__global__ __launch_bounds__(512, 4) void fwtiles(const unsigned short* __restrict__ qn,
                                                  const unsigned short* __restrict__ kn,
                                                  const unsigned short* __restrict__ vn,
                                                  const float* __restrict__ beta,
                                                  unsigned short* __restrict__ tiles,
                                                  unsigned short* __restrict__ outs) {
    __shared__ unsigned short Ax[64 * PB], Atr[64 * PB], Pw[64 * PB], Pwtr[64 * PB];
    __shared__ unsigned short Z0[128 * PB], Z1[128 * PB];
    __shared__ float bv[64];
    const int bx = blockIdx.x;
    const int bh = bx >> 4, c = bx & 15;
    const int b = bh >> 3, h = bh & 7;
    const int c0 = c * 64;
    const int tid = threadIdx.x;
    const int w = tid >> 6, l = tid & 63;
    const int mw = w & 3, nh = w >> 2;
    const int lr = l & 15, lk = (l >> 4) << 3, rb = (l >> 4) << 2;
    const unsigned short* kc = kn + ((size_t)bh * SLEN + c0) * 64;
    const unsigned short* qc = qn + ((size_t)bh * SLEN + c0) * 64;
    const unsigned short* vc = vn + ((size_t)bh * SLEN + c0) * 64;
    const float* bb = beta + (size_t)bh * SLEN + c0;

    // ---- stage Z1 <- [V rows 0..63 | K rows 64..127] row-major; bv; zero Ax/Atr ----
    {
        #pragma unroll
        for (int i = 0; i < 2; ++i) {
            int idx = i * 512 + tid;
            int row = idx >> 3, seg = idx & 7;
            const unsigned short* src = (row < 64) ? (vc + (size_t)row * 64 + seg * 8)
                                                   : (kc + (size_t)(row - 64) * 64 + seg * 8);
            *(ushort8*)&Z1[row * PB + seg * 8] = *(const ushort8*)src;
        }
        if (tid < 64) bv[tid] = bb[tid];
        ushort8 z8 = {};
        for (int i = tid; i < 576; i += 512) { ((ushort8*)Ax)[i] = z8; ((ushort8*)Atr)[i] = z8; }
    }
    __syncthreads();

    auto ldb = [&](const unsigned short* M, int m, int kk) -> short8 {
        return *(const short8*)&M[(m * 16 + lr) * PB + kk * 32 + lk];
    };

    // ---- Part B v2: Z0 <- scaled transpose of Z1, wave-row broadcast (conflict-free) ----
    // wave w sweeps its 16 source rows; all lanes read one row's contiguous shorts.
    {
        const int zoff2 = (w >> 2) * 64;
        const int tbase = (w & 3) * 16;
        const float sgn = (w >= 4) ? -1.f : 1.f;
        ushort8 b0v, b1v;
        #pragma unroll
        for (int i = 0; i < 16; ++i) {
            int r = w * 16 + i;            // Z1 source row
            float val = sgn * bv[tbase + i] * bf2f(Z1[r * PB + l]);
            unsigned short uv = f2bf(val);
            if (i < 8) b0v[i] = uv; else b1v[i - 8] = uv;
        }
        *(ushort8*)&Z0[(zoff2 + l) * PB + tbase]     = b0v;
        *(ushort8*)&Z0[(zoff2 + l) * PB + tbase + 8] = b1v;
    }
    // ---- S1: A = -b_t * tril(K K^T, s<t) from Z1 K-rows (10 pairs over 8 waves) ----
    {
        const int pm[10] = {0, 1, 1, 2, 2, 2, 3, 3, 3, 3};
        const int pn[10] = {0, 0, 1, 0, 1, 2, 0, 1, 2, 3};
        for (int pi = w; pi < 10; pi += 8) {
            int m = pm[pi], n = pn[pi];
            short8 ka0 = *(const short8*)&Z1[(64 + 16 * m + lr) * PB + lk];
            short8 ka1 = *(const short8*)&Z1[(64 + 16 * m + lr) * PB + 32 + lk];
            short8 kb0 = *(const short8*)&Z1[(64 + 16 * n + lr) * PB + lk];
            short8 kb1 = *(const short8*)&Z1[(64 + 16 * n + lr) * PB + 32 + lk];
            f32x4 a = {};
            a = __builtin_amdgcn_mfma_f32_16x16x32_bf16(ka0, kb0, a, 0, 0, 0);
            a = __builtin_amdgcn_mfma_f32_16x16x32_bf16(ka1, kb1, a, 0, 0, 0);
            f32x4 btm = *(const f32x4*)&bv[16 * m + rb];
            short4v pk;
            #pragma unroll
            for (int j = 0; j < 4; ++j) {
                int tt = 16 * m + rb + j, s = 16 * n + lr;
                unsigned short v = (s < tt) ? f2bf(-btm[j] * a[j]) : (unsigned short)0;
                Ax[tt * PB + s] = v;
                pk[j] = (short)v;
            }
            *(short4v*)&Atr[(16 * n + lr) * PB + 16 * m + rb] = pk;
        }
    }
    __syncthreads();

    auto zprod = [&](const unsigned short* Xb, int p, const unsigned short* Zs, unsigned short* Zd) {
        const bool msk0 = (16 * mw + 15 >= p), msk1 = (16 * mw + 15 - 32 >= p);
        short8 xf0, xf1;
        if (msk0) xf0 = ldb(Xb, mw, 0);
        if (msk1) xf1 = ldb(Xb, mw, 1);
        #pragma unroll
        for (int ni = 0; ni < 4; ++ni) {
            int n = nh * 4 + ni;
            short4v zi = *(const short4v*)&Zs[(16 * n + lr) * PB + 16 * mw + rb];
            f32x4 a;
            #pragma unroll
            for (int j = 0; j < 4; ++j) a[j] = bf2f((unsigned short)zi[j]);
            if (msk0) a = __builtin_amdgcn_mfma_f32_16x16x32_bf16(xf0, ldb(Zs, n, 0), a, 0, 0, 0);
            if (msk1) a = __builtin_amdgcn_mfma_f32_16x16x32_bf16(xf1, ldb(Zs, n, 1), a, 0, 0, 0);
            short4v zo;
            #pragma unroll
            for (int j = 0; j < 4; ++j) zo[j] = (short)f2bf(a[j]);
            *(short4v*)&Zd[(16 * n + lr) * PB + 16 * mw + rb] = zo;
        }
    };
    auto powp = [&](const unsigned short* Ps, const unsigned short* Pstr, int p,
                    unsigned short* Pd, unsigned short* Pdtr) {
        const bool x0 = (16 * mw + 15 >= p), x1 = (16 * mw + 15 - 32 >= p);
        short8 xf0, xf1;
        if (x0) xf0 = ldb(Ps, mw, 0);
        if (x1) xf1 = ldb(Ps, mw, 1);
        #pragma unroll
        for (int ni = 0; ni < 2; ++ni) {
            int n = nh * 2 + ni;
            const bool y0 = (31 - 16 * n >= p), y1 = (63 - 16 * n >= p);
            f32x4 a = {};
            if (x0 && y0) a = __builtin_amdgcn_mfma_f32_16x16x32_bf16(xf0, ldb(Pstr, n, 0), a, 0, 0, 0);
            if (x1 && y1) a = __builtin_amdgcn_mfma_f32_16x16x32_bf16(xf1, ldb(Pstr, n, 1), a, 0, 0, 0);
            short4v pk;
            #pragma unroll
            for (int j = 0; j < 4; ++j) {
                unsigned short v = f2bf(a[j]);
                Pd[(16 * mw + rb + j) * PB + 16 * n + lr] = v;
                pk[j] = (short)v;
            }
            *(short4v*)&Pdtr[(16 * n + lr) * PB + 16 * mw + rb] = pk;
        }
    };

    zprod(Ax, 1, Z0, Z1);  powp(Ax, Atr, 1, Pw, Pwtr);  __syncthreads();
    zprod(Pw, 2, Z1, Z0);  powp(Pw, Pwtr, 2, Ax, Atr);  __syncthreads();
    zprod(Ax, 4, Z0, Z1);  powp(Ax, Atr, 4, Pw, Pwtr);  __syncthreads();
    zprod(Pw, 8, Z1, Z0);  powp(Pw, Pwtr, 8, Ax, Atr);  __syncthreads();
    zprod(Ax, 16, Z0, Z1); powp(Ax, Atr, 16, Pw, Pwtr); __syncthreads();
    zprod(Pw, 32, Z1, Z0);
    __syncthreads();
    // Z0 rows 0..63 = Bv^T, rows 64..127 = (-Bk)^T ; Pw/Pwtr/Atr now dead

    // ---- re-stage Z1 <- [Q rows 0..63 | K rows 64..127] row-major (L2-hot) ----
    {
        #pragma unroll
        for (int i = 0; i < 2; ++i) {
            int idx = i * 512 + tid;
            int row = idx >> 3, seg = idx & 7;
            const unsigned short* src = (row < 64) ? (qc + (size_t)row * 64 + seg * 8)
                                                   : (kc + (size_t)(row - 64) * 64 + seg * 8);
            *(ushort8*)&Z1[row * PB + seg * 8] = *(const ushort8*)src;
        }
    }
    __syncthreads();

    // ---- S8: P = tril(Q K^T, incl) -> Ax ; build KtrL = K^T into Pwtr (conflict-free) ----
    {
        short8 qa0 = *(const short8*)&Z1[(16 * mw + lr) * PB + lk];
        short8 qa1 = *(const short8*)&Z1[(16 * mw + lr) * PB + 32 + lk];
        #pragma unroll
        for (int ni = 0; ni < 2; ++ni) {
            int n = nh * 2 + ni;
            short8 kb0 = *(const short8*)&Z1[(64 + 16 * n + lr) * PB + lk];
            short8 kb1 = *(const short8*)&Z1[(64 + 16 * n + lr) * PB + 32 + lk];
            f32x4 a = {};
            a = __builtin_amdgcn_mfma_f32_16x16x32_bf16(qa0, kb0, a, 0, 0, 0);
            a = __builtin_amdgcn_mfma_f32_16x16x32_bf16(qa1, kb1, a, 0, 0, 0);
            #pragma unroll
            for (int j = 0; j < 4; ++j) {
                int tt = 16 * mw + rb + j, s = 16 * n + lr;
                Ax[tt * PB + s] = (s <= tt) ? f2bf(a[j]) : (unsigned short)0;
            }
        }
        // KtrL[d][t] = K[t][d]: thread(w,l): d = l, t in [8w, 8w+8)
        ushort8 kv;
        #pragma unroll
        for (int j = 0; j < 8; ++j)
            kv[j] = Z1[(64 + w * 8 + j) * PB + l];    // column read: banks = f(l) -> free
        *(ushort8*)&Pwtr[l * PB + w * 8] = kv;         // slot (l+w)&7 -> clean
    }
    __syncthreads();

    // ---- S9: outputs (Mt | G | N -> tiles; PBv -> outs) ----
    {
        unsigned short* tb = tiles + ((size_t)bh * 16 + c) * 12288;
        short8 pA0 = ldb(Ax, mw, 0), pA1 = ldb(Ax, mw, 1);
        short8 zA0 = ldb(Z0, mw, 0), zA1 = ldb(Z0, mw, 1);
        short8 kt0 = ldb(Pwtr, mw, 0), kt1 = ldb(Pwtr, mw, 1);
        #pragma unroll
        for (int ni = 0; ni < 2; ++ni) {
            int n = nh * 2 + ni;
            f32x4 aN = {};
            aN = __builtin_amdgcn_mfma_f32_16x16x32_bf16(zA0, ldb(Pwtr, n, 0), aN, 0, 0, 0);
            aN = __builtin_amdgcn_mfma_f32_16x16x32_bf16(zA1, ldb(Pwtr, n, 1), aN, 0, 0, 0);
            f32x4 aM = {};
            aM = __builtin_amdgcn_mfma_f32_16x16x32_bf16(kt0, ldb(Z0, 4 + n, 0), aM, 0, 0, 0);
            aM = __builtin_amdgcn_mfma_f32_16x16x32_bf16(kt1, ldb(Z0, 4 + n, 1), aM, 0, 0, 0);
            f32x4 aG;
            #pragma unroll
            for (int j = 0; j < 4; ++j) aG[j] = bf2f(Z1[(16 * mw + rb + j) * PB + 16 * n + lr]);
            aG = __builtin_amdgcn_mfma_f32_16x16x32_bf16(pA0, ldb(Z0, 4 + n, 0), aG, 0, 0, 0);
            aG = __builtin_amdgcn_mfma_f32_16x16x32_bf16(pA1, ldb(Z0, 4 + n, 1), aG, 0, 0, 0);
            f32x4 aP = {};
            aP = __builtin_amdgcn_mfma_f32_16x16x32_bf16(pA0, ldb(Z0, n, 0), aP, 0, 0, 0);
            aP = __builtin_amdgcn_mfma_f32_16x16x32_bf16(pA1, ldb(Z0, n, 1), aP, 0, 0, 0);
            #pragma unroll
            for (int j = 0; j < 4; ++j) {
                int r = 16 * mw + rb + j, cl = 16 * n + lr;
                tb[r * 64 + cl]        = f2bf(aM[j]);
                tb[4096 + r * 64 + cl] = f2bf(aG[j]);
                tb[8192 + r * 64 + cl] = f2bf(aN[j]);
                outs[((size_t)(c0 + r) * BSZ + b) * 512 + h * 64 + cl] = f2bf(aP[j]);
            }
        }
    }
}

// ---------------- phase 2a: W-only scan with register prefetch; stores bf16 W checkpoints ----------------
__global__ __launch_bounds__(256) void fwscan_w(const unsigned short* __restrict__ tiles,
                                                unsigned short* __restrict__ wchk) {
    __shared__ float Wf[64 * 68];
    const int bh = blockIdx.x;
    const int tid = threadIdx.x;
    const int w = tid >> 6, l = tid & 63;
    const int lr = l & 15, lk = (l >> 4) << 3, rb = (l >> 4) << 2;
    const int cr = l >> 3, cc8 = (l & 7) * 8;
    #pragma unroll
    for (int j = 0; j < 16; ++j) Wf[(16 * w + j) * 68 + l] = 0.f;

    const unsigned short* tb0 = tiles + (size_t)bh * 16 * 12288;
    unsigned short* wc0 = wchk + (size_t)bh * 16 * 4096;

    auto loadc = [&](short8 (&MT)[4][2], unsigned short (&NV)[4][4], int c) {
        const unsigned short* tb = tb0 + (size_t)c * 12288;
        #pragma unroll
        for (int n = 0; n < 4; ++n) {
            MT[n][0] = *(const short8*)(tb + (size_t)(16 * n + lr) * 64 + lk);
            MT[n][1] = *(const short8*)(tb + (size_t)(16 * n + lr) * 64 + 32 + lk);
            #pragma unroll
            for (int j = 0; j < 4; ++j)
                NV[n][j] = tb[8192 + (size_t)(16 * w + rb + j) * 64 + 16 * n + lr];
        }
    };
    auto stepc = [&](short8 (&MT)[4][2], unsigned short (&NV)[4][4], int c) {
        #pragma unroll
        for (int half = 0; half < 2; ++half) {
            int row = 16 * w + half * 8 + cr;
            const float* p = &Wf[row * 68 + cc8];
            f32x4 x0 = *(const f32x4*)p, x1 = *(const f32x4*)(p + 4);
            ushort8 o;
            #pragma unroll
            for (int j = 0; j < 4; ++j) { o[j] = f2bf(x0[j]); o[4 + j] = f2bf(x1[j]); }
            *(ushort8*)(wc0 + (size_t)c * 4096 + row * 64 + cc8) = o;
        }
        short8 wf0, wf1;
        {
            const float* p0 = &Wf[(16 * w + lr) * 68 + lk];
            f32x4 a0 = *(const f32x4*)p0, b0 = *(const f32x4*)(p0 + 4);
            f32x4 a1 = *(const f32x4*)(p0 + 32), b1 = *(const f32x4*)(p0 + 36);
            #pragma unroll
            for (int j = 0; j < 4; ++j) {
                wf0[j] = (short)f2bf(a0[j]); wf0[4 + j] = (short)f2bf(b0[j]);
                wf1[j] = (short)f2bf(a1[j]); wf1[4 + j] = (short)f2bf(b1[j]);
            }
        }
        #pragma unroll
        for (int n = 0; n < 4; ++n) {
            f32x4 a;
            #pragma unroll
            for (int j = 0; j < 4; ++j)
                a[j] = Wf[(16 * w + rb + j) * 68 + 16 * n + lr] + bf2f(NV[n][j]);
            a = __builtin_amdgcn_mfma_f32_16x16x32_bf16(wf0, MT[n][0], a, 0, 0, 0);
            a = __builtin_amdgcn_mfma_f32_16x16x32_bf16(wf1, MT[n][1], a, 0, 0, 0);
            #pragma unroll
            for (int j = 0; j < 4; ++j) Wf[(16 * w + rb + j) * 68 + 16 * n + lr] = a[j];
        }
    };

    short8 mtA[4][2], mtB[4][2];
    unsigned short nvA[4][4], nvB[4][4];
    loadc(mtA, nvA, 0);
    #pragma unroll 1
    for (int cc = 0; cc < 8; ++cc) {
        int c = 2 * cc;
        if (c + 1 < 16) loadc(mtB, nvB, c + 1);
        stepc(mtA, nvA, c);
        if (c + 2 < 16) loadc(mtA, nvA, c + 2);
        stepc(mtB, nvB, c + 1);
    }
}

// ---------------- phase 2b: O finalize, parallel over (chunk 1..15, bh) ----------------
__global__ __launch_bounds__(256) void fw_o(const unsigned short* __restrict__ tiles,
                                            const unsigned short* __restrict__ wchk,
                                            unsigned short* __restrict__ outs) {
    __shared__ unsigned short Ot[64 * 72];
    const int c = blockIdx.x + 1;
    const int bh = blockIdx.y;
    const int b = bh >> 3, h = bh & 7;
    const int c0 = c * 64;
    const int tid = threadIdx.x;
    const int w = tid >> 6, l = tid & 63;
    const int lr = l & 15, lk = (l >> 4) << 3, rb = (l >> 4) << 2;
    const unsigned short* G  = tiles + ((size_t)bh * 16 + c) * 12288 + 4096;
    const unsigned short* W0 = wchk + ((size_t)bh * 16 + c) * 4096;

    #pragma unroll
    for (int i = 0; i < 2; ++i) {
        int idx = i * 256 + tid;
        int t = idx >> 3, d0 = (idx & 7) * 8;
        *(ushort8*)&Ot[t * 72 + d0] =
            *(const ushort8*)(outs + ((size_t)(c0 + t) * BSZ + b) * 512 + h * 64 + d0);
    }
    __syncthreads();

    short8 g0 = *(const short8*)(G + (size_t)(16 * w + lr) * 64 + lk);
    short8 g1 = *(const short8*)(G + (size_t)(16 * w + lr) * 64 + 32 + lk);
    #pragma unroll
    for (int n = 0; n < 4; ++n) {
        short8 wf0 = *(const short8*)(W0 + (size_t)(16 * n + lr) * 64 + lk);
        short8 wf1 = *(const short8*)(W0 + (size_t)(16 * n + lr) * 64 + 32 + lk);
        f32x4 a;
        #pragma unroll
        for (int j = 0; j < 4; ++j) a[j] = bf2f(Ot[(16 * w + rb + j) * 72 + 16 * n + lr]);
        a = __builtin_amdgcn_mfma_f32_16x16x32_bf16(g0, wf0, a, 0, 0, 0);
        a = __builtin_amdgcn_mfma_f32_16x16x32_bf16(g1, wf1, a, 0, 0, 0);
        #pragma unroll
        for (int j = 0; j < 4; ++j) Ot[(16 * w + rb + j) * 72 + 16 * n + lr] = f2bf(a[j]);
    }
    __syncthreads();

    #pragma unroll
    for (int i = 0; i < 2; ++i) {
        int idx = i * 256 + tid;
        int t = idx >> 3, d0 = (idx & 7) * 8;
        *(ushort8*)(outs + ((size_t)(c0 + t) * BSZ + b) * 512 + h * 64 + d0) =
            *(const ushort8*)&Ot[t * 72 + d0];
    }
}

// ---------------- launch ----------------
extern "C" void kernel_launch(void* const* d_in, const int* in_sizes, int n_in,
                              void* d_out, int out_size, void* d_ws, size_t ws_size,
                              hipStream_t stream) {
    const float* x      = (const float*)d_in[0];
    const float* g      = (const float*)d_in[1];
    const float* be     = (const float*)d_in[2];
    const float* w_slow = (const float*)d_in[3];
    const float* w_out  = (const float*)d_in[4];
    float* out = (float*)d_out;
    char* ws = (char*)d_ws;

    unsigned short* h    = (unsigned short*)(ws);
    unsigned short* outs = (unsigned short*)(ws);                 // alias h
    unsigned short* qn   = (unsigned short*)(ws + 33554432);
    unsigned short* wchk = (unsigned short*)(ws + 33554432);      // alias qn (dead after fwtiles)
    unsigned short* kn   = (unsigned short*)(ws + 67108864);
    unsigned short* vn   = (unsigned short*)(ws + 100663296);
    float*          bet  = (float*)         (ws + 134217728);
    unsigned short* wsT  = (unsigned short*)(ws + 135266304);
    unsigned short* woT  = (unsigned short*)(ws + 136970240);
    unsigned short* tiles= (unsigned short*)(ws + 137494528);

    if (ws_size < 238157824) return;

    ln_kernel<<<8192, 256, 0, stream>>>(x, g, be, h);
    cvt_wslow<<<(NPAD * 512) / 256, 256, 0, stream>>>(w_slow, wsT);
    cvt_wout<<<(512 * 512) / 256, 256, 0, stream>>>(w_out, woT);
    gemm_qkv<<<dim3(13, MROWS / 128), 256, 0, stream>>>(h, wsT, qn, kn, vn, bet);
    fwtiles<<<BSZ * H_ * 16, 512, 0, stream>>>(qn, kn, vn, bet, tiles, outs);
    fwscan_w<<<BSZ * H_, 256, 0, stream>>>(tiles, wchk);
    fw_o<<<dim3(15, BSZ * H_), 256, 0, stream>>>(tiles, wchk, outs);
    gemm_out<<<dim3(4, MROWS / 128), 256, 0, stream>>>(outs, woT, x, out);
}

// Round 11
// 339.584 us; speedup vs baseline: 2.5724x; 1.0151x over previous
//
#include <hip/hip_runtime.h>
#include <cstdint>

using short8  = __attribute__((ext_vector_type(8))) short;
using ushort8 = __attribute__((ext_vector_type(8))) unsigned short;
using short4v = __attribute__((ext_vector_type(4))) short;
using f32x4   = __attribute__((ext_vector_type(4))) float;

#define H_    8
#define SLEN  1024
#define BSZ   32
#define INDIM 512
#define NQKV  1544   // H*(3*D+1)
#define NPAD2 1792   // 7*256 (gemm_qkv N padding)
#define MROWS 32768  // SLEN*BSZ
#define PB    72     // bf16 LDS pad stride

#define GLOAD16(gp, lp) __builtin_amdgcn_global_load_lds( \
    (const __attribute__((address_space(1))) void*)(gp),  \
    (__attribute__((address_space(3))) void*)(lp), 16, 0, 0)

#define VMCNT8() do { asm volatile("s_waitcnt vmcnt(8)" ::: "memory"); \
                      __builtin_amdgcn_sched_barrier(0); } while (0)
#define VMCNT0() do { asm volatile("s_waitcnt vmcnt(0)" ::: "memory"); \
                      __builtin_amdgcn_sched_barrier(0); } while (0)
#define SBAR()   do { __builtin_amdgcn_sched_barrier(0); \
                      __builtin_amdgcn_s_barrier(); \
                      __builtin_amdgcn_sched_barrier(0); } while (0)

static __device__ __forceinline__ float bf2f(unsigned short s) {
    return __uint_as_float(((unsigned int)s) << 16);
}
#if defined(__BF16_MANT_DIG__)
static __device__ __forceinline__ unsigned short f2bf(float f) {
    union { __bf16 b; unsigned short u; } cv;
    cv.b = (__bf16)f;
    return cv.u;
}
#else
static __device__ __forceinline__ unsigned short f2bf(float f) {
    unsigned int u = __float_as_uint(f);
    u += 0x7FFFu + ((u >> 16) & 1u);
    return (unsigned short)(u >> 16);
}
#endif

// ---------------- LayerNorm: x[32768][512] f32 -> h bf16 ----------------
__global__ __launch_bounds__(256) void ln_kernel(const float* __restrict__ x,
                                                 const float* __restrict__ gamma,
                                                 const float* __restrict__ betap,
                                                 unsigned short* __restrict__ h) {
    int row = blockIdx.x * 4 + (threadIdx.x >> 6);
    int l   = threadIdx.x & 63;
    const f32x4* xr = (const f32x4*)(x + (size_t)row * INDIM);
    f32x4 a = xr[l * 2], b = xr[l * 2 + 1];
    float s = 0.f, sq = 0.f;
    #pragma unroll
    for (int j = 0; j < 4; ++j) { s += a[j]; sq += a[j] * a[j]; }
    #pragma unroll
    for (int j = 0; j < 4; ++j) { s += b[j]; sq += b[j] * b[j]; }
    #pragma unroll
    for (int off = 32; off; off >>= 1) { s += __shfl_xor(s, off); sq += __shfl_xor(sq, off); }
    float mean = s * (1.f / 512.f);
    float var  = sq * (1.f / 512.f) - mean * mean;
    float rstd = rsqrtf(var + 1e-5f);
    const f32x4* g4 = (const f32x4*)gamma;
    const f32x4* b4 = (const f32x4*)betap;
    f32x4 g0 = g4[l * 2], g1 = g4[l * 2 + 1], e0 = b4[l * 2], e1 = b4[l * 2 + 1];
    short8 o;
    #pragma unroll
    for (int j = 0; j < 4; ++j) o[j]     = (short)f2bf((a[j] - mean) * rstd * g0[j] + e0[j]);
    #pragma unroll
    for (int j = 0; j < 4; ++j) o[4 + j] = (short)f2bf((b[j] - mean) * rstd * g1[j] + e1[j]);
    ((short8*)(h + (size_t)row * INDIM))[l] = o;
}

// ---------------- weight transpose+permute ----------------
__global__ __launch_bounds__(256) void cvt_wslow(const float* __restrict__ w,
                                                 unsigned short* __restrict__ wT) {
    int idx = blockIdx.x * 256 + threadIdx.x;   // NPAD2*512
    int n = idx >> 9, k = idx & 511;
    int c;
    if (n < 512)       c = (n >> 6) * 193 + (n & 63);
    else if (n < 1024) c = ((n - 512) >> 6) * 193 + 64 + (n & 63);
    else if (n < 1536) c = ((n - 1024) >> 6) * 193 + 128 + (n & 63);
    else if (n < 1544) c = (n - 1536) * 193 + 192;
    else               c = -1;
    wT[idx] = (c >= 0) ? f2bf(w[(size_t)k * NQKV + c]) : (unsigned short)0;
}
__global__ __launch_bounds__(256) void cvt_wout(const float* __restrict__ w,
                                                unsigned short* __restrict__ wT) {
    int idx = blockIdx.x * 256 + threadIdx.x;
    int n = idx >> 9, k = idx & 511;
    wT[idx] = f2bf(w[(size_t)k * 512 + n]);
}

// ---------------- GEMM1 fused, 256x256 tile, 8 waves, counted-vmcnt double buffer ----------------
__global__ __launch_bounds__(512, 2) void gemm_qkv(const unsigned short* __restrict__ A,
                                                   const unsigned short* __restrict__ BT,
                                                   unsigned short* __restrict__ qn,
                                                   unsigned short* __restrict__ kn,
                                                   unsigned short* __restrict__ vn,
                                                   float* __restrict__ bet) {
    __shared__ unsigned short As[2][256 * 64];   // 64 KB
    __shared__ unsigned short Bs[2][256 * 64];   // 64 KB
    const int tid = threadIdx.x;
    const int id = blockIdx.y * 7 + blockIdx.x;       // 896 = 8*112
    const int newid = (id & 7) * 112 + (id >> 3);     // bijective XCD chunking
    const int bx = newid % 7;
    const int n0 = bx * 256;
    const int m0 = (newid / 7) * 256;
    const int w = tid >> 6, l = tid & 63;
    const int wm = w >> 2, wn = w & 3;                // 2M x 4N waves
    const int lr = l & 15, lk8 = (l >> 4) * 8;
    f32x4 acc[8][4] = {};

    auto STAGE = [&](int buf, int kt) {
        #pragma unroll
        for (int c2 = 0; c2 < 4; ++c2) {
            int idx = c2 * 512 + tid;                 // 0..2047
            int row = idx >> 3, kc2 = (idx & 7) * 8;
            int lb = (c2 * 512 + (tid & 448)) * 8;    // wave-uniform LDS base (elements)
            GLOAD16(A  + (size_t)(m0 + row) * INDIM + kt + kc2, &As[buf][lb]);
            GLOAD16(BT + (size_t)(n0 + row) * INDIM + kt + kc2, &Bs[buf][lb]);
        }
    };
    auto COMPUTE = [&](int buf) {
        short8 bf2[4][2];
        #pragma unroll
        for (int ni = 0; ni < 4; ++ni)
            #pragma unroll
            for (int kk = 0; kk < 2; ++kk)
                bf2[ni][kk] = *(const short8*)&Bs[buf][(wn * 64 + ni * 16 + lr) * 64 + kk * 32 + lk8];
        #pragma unroll
        for (int p = 0; p < 4; ++p) {
            short8 af[2][2];
            #pragma unroll
            for (int d = 0; d < 2; ++d)
                #pragma unroll
                for (int kk = 0; kk < 2; ++kk)
                    af[d][kk] = *(const short8*)&As[buf][(wm * 128 + (2 * p + d) * 16 + lr) * 64 + kk * 32 + lk8];
            #pragma unroll
            for (int d = 0; d < 2; ++d)
                #pragma unroll
                for (int ni = 0; ni < 4; ++ni)
                    #pragma unroll
                    for (int kk = 0; kk < 2; ++kk)
                        acc[2 * p + d][ni] =
                            __builtin_amdgcn_mfma_f32_16x16x32_bf16(af[d][kk], bf2[ni][kk], acc[2 * p + d][ni], 0, 0, 0);
        }
    };

    // prologue: tiles 0,1 in flight (16 loads/lane)
    STAGE(0, 0);
    STAGE(1, 64);
    // pipeline: tiles consumed in pairs; stage t+2 right after t is consumed
    #pragma unroll
    for (int tp = 0; tp < 4; ++tp) {
        VMCNT8();                 // tile 2tp landed (8 = tile 2tp+1 outstanding)
        SBAR();
        COMPUTE(0);               // tile 2tp from buf0
        SBAR();                   // buf0 fully consumed by all waves
        if (tp < 3) {
            STAGE(0, (2 * tp + 2) * 64);   // outstanding: 2tp+1 (8) + 2tp+2 (8)
            VMCNT8();             // tile 2tp+1 landed
        } else {
            VMCNT0();             // tail: only tile 7 outstanding
        }
        SBAR();
        COMPUTE(1);               // tile 2tp+1 from buf1
        SBAR();                   // buf1 fully consumed
        if (tp < 3) STAGE(1, (2 * tp + 3) * 64);
    }

    // ---- fused epilogue ----
    const int g = l >> 4, cc = l & 15;
    const int colbase = n0 + wn * 64;
    if (bx < 6) {
        const int reg  = colbase >> 9;            // 0=q,1=k,2=v (strip-uniform)
        const int head = (colbase >> 6) & 7;
        unsigned short* dst = (reg == 0) ? qn : (reg == 1) ? kn : vn;
        #pragma unroll
        for (int mi = 0; mi < 8; ++mi) {
            #pragma unroll
            for (int j = 0; j < 4; ++j) {
                int row = m0 + wm * 128 + mi * 16 + g * 4 + j;
                int s = row >> 5, b = row & 31;
                size_t base = ((size_t)(b * H_ + head) * SLEN + s) * 64;
                float e0 = acc[mi][0][j], e1 = acc[mi][1][j], e2 = acc[mi][2][j], e3 = acc[mi][3][j];
                if (reg < 2) {
                    e0 = e0 > 0.f ? e0 + 1.f : __expf(e0);
                    e1 = e1 > 0.f ? e1 + 1.f : __expf(e1);
                    e2 = e2 > 0.f ? e2 + 1.f : __expf(e2);
                    e3 = e3 > 0.f ? e3 + 1.f : __expf(e3);
                    float ssum = (e0 + e1) + (e2 + e3);
                    ssum += __shfl_xor(ssum, 1);
                    ssum += __shfl_xor(ssum, 2);
                    ssum += __shfl_xor(ssum, 4);
                    ssum += __shfl_xor(ssum, 8);
                    float inv = 1.f / ssum;
                    e0 *= inv; e1 *= inv; e2 *= inv; e3 *= inv;
                }
                dst[base +  0 + cc] = f2bf(e0);
                dst[base + 16 + cc] = f2bf(e1);
                dst[base + 32 + cc] = f2bf(e2);
                dst[base + 48 + cc] = f2bf(e3);
            }
        }
    } else {
        // bx==6: beta cols 1536..1543 live in strip wn==0, frag ni=0, cc<8; rest is pad
        if (wn == 0 && cc < 8) {
            #pragma unroll
            for (int mi = 0; mi < 8; ++mi)
                #pragma unroll
                for (int j = 0; j < 4; ++j) {
                    int row = m0 + wm * 128 + mi * 16 + g * 4 + j;
                    int s = row >> 5, b = row & 31;
                    float v = acc[mi][0][j];
                    bet[(size_t)(b * H_ + cc) * SLEN + s] = 1.f / (1.f + __expf(-v));
                }
        }
    }
}

// ---------------- GEMM2: out = x + outs @ woT^T (XCD-chunked swizzle) ----------------
__global__ __launch_bounds__(256) void gemm_out(const unsigned short* __restrict__ A,
                                                const unsigned short* __restrict__ BT,
                                                const float* __restrict__ X,
                                                float* __restrict__ outf) {
    __shared__ unsigned short As[128 * 64];
    __shared__ unsigned short Bs[128 * 64];
    const int t  = threadIdx.x;
    const int id = blockIdx.y * 4 + blockIdx.x;
    const int newid = (id & 7) * 128 + (id >> 3);
    const int n0 = (newid % 4) * 128;
    const int m0 = (newid / 4) * 128;
    const int w = t >> 6, l = t & 63;
    const int wr = (w >> 1) * 64, wc = (w & 1) * 64;
    f32x4 acc[4][4] = {};
    for (int kt = 0; kt < INDIM; kt += 64) {
        __syncthreads();
        #pragma unroll
        for (int c = 0; c < 4; ++c) {
            int idx = c * 256 + t;
            int row = idx >> 3, kc2 = (idx & 7) * 8;
            int lb = (c * 256 + (t & 192)) * 8;
            GLOAD16(A  + (size_t)(m0 + row) * INDIM + kt + kc2, &As[lb]);
            GLOAD16(BT + (size_t)(n0 + row) * INDIM + kt + kc2, &Bs[lb]);
        }
        __syncthreads();
        #pragma unroll
        for (int kk = 0; kk < 2; ++kk) {
            const int kr = kk * 32 + (l >> 4) * 8;
            short8 af[4], bf[4];
            #pragma unroll
            for (int m = 0; m < 4; ++m) af[m] = *(const short8*)&As[(wr + m * 16 + (l & 15)) * 64 + kr];
            #pragma unroll
            for (int n = 0; n < 4; ++n) bf[n] = *(const short8*)&Bs[(wc + n * 16 + (l & 15)) * 64 + kr];
            #pragma unroll
            for (int m = 0; m < 4; ++m)
                #pragma unroll
                for (int n = 0; n < 4; ++n)
                    acc[m][n] = __builtin_amdgcn_mfma_f32_16x16x32_bf16(af[m], bf[n], acc[m][n], 0, 0, 0);
        }
    }
    const int rb = (l >> 4) * 4, cc = l & 15;
    #pragma unroll
    for (int m = 0; m < 4; ++m)
        #pragma unroll
        for (int n = 0; n < 4; ++n)
            #pragma unroll
            for (int j = 0; j < 4; ++j) {
                int row = m0 + wr + m * 16 + rb + j;
                int col = n0 + wc + n * 16 + cc;
                size_t o = (size_t)row * 512 + col;
                outf[o] = X[o] + acc[m][n][j];
            }
}

// ---------------- phase 1 v3: per-(bh,chunk) WY tile factors, 8 waves, conflict-fixed ----------------
__global__ __launch_bounds__(512, 4) void fwtiles(const unsigned short* __restrict__ qn,
                                                  const unsigned short* __restrict__ kn,
                                                  const unsigned short* __restrict__ vn,
                                                  const float* __restrict__ beta,
                                                  unsigned short* __restrict__ tiles,
                                                  unsigned short* __restrict__ outs) {
    __shared__ unsigned short Ax[64 * PB], Atr[64 * PB], Pw[64 * PB], Pwtr[64 * PB];
    __shared__ unsigned short Z0[128 * PB], Z1[128 * PB];
    __shared__ float bv[64];
    const int bx = blockIdx.x;
    const int bh = bx >> 4, c = bx & 15;
    const int b = bh >> 3, h = bh & 7;
    const int c0 = c * 64;
    const int tid = threadIdx.x;
    const int w = tid >> 6, l = tid & 63;
    const int mw = w & 3, nh = w >> 2;
    const int lr = l & 15, lk = (l >> 4) << 3, rb = (l >> 4) << 2;
    const unsigned short* kc = kn + ((size_t)bh * SLEN + c0) * 64;
    const unsigned short* qc = qn + ((size_t)bh * SLEN + c0) * 64;
    const unsigned short* vc = vn + ((size_t)bh * SLEN + c0) * 64;
    const float* bb = beta + (size_t)bh * SLEN + c0;

    {
        #pragma unroll
        for (int i = 0; i < 2; ++i) {
            int idx = i * 512 + tid;
            int row = idx >> 3, seg = idx & 7;
            const unsigned short* src = (row < 64) ? (vc + (size_t)row * 64 + seg * 8)
                                                   : (kc + (size_t)(row - 64) * 64 + seg * 8);
            *(ushort8*)&Z1[row * PB + seg * 8] = *(const ushort8*)src;
        }
        if (tid < 64) bv[tid] = bb[tid];
        ushort8 z8 = {};
        for (int i = tid; i < 576; i += 512) { ((ushort8*)Ax)[i] = z8; ((ushort8*)Atr)[i] = z8; }
    }
    __syncthreads();

    auto ldb = [&](const unsigned short* M, int m, int kk) -> short8 {
        return *(const short8*)&M[(m * 16 + lr) * PB + kk * 32 + lk];
    };

    {
        const int zoff2 = (w >> 2) * 64;
        const int tbase = (w & 3) * 16;
        const float sgn = (w >= 4) ? -1.f : 1.f;
        ushort8 b0v, b1v;
        #pragma unroll
        for (int i = 0; i < 16; ++i) {
            int r = w * 16 + i;
            float val = sgn * bv[tbase + i] * bf2f(Z1[r * PB + l]);
            unsigned short uv = f2bf(val);
            if (i < 8) b0v[i] = uv; else b1v[i - 8] = uv;
        }
        *(ushort8*)&Z0[(zoff2 + l) * PB + tbase]     = b0v;
        *(ushort8*)&Z0[(zoff2 + l) * PB + tbase + 8] = b1v;
    }
    {
        const int pm[10] = {0, 1, 1, 2, 2, 2, 3, 3, 3, 3};
        const int pn[10] = {0, 0, 1, 0, 1, 2, 0, 1, 2, 3};
        for (int pi = w; pi < 10; pi += 8) {
            int m = pm[pi], n = pn[pi];
            short8 ka0 = *(const short8*)&Z1[(64 + 16 * m + lr) * PB + lk];
            short8 ka1 = *(const short8*)&Z1[(64 + 16 * m + lr) * PB + 32 + lk];
            short8 kb0 = *(const short8*)&Z1[(64 + 16 * n + lr) * PB + lk];
            short8 kb1 = *(const short8*)&Z1[(64 + 16 * n + lr) * PB + 32 + lk];
            f32x4 a = {};
            a = __builtin_amdgcn_mfma_f32_16x16x32_bf16(ka0, kb0, a, 0, 0, 0);
            a = __builtin_amdgcn_mfma_f32_16x16x32_bf16(ka1, kb1, a, 0, 0, 0);
            f32x4 btm = *(const f32x4*)&bv[16 * m + rb];
            short4v pk;
            #pragma unroll
            for (int j = 0; j < 4; ++j) {
                int tt = 16 * m + rb + j, s = 16 * n + lr;
                unsigned short v = (s < tt) ? f2bf(-btm[j] * a[j]) : (unsigned short)0;
                Ax[tt * PB + s] = v;
                pk[j] = (short)v;
            }
            *(short4v*)&Atr[(16 * n + lr) * PB + 16 * m + rb] = pk;
        }
    }
    __syncthreads();

    auto zprod = [&](const unsigned short* Xb, int p, const unsigned short* Zs, unsigned short* Zd) {
        const bool msk0 = (16 * mw + 15 >= p), msk1 = (16 * mw + 15 - 32 >= p);
        short8 xf0, xf1;
        if (msk0) xf0 = ldb(Xb, mw, 0);
        if (msk1) xf1 = ldb(Xb, mw, 1);
        #pragma unroll
        for (int ni = 0; ni < 4; ++ni) {
            int n = nh * 4 + ni;
            short4v zi = *(const short4v*)&Zs[(16 * n + lr) * PB + 16 * mw + rb];
            f32x4 a;
            #pragma unroll
            for (int j = 0; j < 4; ++j) a[j] = bf2f((unsigned short)zi[j]);
            if (msk0) a = __builtin_amdgcn_mfma_f32_16x16x32_bf16(xf0, ldb(Zs, n, 0), a, 0, 0, 0);
            if (msk1) a = __builtin_amdgcn_mfma_f32_16x16x32_bf16(xf1, ldb(Zs, n, 1), a, 0, 0, 0);
            short4v zo;
            #pragma unroll
            for (int j = 0; j < 4; ++j) zo[j] = (short)f2bf(a[j]);
            *(short4v*)&Zd[(16 * n + lr) * PB + 16 * mw + rb] = zo;
        }
    };
    auto powp = [&](const unsigned short* Ps, const unsigned short* Pstr, int p,
                    unsigned short* Pd, unsigned short* Pdtr) {
        const bool x0 = (16 * mw + 15 >= p), x1 = (16 * mw + 15 - 32 >= p);
        short8 xf0, xf1;
        if (x0) xf0 = ldb(Ps, mw, 0);
        if (x1) xf1 = ldb(Ps, mw, 1);
        #pragma unroll
        for (int ni = 0; ni < 2; ++ni) {
            int n = nh * 2 + ni;
            const bool y0 = (31 - 16 * n >= p), y1 = (63 - 16 * n >= p);
            f32x4 a = {};
            if (x0 && y0) a = __builtin_amdgcn_mfma_f32_16x16x32_bf16(xf0, ldb(Pstr, n, 0), a, 0, 0, 0);
            if (x1 && y1) a = __builtin_amdgcn_mfma_f32_16x16x32_bf16(xf1, ldb(Pstr, n, 1), a, 0, 0, 0);
            short4v pk;
            #pragma unroll
            for (int j = 0; j < 4; ++j) {
                unsigned short v = f2bf(a[j]);
                Pd[(16 * mw + rb + j) * PB + 16 * n + lr] = v;
                pk[j] = (short)v;
            }
            *(short4v*)&Pdtr[(16 * n + lr) * PB + 16 * mw + rb] = pk;
        }
    };

    zprod(Ax, 1, Z0, Z1);  powp(Ax, Atr, 1, Pw, Pwtr);  __syncthreads();
    zprod(Pw, 2, Z1, Z0);  powp(Pw, Pwtr, 2, Ax, Atr);  __syncthreads();
    zprod(Ax, 4, Z0, Z1);  powp(Ax, Atr, 4, Pw, Pwtr);  __syncthreads();
    zprod(Pw, 8, Z1, Z0);  powp(Pw, Pwtr, 8, Ax, Atr);  __syncthreads();
    zprod(Ax, 16, Z0, Z1); powp(Ax, Atr, 16, Pw, Pwtr); __syncthreads();
    zprod(Pw, 32, Z1, Z0);
    __syncthreads();

    {
        #pragma unroll
        for (int i = 0; i < 2; ++i) {
            int idx = i * 512 + tid;
            int row = idx >> 3, seg = idx & 7;
            const unsigned short* src = (row < 64) ? (qc + (size_t)row * 64 + seg * 8)
                                                   : (kc + (size_t)(row - 64) * 64 + seg * 8);
            *(ushort8*)&Z1[row * PB + seg * 8] = *(const ushort8*)src;
        }
    }
    __syncthreads();

    {
        short8 qa0 = *(const short8*)&Z1[(16 * mw + lr) * PB + lk];
        short8 qa1 = *(const short8*)&Z1[(16 * mw + lr) * PB + 32 + lk];
        #pragma unroll
        for (int ni = 0; ni < 2; ++ni) {
            int n = nh * 2 + ni;
            short8 kb0 = *(const short8*)&Z1[(64 + 16 * n + lr) * PB + lk];
            short8 kb1 = *(const short8*)&Z1[(64 + 16 * n + lr) * PB + 32 + lk];
            f32x4 a = {};
            a = __builtin_amdgcn_mfma_f32_16x16x32_bf16(qa0, kb0, a, 0, 0, 0);
            a = __builtin_amdgcn_mfma_f32_16x16x32_bf16(qa1, kb1, a, 0, 0, 0);
            #pragma unroll
            for (int j = 0; j < 4; ++j) {
                int tt = 16 * mw + rb + j, s = 16 * n + lr;
                Ax[tt * PB + s] = (s <= tt) ? f2bf(a[j]) : (unsigned short)0;
            }
        }
        ushort8 kv;
        #pragma unroll
        for (int j = 0; j < 8; ++j)
            kv[j] = Z1[(64 + w * 8 + j) * PB + l];
        *(ushort8*)&Pwtr[l * PB + w * 8] = kv;
    }
    __syncthreads();

    {
        unsigned short* tb = tiles + ((size_t)bh * 16 + c) * 12288;
        short8 pA0 = ldb(Ax, mw, 0), pA1 = ldb(Ax, mw, 1);
        short8 zA0 = ldb(Z0, mw, 0), zA1 = ldb(Z0, mw, 1);
        short8 kt0 = ldb(Pwtr, mw, 0), kt1 = ldb(Pwtr, mw, 1);
        #pragma unroll
        for (int ni = 0; ni < 2; ++ni) {
            int n = nh * 2 + ni;
            f32x4 aN = {};
            aN = __builtin_amdgcn_mfma_f32_16x16x32_bf16(zA0, ldb(Pwtr, n, 0), aN, 0, 0, 0);
            aN = __builtin_amdgcn_mfma_f32_16x16x32_bf16(zA1, ldb(Pwtr, n, 1), aN, 0, 0, 0);
            f32x4 aM = {};
            aM = __builtin_amdgcn_mfma_f32_16x16x32_bf16(kt0, ldb(Z0, 4 + n, 0), aM, 0, 0, 0);
            aM = __builtin_amdgcn_mfma_f32_16x16x32_bf16(kt1, ldb(Z0, 4 + n, 1), aM, 0, 0, 0);
            f32x4 aG;
            #pragma unroll
            for (int j = 0; j < 4; ++j) aG[j] = bf2f(Z1[(16 * mw + rb + j) * PB + 16 * n + lr]);
            aG = __builtin_amdgcn_mfma_f32_16x16x32_bf16(pA0, ldb(Z0, 4 + n, 0), aG, 0, 0, 0);
            aG = __builtin_amdgcn_mfma_f32_16x16x32_bf16(pA1, ldb(Z0, 4 + n, 1), aG, 0, 0, 0);
            f32x4 aP = {};
            aP = __builtin_amdgcn_mfma_f32_16x16x32_bf16(pA0, ldb(Z0, n, 0), aP, 0, 0, 0);
            aP = __builtin_amdgcn_mfma_f32_16x16x32_bf16(pA1, ldb(Z0, n, 1), aP, 0, 0, 0);
            #pragma unroll
            for (int j = 0; j < 4; ++j) {
                int r = 16 * mw + rb + j, cl = 16 * n + lr;
                tb[r * 64 + cl]        = f2bf(aM[j]);
                tb[4096 + r * 64 + cl] = f2bf(aG[j]);
                tb[8192 + r * 64 + cl] = f2bf(aN[j]);
                outs[((size_t)(c0 + r) * BSZ + b) * 512 + h * 64 + cl] = f2bf(aP[j]);
            }
        }
    }
}

// ---------------- phase 2a: W-only scan with register prefetch; stores bf16 W checkpoints ----------------
__global__ __launch_bounds__(256) void fwscan_w(const unsigned short* __restrict__ tiles,
                                                unsigned short* __restrict__ wchk) {
    __shared__ float Wf[64 * 68];
    const int bh = blockIdx.x;
    const int tid = threadIdx.x;
    const int w = tid >> 6, l = tid & 63;
    const int lr = l & 15, lk = (l >> 4) << 3, rb = (l >> 4) << 2;
    const int cr = l >> 3, cc8 = (l & 7) * 8;
    #pragma unroll
    for (int j = 0; j < 16; ++j) Wf[(16 * w + j) * 68 + l] = 0.f;

    const unsigned short* tb0 = tiles + (size_t)bh * 16 * 12288;
    unsigned short* wc0 = wchk + (size_t)bh * 16 * 4096;

    auto loadc = [&](short8 (&MT)[4][2], unsigned short (&NV)[4][4], int c) {
        const unsigned short* tb = tb0 + (size_t)c * 12288;
        #pragma unroll
        for (int n = 0; n < 4; ++n) {
            MT[n][0] = *(const short8*)(tb + (size_t)(16 * n + lr) * 64 + lk);
            MT[n][1] = *(const short8*)(tb + (size_t)(16 * n + lr) * 64 + 32 + lk);
            #pragma unroll
            for (int j = 0; j < 4; ++j)
                NV[n][j] = tb[8192 + (size_t)(16 * w + rb + j) * 64 + 16 * n + lr];
        }
    };
    auto stepc = [&](short8 (&MT)[4][2], unsigned short (&NV)[4][4], int c) {
        #pragma unroll
        for (int half = 0; half < 2; ++half) {
            int row = 16 * w + half * 8 + cr;
            const float* p = &Wf[row * 68 + cc8];
            f32x4 x0 = *(const f32x4*)p, x1 = *(const f32x4*)(p + 4);
            ushort8 o;
            #pragma unroll
            for (int j = 0; j < 4; ++j) { o[j] = f2bf(x0[j]); o[4 + j] = f2bf(x1[j]); }
            *(ushort8*)(wc0 + (size_t)c * 4096 + row * 64 + cc8) = o;
        }
        short8 wf0, wf1;
        {
            const float* p0 = &Wf[(16 * w + lr) * 68 + lk];
            f32x4 a0 = *(const f32x4*)p0, b0 = *(const f32x4*)(p0 + 4);
            f32x4 a1 = *(const f32x4*)(p0 + 32), b1 = *(const f32x4*)(p0 + 36);
            #pragma unroll
            for (int j = 0; j < 4; ++j) {
                wf0[j] = (short)f2bf(a0[j]); wf0[4 + j] = (short)f2bf(b0[j]);
                wf1[j] = (short)f2bf(a1[j]); wf1[4 + j] = (short)f2bf(b1[j]);
            }
        }
        #pragma unroll
        for (int n = 0; n < 4; ++n) {
            f32x4 a;
            #pragma unroll
            for (int j = 0; j < 4; ++j)
                a[j] = Wf[(16 * w + rb + j) * 68 + 16 * n + lr] + bf2f(NV[n][j]);
            a = __builtin_amdgcn_mfma_f32_16x16x32_bf16(wf0, MT[n][0], a, 0, 0, 0);
            a = __builtin_amdgcn_mfma_f32_16x16x32_bf16(wf1, MT[n][1], a, 0, 0, 0);
            #pragma unroll
            for (int j = 0; j < 4; ++j) Wf[(16 * w + rb + j) * 68 + 16 * n + lr] = a[j];
        }
    };

    short8 mtA[4][2], mtB[4][2];
    unsigned short nvA[4][4], nvB[4][4];
    loadc(mtA, nvA, 0);
    #pragma unroll 1
    for (int cc = 0; cc < 8; ++cc) {
        int c = 2 * cc;
        if (c + 1 < 16) loadc(mtB, nvB, c + 1);
        stepc(mtA, nvA, c);
        if (c + 2 < 16) loadc(mtA, nvA, c + 2);
        stepc(mtB, nvB, c + 1);
    }
}

// ---------------- phase 2b: O finalize, parallel over (chunk 1..15, bh) ----------------
__global__ __launch_bounds__(256) void fw_o(const unsigned short* __restrict__ tiles,
                                            const unsigned short* __restrict__ wchk,
                                            unsigned short* __restrict__ outs) {
    __shared__ unsigned short Ot[64 * 72];
    const int c = blockIdx.x + 1;
    const int bh = blockIdx.y;
    const int b = bh >> 3, h = bh & 7;
    const int c0 = c * 64;
    const int tid = threadIdx.x;
    const int w = tid >> 6, l = tid & 63;
    const int lr = l & 15, lk = (l >> 4) << 3, rb = (l >> 4) << 2;
    const unsigned short* G  = tiles + ((size_t)bh * 16 + c) * 12288 + 4096;
    const unsigned short* W0 = wchk + ((size_t)bh * 16 + c) * 4096;

    #pragma unroll
    for (int i = 0; i < 2; ++i) {
        int idx = i * 256 + tid;
        int t = idx >> 3, d0 = (idx & 7) * 8;
        *(ushort8*)&Ot[t * 72 + d0] =
            *(const ushort8*)(outs + ((size_t)(c0 + t) * BSZ + b) * 512 + h * 64 + d0);
    }
    __syncthreads();

    short8 g0 = *(const short8*)(G + (size_t)(16 * w + lr) * 64 + lk);
    short8 g1 = *(const short8*)(G + (size_t)(16 * w + lr) * 64 + 32 + lk);
    #pragma unroll
    for (int n = 0; n < 4; ++n) {
        short8 wf0 = *(const short8*)(W0 + (size_t)(16 * n + lr) * 64 + lk);
        short8 wf1 = *(const short8*)(W0 + (size_t)(16 * n + lr) * 64 + 32 + lk);
        f32x4 a;
        #pragma unroll
        for (int j = 0; j < 4; ++j) a[j] = bf2f(Ot[(16 * w + rb + j) * 72 + 16 * n + lr]);
        a = __builtin_amdgcn_mfma_f32_16x16x32_bf16(g0, wf0, a, 0, 0, 0);
        a = __builtin_amdgcn_mfma_f32_16x16x32_bf16(g1, wf1, a, 0, 0, 0);
        #pragma unroll
        for (int j = 0; j < 4; ++j) Ot[(16 * w + rb + j) * 72 + 16 * n + lr] = f2bf(a[j]);
    }
    __syncthreads();

    #pragma unroll
    for (int i = 0; i < 2; ++i) {
        int idx = i * 256 + tid;
        int t = idx >> 3, d0 = (idx & 7) * 8;
        *(ushort8*)(outs + ((size_t)(c0 + t) * BSZ + b) * 512 + h * 64 + d0) =
            *(const ushort8*)&Ot[t * 72 + d0];
    }
}

// ---------------- launch ----------------
extern "C" void kernel_launch(void* const* d_in, const int* in_sizes, int n_in,
                              void* d_out, int out_size, void* d_ws, size_t ws_size,
                              hipStream_t stream) {
    const float* x      = (const float*)d_in[0];
    const float* g      = (const float*)d_in[1];
    const float* be     = (const float*)d_in[2];
    const float* w_slow = (const float*)d_in[3];
    const float* w_out  = (const float*)d_in[4];
    float* out = (float*)d_out;
    char* ws = (char*)d_ws;

    unsigned short* h    = (unsigned short*)(ws);
    unsigned short* outs = (unsigned short*)(ws);                 // alias h
    unsigned short* qn   = (unsigned short*)(ws + 33554432);
    unsigned short* wchk = (unsigned short*)(ws + 33554432);      // alias qn (dead after fwtiles)
    unsigned short* kn   = (unsigned short*)(ws + 67108864);
    unsigned short* vn   = (unsigned short*)(ws + 100663296);
    float*          bet  = (float*)         (ws + 134217728);
    unsigned short* wsT  = (unsigned short*)(ws + 135266304);     // 1792*512*2 = 1,835,008
    unsigned short* woT  = (unsigned short*)(ws + 137101312);     //   524,288
    unsigned short* tiles= (unsigned short*)(ws + 137625600);     // 100,663,296

    if (ws_size < 238288896) return;

    ln_kernel<<<8192, 256, 0, stream>>>(x, g, be, h);
    cvt_wslow<<<(NPAD2 * 512) / 256, 256, 0, stream>>>(w_slow, wsT);
    cvt_wout<<<(512 * 512) / 256, 256, 0, stream>>>(w_out, woT);
    gemm_qkv<<<dim3(7, MROWS / 256), 512, 0, stream>>>(h, wsT, qn, kn, vn, bet);
    fwtiles<<<BSZ * H_ * 16, 512, 0, stream>>>(qn, kn, vn, bet, tiles, outs);
    fwscan_w<<<BSZ * H_, 256, 0, stream>>>(tiles, wchk);
    fw_o<<<dim3(15, BSZ * H_), 256, 0, stream>>>(tiles, wchk, outs);
    gemm_out<<<dim3(4, MROWS / 128), 256, 0, stream>>>(outs, woT, x, out);
}

// Round 12
// 337.493 us; speedup vs baseline: 2.5883x; 1.0062x over previous
//
#include <hip/hip_runtime.h>
#include <cstdint>

using short8  = __attribute__((ext_vector_type(8))) short;
using ushort8 = __attribute__((ext_vector_type(8))) unsigned short;
using short4v = __attribute__((ext_vector_type(4))) short;
using f32x4   = __attribute__((ext_vector_type(4))) float;

#define H_    8
#define SLEN  1024
#define BSZ   32
#define INDIM 512
#define NQKV  1544   // H*(3*D+1)
#define NPAD2 1792   // 7*256 (gemm_qkv N padding)
#define MROWS 32768  // SLEN*BSZ
#define PB    72     // bf16 LDS pad stride

#define GLOAD16(gp, lp) __builtin_amdgcn_global_load_lds( \
    (const __attribute__((address_space(1))) void*)(gp),  \
    (__attribute__((address_space(3))) void*)(lp), 16, 0, 0)

#define VMCNT8() do { asm volatile("s_waitcnt vmcnt(8)" ::: "memory"); \
                      __builtin_amdgcn_sched_barrier(0); } while (0)
#define VMCNT0() do { asm volatile("s_waitcnt vmcnt(0)" ::: "memory"); \
                      __builtin_amdgcn_sched_barrier(0); } while (0)
#define SBAR()   do { __builtin_amdgcn_sched_barrier(0); \
                      __builtin_amdgcn_s_barrier(); \
                      __builtin_amdgcn_sched_barrier(0); } while (0)

static __device__ __forceinline__ float bf2f(unsigned short s) {
    return __uint_as_float(((unsigned int)s) << 16);
}
#if defined(__BF16_MANT_DIG__)
static __device__ __forceinline__ unsigned short f2bf(float f) {
    union { __bf16 b; unsigned short u; } cv;
    cv.b = (__bf16)f;
    return cv.u;
}
#else
static __device__ __forceinline__ unsigned short f2bf(float f) {
    unsigned int u = __float_as_uint(f);
    u += 0x7FFFu + ((u >> 16) & 1u);
    return (unsigned short)(u >> 16);
}
#endif

// ---------------- LayerNorm: x[32768][512] f32 -> h bf16 ----------------
__global__ __launch_bounds__(256) void ln_kernel(const float* __restrict__ x,
                                                 const float* __restrict__ gamma,
                                                 const float* __restrict__ betap,
                                                 unsigned short* __restrict__ h) {
    int row = blockIdx.x * 4 + (threadIdx.x >> 6);
    int l   = threadIdx.x & 63;
    const f32x4* xr = (const f32x4*)(x + (size_t)row * INDIM);
    f32x4 a = xr[l * 2], b = xr[l * 2 + 1];
    float s = 0.f, sq = 0.f;
    #pragma unroll
    for (int j = 0; j < 4; ++j) { s += a[j]; sq += a[j] * a[j]; }
    #pragma unroll
    for (int j = 0; j < 4; ++j) { s += b[j]; sq += b[j] * b[j]; }
    #pragma unroll
    for (int off = 32; off; off >>= 1) { s += __shfl_xor(s, off); sq += __shfl_xor(sq, off); }
    float mean = s * (1.f / 512.f);
    float var  = sq * (1.f / 512.f) - mean * mean;
    float rstd = rsqrtf(var + 1e-5f);
    const f32x4* g4 = (const f32x4*)gamma;
    const f32x4* b4 = (const f32x4*)betap;
    f32x4 g0 = g4[l * 2], g1 = g4[l * 2 + 1], e0 = b4[l * 2], e1 = b4[l * 2 + 1];
    short8 o;
    #pragma unroll
    for (int j = 0; j < 4; ++j) o[j]     = (short)f2bf((a[j] - mean) * rstd * g0[j] + e0[j]);
    #pragma unroll
    for (int j = 0; j < 4; ++j) o[4 + j] = (short)f2bf((b[j] - mean) * rstd * g1[j] + e1[j]);
    ((short8*)(h + (size_t)row * INDIM))[l] = o;
}

// ---------------- weight transpose+permute ----------------
__global__ __launch_bounds__(256) void cvt_wslow(const float* __restrict__ w,
                                                 unsigned short* __restrict__ wT) {
    int idx = blockIdx.x * 256 + threadIdx.x;   // NPAD2*512
    int n = idx >> 9, k = idx & 511;
    int c;
    if (n < 512)       c = (n >> 6) * 193 + (n & 63);
    else if (n < 1024) c = ((n - 512) >> 6) * 193 + 64 + (n & 63);
    else if (n < 1536) c = ((n - 1024) >> 6) * 193 + 128 + (n & 63);
    else if (n < 1544) c = (n - 1536) * 193 + 192;
    else               c = -1;
    wT[idx] = (c >= 0) ? f2bf(w[(size_t)k * NQKV + c]) : (unsigned short)0;
}
__global__ __launch_bounds__(256) void cvt_wout(const float* __restrict__ w,
                                                unsigned short* __restrict__ wT) {
    int idx = blockIdx.x * 256 + threadIdx.x;
    int n = idx >> 9, k = idx & 511;
    wT[idx] = f2bf(w[(size_t)k * 512 + n]);
}

// ---------------- GEMM1 fused, 256x256 tile, 8 waves, counted-vmcnt double buffer ----------------
__global__ __launch_bounds__(512, 2) void gemm_qkv(const unsigned short* __restrict__ A,
                                                   const unsigned short* __restrict__ BT,
                                                   unsigned short* __restrict__ qn,
                                                   unsigned short* __restrict__ kn,
                                                   unsigned short* __restrict__ vn,
                                                   float* __restrict__ bet) {
    __shared__ unsigned short As[2][256 * 64];
    __shared__ unsigned short Bs[2][256 * 64];
    const int tid = threadIdx.x;
    const int id = blockIdx.y * 7 + blockIdx.x;       // 896 = 8*112
    const int newid = (id & 7) * 112 + (id >> 3);     // bijective XCD chunking
    const int bx = newid % 7;
    const int n0 = bx * 256;
    const int m0 = (newid / 7) * 256;
    const int w = tid >> 6, l = tid & 63;
    const int wm = w >> 2, wn = w & 3;
    const int lr = l & 15, lk8 = (l >> 4) * 8;
    f32x4 acc[8][4] = {};

    auto STAGE = [&](int buf, int kt) {
        #pragma unroll
        for (int c2 = 0; c2 < 4; ++c2) {
            int idx = c2 * 512 + tid;
            int row = idx >> 3, kc2 = (idx & 7) * 8;
            int lb = (c2 * 512 + (tid & 448)) * 8;
            GLOAD16(A  + (size_t)(m0 + row) * INDIM + kt + kc2, &As[buf][lb]);
            GLOAD16(BT + (size_t)(n0 + row) * INDIM + kt + kc2, &Bs[buf][lb]);
        }
    };
    auto COMPUTE = [&](int buf) {
        short8 bf2[4][2];
        #pragma unroll
        for (int ni = 0; ni < 4; ++ni)
            #pragma unroll
            for (int kk = 0; kk < 2; ++kk)
                bf2[ni][kk] = *(const short8*)&Bs[buf][(wn * 64 + ni * 16 + lr) * 64 + kk * 32 + lk8];
        #pragma unroll
        for (int p = 0; p < 4; ++p) {
            short8 af[2][2];
            #pragma unroll
            for (int d = 0; d < 2; ++d)
                #pragma unroll
                for (int kk = 0; kk < 2; ++kk)
                    af[d][kk] = *(const short8*)&As[buf][(wm * 128 + (2 * p + d) * 16 + lr) * 64 + kk * 32 + lk8];
            #pragma unroll
            for (int d = 0; d < 2; ++d)
                #pragma unroll
                for (int ni = 0; ni < 4; ++ni)
                    #pragma unroll
                    for (int kk = 0; kk < 2; ++kk)
                        acc[2 * p + d][ni] =
                            __builtin_amdgcn_mfma_f32_16x16x32_bf16(af[d][kk], bf2[ni][kk], acc[2 * p + d][ni], 0, 0, 0);
        }
    };

    STAGE(0, 0);
    STAGE(1, 64);
    #pragma unroll
    for (int tp = 0; tp < 4; ++tp) {
        VMCNT8();
        SBAR();
        COMPUTE(0);
        SBAR();
        if (tp < 3) {
            STAGE(0, (2 * tp + 2) * 64);
            VMCNT8();
        } else {
            VMCNT0();
        }
        SBAR();
        COMPUTE(1);
        SBAR();
        if (tp < 3) STAGE(1, (2 * tp + 3) * 64);
    }

    const int g = l >> 4, cc = l & 15;
    const int colbase = n0 + wn * 64;
    if (bx < 6) {
        const int reg  = colbase >> 9;
        const int head = (colbase >> 6) & 7;
        unsigned short* dst = (reg == 0) ? qn : (reg == 1) ? kn : vn;
        #pragma unroll
        for (int mi = 0; mi < 8; ++mi) {
            #pragma unroll
            for (int j = 0; j < 4; ++j) {
                int row = m0 + wm * 128 + mi * 16 + g * 4 + j;
                int s = row >> 5, b = row & 31;
                size_t base = ((size_t)(b * H_ + head) * SLEN + s) * 64;
                float e0 = acc[mi][0][j], e1 = acc[mi][1][j], e2 = acc[mi][2][j], e3 = acc[mi][3][j];
                if (reg < 2) {
                    e0 = e0 > 0.f ? e0 + 1.f : __expf(e0);
                    e1 = e1 > 0.f ? e1 + 1.f : __expf(e1);
                    e2 = e2 > 0.f ? e2 + 1.f : __expf(e2);
                    e3 = e3 > 0.f ? e3 + 1.f : __expf(e3);
                    float ssum = (e0 + e1) + (e2 + e3);
                    ssum += __shfl_xor(ssum, 1);
                    ssum += __shfl_xor(ssum, 2);
                    ssum += __shfl_xor(ssum, 4);
                    ssum += __shfl_xor(ssum, 8);
                    float inv = 1.f / ssum;
                    e0 *= inv; e1 *= inv; e2 *= inv; e3 *= inv;
                }
                dst[base +  0 + cc] = f2bf(e0);
                dst[base + 16 + cc] = f2bf(e1);
                dst[base + 32 + cc] = f2bf(e2);
                dst[base + 48 + cc] = f2bf(e3);
            }
        }
    } else {
        if (wn == 0 && cc < 8) {
            #pragma unroll
            for (int mi = 0; mi < 8; ++mi)
                #pragma unroll
                for (int j = 0; j < 4; ++j) {
                    int row = m0 + wm * 128 + mi * 16 + g * 4 + j;
                    int s = row >> 5, b = row & 31;
                    float v = acc[mi][0][j];
                    bet[(size_t)(b * H_ + cc) * SLEN + s] = 1.f / (1.f + __expf(-v));
                }
        }
    }
}

// ---------------- GEMM2, 256x256 tile, counted-vmcnt pipeline: out = x + outs @ woT^T ----------------
__global__ __launch_bounds__(512, 2) void gemm_out(const unsigned short* __restrict__ A,
                                                   const unsigned short* __restrict__ BT,
                                                   const float* __restrict__ X,
                                                   float* __restrict__ outf) {
    __shared__ unsigned short As[2][256 * 64];
    __shared__ unsigned short Bs[2][256 * 64];
    const int tid = threadIdx.x;
    const int id = blockIdx.y * 2 + blockIdx.x;       // 256 = 8*32
    const int newid = (id & 7) * 32 + (id >> 3);      // bijective XCD chunking
    const int n0 = (newid & 1) * 256;
    const int m0 = (newid >> 1) * 256;
    const int w = tid >> 6, l = tid & 63;
    const int wm = w >> 2, wn = w & 3;
    const int lr = l & 15, lk8 = (l >> 4) * 8;
    f32x4 acc[8][4] = {};

    auto STAGE = [&](int buf, int kt) {
        #pragma unroll
        for (int c2 = 0; c2 < 4; ++c2) {
            int idx = c2 * 512 + tid;
            int row = idx >> 3, kc2 = (idx & 7) * 8;
            int lb = (c2 * 512 + (tid & 448)) * 8;
            GLOAD16(A  + (size_t)(m0 + row) * INDIM + kt + kc2, &As[buf][lb]);
            GLOAD16(BT + (size_t)(n0 + row) * INDIM + kt + kc2, &Bs[buf][lb]);
        }
    };
    auto COMPUTE = [&](int buf) {
        short8 bf2[4][2];
        #pragma unroll
        for (int ni = 0; ni < 4; ++ni)
            #pragma unroll
            for (int kk = 0; kk < 2; ++kk)
                bf2[ni][kk] = *(const short8*)&Bs[buf][(wn * 64 + ni * 16 + lr) * 64 + kk * 32 + lk8];
        #pragma unroll
        for (int p = 0; p < 4; ++p) {
            short8 af[2][2];
            #pragma unroll
            for (int d = 0; d < 2; ++d)
                #pragma unroll
                for (int kk = 0; kk < 2; ++kk)
                    af[d][kk] = *(const short8*)&As[buf][(wm * 128 + (2 * p + d) * 16 + lr) * 64 + kk * 32 + lk8];
            #pragma unroll
            for (int d = 0; d < 2; ++d)
                #pragma unroll
                for (int ni = 0; ni < 4; ++ni)
                    #pragma unroll
                    for (int kk = 0; kk < 2; ++kk)
                        acc[2 * p + d][ni] =
                            __builtin_amdgcn_mfma_f32_16x16x32_bf16(af[d][kk], bf2[ni][kk], acc[2 * p + d][ni], 0, 0, 0);
        }
    };

    STAGE(0, 0);
    STAGE(1, 64);
    #pragma unroll
    for (int tp = 0; tp < 4; ++tp) {
        VMCNT8();
        SBAR();
        COMPUTE(0);
        SBAR();
        if (tp < 3) {
            STAGE(0, (2 * tp + 2) * 64);
            VMCNT8();
        } else {
            VMCNT0();
        }
        SBAR();
        COMPUTE(1);
        SBAR();
        if (tp < 3) STAGE(1, (2 * tp + 3) * 64);
    }

    const int g = l >> 4, cc = l & 15;
    #pragma unroll
    for (int mi = 0; mi < 8; ++mi)
        #pragma unroll
        for (int ni = 0; ni < 4; ++ni)
            #pragma unroll
            for (int j = 0; j < 4; ++j) {
                int row = m0 + wm * 128 + mi * 16 + g * 4 + j;
                int col = n0 + wn * 64 + ni * 16 + cc;
                size_t o = (size_t)row * 512 + col;
                outf[o] = X[o] + acc[mi][ni][j];
            }
}

// ---------------- phase 1 v3: per-(bh,chunk) WY tile factors, 8 waves, conflict-fixed ----------------
__global__ __launch_bounds__(512, 4) void fwtiles(const unsigned short* __restrict__ qn,
                                                  const unsigned short* __restrict__ kn,
                                                  const unsigned short* __restrict__ vn,
                                                  const float* __restrict__ beta,
                                                  unsigned short* __restrict__ tiles,
                                                  unsigned short* __restrict__ outs) {
    __shared__ unsigned short Ax[64 * PB], Atr[64 * PB], Pw[64 * PB], Pwtr[64 * PB];
    __shared__ unsigned short Z0[128 * PB], Z1[128 * PB];
    __shared__ float bv[64];
    const int bx = blockIdx.x;
    const int bh = bx >> 4, c = bx & 15;
    const int b = bh >> 3, h = bh & 7;
    const int c0 = c * 64;
    const int tid = threadIdx.x;
    const int w = tid >> 6, l = tid & 63;
    const int mw = w & 3, nh = w >> 2;
    const int lr = l & 15, lk = (l >> 4) << 3, rb = (l >> 4) << 2;
    const unsigned short* kc = kn + ((size_t)bh * SLEN + c0) * 64;
    const unsigned short* qc = qn + ((size_t)bh * SLEN + c0) * 64;
    const unsigned short* vc = vn + ((size_t)bh * SLEN + c0) * 64;
    const float* bb = beta + (size_t)bh * SLEN + c0;

    {
        #pragma unroll
        for (int i = 0; i < 2; ++i) {
            int idx = i * 512 + tid;
            int row = idx >> 3, seg = idx & 7;
            const unsigned short* src = (row < 64) ? (vc + (size_t)row * 64 + seg * 8)
                                                   : (kc + (size_t)(row - 64) * 64 + seg * 8);
            *(ushort8*)&Z1[row * PB + seg * 8] = *(const ushort8*)src;
        }
        if (tid < 64) bv[tid] = bb[tid];
        ushort8 z8 = {};
        for (int i = tid; i < 576; i += 512) { ((ushort8*)Ax)[i] = z8; ((ushort8*)Atr)[i] = z8; }
    }
    __syncthreads();

    auto ldb = [&](const unsigned short* M, int m, int kk) -> short8 {
        return *(const short8*)&M[(m * 16 + lr) * PB + kk * 32 + lk];
    };

    {
        const int zoff2 = (w >> 2) * 64;
        const int tbase = (w & 3) * 16;
        const float sgn = (w >= 4) ? -1.f : 1.f;
        ushort8 b0v, b1v;
        #pragma unroll
        for (int i = 0; i < 16; ++i) {
            int r = w * 16 + i;
            float val = sgn * bv[tbase + i] * bf2f(Z1[r * PB + l]);
            unsigned short uv = f2bf(val);
            if (i < 8) b0v[i] = uv; else b1v[i - 8] = uv;
        }
        *(ushort8*)&Z0[(zoff2 + l) * PB + tbase]     = b0v;
        *(ushort8*)&Z0[(zoff2 + l) * PB + tbase + 8] = b1v;
    }
    {
        const int pm[10] = {0, 1, 1, 2, 2, 2, 3, 3, 3, 3};
        const int pn[10] = {0, 0, 1, 0, 1, 2, 0, 1, 2, 3};
        for (int pi = w; pi < 10; pi += 8) {
            int m = pm[pi], n = pn[pi];
            short8 ka0 = *(const short8*)&Z1[(64 + 16 * m + lr) * PB + lk];
            short8 ka1 = *(const short8*)&Z1[(64 + 16 * m + lr) * PB + 32 + lk];
            short8 kb0 = *(const short8*)&Z1[(64 + 16 * n + lr) * PB + lk];
            short8 kb1 = *(const short8*)&Z1[(64 + 16 * n + lr) * PB + 32 + lk];
            f32x4 a = {};
            a = __builtin_amdgcn_mfma_f32_16x16x32_bf16(ka0, kb0, a, 0, 0, 0);
            a = __builtin_amdgcn_mfma_f32_16x16x32_bf16(ka1, kb1, a, 0, 0, 0);
            f32x4 btm = *(const f32x4*)&bv[16 * m + rb];
            short4v pk;
            #pragma unroll
            for (int j = 0; j < 4; ++j) {
                int tt = 16 * m + rb + j, s = 16 * n + lr;
                unsigned short v = (s < tt) ? f2bf(-btm[j] * a[j]) : (unsigned short)0;
                Ax[tt * PB + s] = v;
                pk[j] = (short)v;
            }
            *(short4v*)&Atr[(16 * n + lr) * PB + 16 * m + rb] = pk;
        }
    }
    __syncthreads();

    auto zprod = [&](const unsigned short* Xb, int p, const unsigned short* Zs, unsigned short* Zd) {
        const bool msk0 = (16 * mw + 15 >= p), msk1 = (16 * mw + 15 - 32 >= p);
        short8 xf0, xf1;
        if (msk0) xf0 = ldb(Xb, mw, 0);
        if (msk1) xf1 = ldb(Xb, mw, 1);
        #pragma unroll
        for (int ni = 0; ni < 4; ++ni) {
            int n = nh * 4 + ni;
            short4v zi = *(const short4v*)&Zs[(16 * n + lr) * PB + 16 * mw + rb];
            f32x4 a;
            #pragma unroll
            for (int j = 0; j < 4; ++j) a[j] = bf2f((unsigned short)zi[j]);
            if (msk0) a = __builtin_amdgcn_mfma_f32_16x16x32_bf16(xf0, ldb(Zs, n, 0), a, 0, 0, 0);
            if (msk1) a = __builtin_amdgcn_mfma_f32_16x16x32_bf16(xf1, ldb(Zs, n, 1), a, 0, 0, 0);
            short4v zo;
            #pragma unroll
            for (int j = 0; j < 4; ++j) zo[j] = (short)f2bf(a[j]);
            *(short4v*)&Zd[(16 * n + lr) * PB + 16 * mw + rb] = zo;
        }
    };
    auto powp = [&](const unsigned short* Ps, const unsigned short* Pstr, int p,
                    unsigned short* Pd, unsigned short* Pdtr, bool wrTr) {
        const bool x0 = (16 * mw + 15 >= p), x1 = (16 * mw + 15 - 32 >= p);
        short8 xf0, xf1;
        if (x0) xf0 = ldb(Ps, mw, 0);
        if (x1) xf1 = ldb(Ps, mw, 1);
        #pragma unroll
        for (int ni = 0; ni < 2; ++ni) {
            int n = nh * 2 + ni;
            const bool y0 = (31 - 16 * n >= p), y1 = (63 - 16 * n >= p);
            f32x4 a = {};
            if (x0 && y0) a = __builtin_amdgcn_mfma_f32_16x16x32_bf16(xf0, ldb(Pstr, n, 0), a, 0, 0, 0);
            if (x1 && y1) a = __builtin_amdgcn_mfma_f32_16x16x32_bf16(xf1, ldb(Pstr, n, 1), a, 0, 0, 0);
            short4v pk;
            #pragma unroll
            for (int j = 0; j < 4; ++j) {
                unsigned short v = f2bf(a[j]);
                Pd[(16 * mw + rb + j) * PB + 16 * n + lr] = v;
                pk[j] = (short)v;
            }
            if (wrTr) *(short4v*)&Pdtr[(16 * n + lr) * PB + 16 * mw + rb] = pk;
        }
    };

    zprod(Ax, 1, Z0, Z1);  powp(Ax, Atr, 1, Pw, Pwtr, true);   __syncthreads();
    zprod(Pw, 2, Z1, Z0);  powp(Pw, Pwtr, 2, Ax, Atr, true);   __syncthreads();
    zprod(Ax, 4, Z0, Z1);  powp(Ax, Atr, 4, Pw, Pwtr, true);   __syncthreads();
    zprod(Pw, 8, Z1, Z0);  powp(Pw, Pwtr, 8, Ax, Atr, true);   __syncthreads();
    zprod(Ax, 16, Z0, Z1); powp(Ax, Atr, 16, Pw, Pwtr, false); __syncthreads();
    zprod(Pw, 32, Z1, Z0);
    __syncthreads();

    {
        #pragma unroll
        for (int i = 0; i < 2; ++i) {
            int idx = i * 512 + tid;
            int row = idx >> 3, seg = idx & 7;
            const unsigned short* src = (row < 64) ? (qc + (size_t)row * 64 + seg * 8)
                                                   : (kc + (size_t)(row - 64) * 64 + seg * 8);
            *(ushort8*)&Z1[row * PB + seg * 8] = *(const ushort8*)src;
        }
    }
    __syncthreads();

    {
        short8 qa0 = *(const short8*)&Z1[(16 * mw + lr) * PB + lk];
        short8 qa1 = *(const short8*)&Z1[(16 * mw + lr) * PB + 32 + lk];
        #pragma unroll
        for (int ni = 0; ni < 2; ++ni) {
            int n = nh * 2 + ni;
            short8 kb0 = *(const short8*)&Z1[(64 + 16 * n + lr) * PB + lk];
            short8 kb1 = *(const short8*)&Z1[(64 + 16 * n + lr) * PB + 32 + lk];
            f32x4 a = {};
            a = __builtin_amdgcn_mfma_f32_16x16x32_bf16(qa0, kb0, a, 0, 0, 0);
            a = __builtin_amdgcn_mfma_f32_16x16x32_bf16(qa1, kb1, a, 0, 0, 0);
            #pragma unroll
            for (int j = 0; j < 4; ++j) {
                int tt = 16 * mw + rb + j, s = 16 * n + lr;
                Ax[tt * PB + s] = (s <= tt) ? f2bf(a[j]) : (unsigned short)0;
            }
        }
        ushort8 kv;
        #pragma unroll
        for (int j = 0; j < 8; ++j)
            kv[j] = Z1[(64 + w * 8 + j) * PB + l];
        *(ushort8*)&Pwtr[l * PB + w * 8] = kv;
    }
    __syncthreads();

    {
        unsigned short* tb = tiles + ((size_t)bh * 16 + c) * 12288;
        short8 pA0 = ldb(Ax, mw, 0), pA1 = ldb(Ax, mw, 1);
        short8 zA0 = ldb(Z0, mw, 0), zA1 = ldb(Z0, mw, 1);
        short8 kt0 = ldb(Pwtr, mw, 0), kt1 = ldb(Pwtr, mw, 1);
        #pragma unroll
        for (int ni = 0; ni < 2; ++ni) {
            int n = nh * 2 + ni;
            f32x4 aN = {};
            aN = __builtin_amdgcn_mfma_f32_16x16x32_bf16(zA0, ldb(Pwtr, n, 0), aN, 0, 0, 0);
            aN = __builtin_amdgcn_mfma_f32_16x16x32_bf16(zA1, ldb(Pwtr, n, 1), aN, 0, 0, 0);
            f32x4 aM = {};
            aM = __builtin_amdgcn_mfma_f32_16x16x32_bf16(kt0, ldb(Z0, 4 + n, 0), aM, 0, 0, 0);
            aM = __builtin_amdgcn_mfma_f32_16x16x32_bf16(kt1, ldb(Z0, 4 + n, 1), aM, 0, 0, 0);
            f32x4 aG;
            #pragma unroll
            for (int j = 0; j < 4; ++j) aG[j] = bf2f(Z1[(16 * mw + rb + j) * PB + 16 * n + lr]);
            aG = __builtin_amdgcn_mfma_f32_16x16x32_bf16(pA0, ldb(Z0, 4 + n, 0), aG, 0, 0, 0);
            aG = __builtin_amdgcn_mfma_f32_16x16x32_bf16(pA1, ldb(Z0, 4 + n, 1), aG, 0, 0, 0);
            f32x4 aP = {};
            aP = __builtin_amdgcn_mfma_f32_16x16x32_bf16(pA0, ldb(Z0, n, 0), aP, 0, 0, 0);
            aP = __builtin_amdgcn_mfma_f32_16x16x32_bf16(pA1, ldb(Z0, n, 1), aP, 0, 0, 0);
            #pragma unroll
            for (int j = 0; j < 4; ++j) {
                int r = 16 * mw + rb + j, cl = 16 * n + lr;
                tb[r * 64 + cl]        = f2bf(aM[j]);
                tb[4096 + r * 64 + cl] = f2bf(aG[j]);
                tb[8192 + r * 64 + cl] = f2bf(aN[j]);
                outs[((size_t)(c0 + r) * BSZ + b) * 512 + h * 64 + cl] = f2bf(aP[j]);
            }
        }
    }
}

// ---------------- phase 2a: W-only scan with register prefetch; stores bf16 W checkpoints ----------------
__global__ __launch_bounds__(256) void fwscan_w(const unsigned short* __restrict__ tiles,
                                                unsigned short* __restrict__ wchk) {
    __shared__ float Wf[64 * 68];
    const int bh = blockIdx.x;
    const int tid = threadIdx.x;
    const int w = tid >> 6, l = tid & 63;
    const int lr = l & 15, lk = (l >> 4) << 3, rb = (l >> 4) << 2;
    const int cr = l >> 3, cc8 = (l & 7) * 8;
    #pragma unroll
    for (int j = 0; j < 16; ++j) Wf[(16 * w + j) * 68 + l] = 0.f;

    const unsigned short* tb0 = tiles + (size_t)bh * 16 * 12288;
    unsigned short* wc0 = wchk + (size_t)bh * 16 * 4096;

    auto loadc = [&](short8 (&MT)[4][2], unsigned short (&NV)[4][4], int c) {
        const unsigned short* tb = tb0 + (size_t)c * 12288;
        #pragma unroll
        for (int n = 0; n < 4; ++n) {
            MT[n][0] = *(const short8*)(tb + (size_t)(16 * n + lr) * 64 + lk);
            MT[n][1] = *(const short8*)(tb + (size_t)(16 * n + lr) * 64 + 32 + lk);
            #pragma unroll
            for (int j = 0; j < 4; ++j)
                NV[n][j] = tb[8192 + (size_t)(16 * w + rb + j) * 64 + 16 * n + lr];
        }
    };
    auto stepc = [&](short8 (&MT)[4][2], unsigned short (&NV)[4][4], int c) {
        #pragma unroll
        for (int half = 0; half < 2; ++half) {
            int row = 16 * w + half * 8 + cr;
            const float* p = &Wf[row * 68 + cc8];
            f32x4 x0 = *(const f32x4*)p, x1 = *(const f32x4*)(p + 4);
            ushort8 o;
            #pragma unroll
            for (int j = 0; j < 4; ++j) { o[j] = f2bf(x0[j]); o[4 + j] = f2bf(x1[j]); }
            *(ushort8*)(wc0 + (size_t)c * 4096 + row * 64 + cc8) = o;
        }
        short8 wf0, wf1;
        {
            const float* p0 = &Wf[(16 * w + lr) * 68 + lk];
            f32x4 a0 = *(const f32x4*)p0, b0 = *(const f32x4*)(p0 + 4);
            f32x4 a1 = *(const f32x4*)(p0 + 32), b1 = *(const f32x4*)(p0 + 36);
            #pragma unroll
            for (int j = 0; j < 4; ++j) {
                wf0[j] = (short)f2bf(a0[j]); wf0[4 + j] = (short)f2bf(b0[j]);
                wf1[j] = (short)f2bf(a1[j]); wf1[4 + j] = (short)f2bf(b1[j]);
            }
        }
        #pragma unroll
        for (int n = 0; n < 4; ++n) {
            f32x4 a;
            #pragma unroll
            for (int j = 0; j < 4; ++j)
                a[j] = Wf[(16 * w + rb + j) * 68 + 16 * n + lr] + bf2f(NV[n][j]);
            a = __builtin_amdgcn_mfma_f32_16x16x32_bf16(wf0, MT[n][0], a, 0, 0, 0);
            a = __builtin_amdgcn_mfma_f32_16x16x32_bf16(wf1, MT[n][1], a, 0, 0, 0);
            #pragma unroll
            for (int j = 0; j < 4; ++j) Wf[(16 * w + rb + j) * 68 + 16 * n + lr] = a[j];
        }
    };

    short8 mtA[4][2], mtB[4][2];
    unsigned short nvA[4][4], nvB[4][4];
    loadc(mtA, nvA, 0);
    #pragma unroll 1
    for (int cc = 0; cc < 8; ++cc) {
        int c = 2 * cc;
        if (c + 1 < 16) loadc(mtB, nvB, c + 1);
        stepc(mtA, nvA, c);
        if (c + 2 < 16) loadc(mtA, nvA, c + 2);
        stepc(mtB, nvB, c + 1);
    }
}

// ---------------- phase 2b: O finalize, parallel over (chunk 1..15, bh) ----------------
__global__ __launch_bounds__(256) void fw_o(const unsigned short* __restrict__ tiles,
                                            const unsigned short* __restrict__ wchk,
                                            unsigned short* __restrict__ outs) {
    __shared__ unsigned short Ot[64 * 72];
    const int c = blockIdx.x + 1;
    const int bh = blockIdx.y;
    const int b = bh >> 3, h = bh & 7;
    const int c0 = c * 64;
    const int tid = threadIdx.x;
    const int w = tid >> 6, l = tid & 63;
    const int lr = l & 15, lk = (l >> 4) << 3, rb = (l >> 4) << 2;
    const unsigned short* G  = tiles + ((size_t)bh * 16 + c) * 12288 + 4096;
    const unsigned short* W0 = wchk + ((size_t)bh * 16 + c) * 4096;

    #pragma unroll
    for (int i = 0; i < 2; ++i) {
        int idx = i * 256 + tid;
        int t = idx >> 3, d0 = (idx & 7) * 8;
        *(ushort8*)&Ot[t * 72 + d0] =
            *(const ushort8*)(outs + ((size_t)(c0 + t) * BSZ + b) * 512 + h * 64 + d0);
    }
    __syncthreads();

    short8 g0 = *(const short8*)(G + (size_t)(16 * w + lr) * 64 + lk);
    short8 g1 = *(const short8*)(G + (size_t)(16 * w + lr) * 64 + 32 + lk);
    #pragma unroll
    for (int n = 0; n < 4; ++n) {
        short8 wf0 = *(const short8*)(W0 + (size_t)(16 * n + lr) * 64 + lk);
        short8 wf1 = *(const short8*)(W0 + (size_t)(16 * n + lr) * 64 + 32 + lk);
        f32x4 a;
        #pragma unroll
        for (int j = 0; j < 4; ++j) a[j] = bf2f(Ot[(16 * w + rb + j) * 72 + 16 * n + lr]);
        a = __builtin_amdgcn_mfma_f32_16x16x32_bf16(g0, wf0, a, 0, 0, 0);
        a = __builtin_amdgcn_mfma_f32_16x16x32_bf16(g1, wf1, a, 0, 0, 0);
        #pragma unroll
        for (int j = 0; j < 4; ++j) Ot[(16 * w + rb + j) * 72 + 16 * n + lr] = f2bf(a[j]);
    }
    __syncthreads();

    #pragma unroll
    for (int i = 0; i < 2; ++i) {
        int idx = i * 256 + tid;
        int t = idx >> 3, d0 = (idx & 7) * 8;
        *(ushort8*)(outs + ((size_t)(c0 + t) * BSZ + b) * 512 + h * 64 + d0) =
            *(const ushort8*)&Ot[t * 72 + d0];
    }
}

// ---------------- launch ----------------
extern "C" void kernel_launch(void* const* d_in, const int* in_sizes, int n_in,
                              void* d_out, int out_size, void* d_ws, size_t ws_size,
                              hipStream_t stream) {
    const float* x      = (const float*)d_in[0];
    const float* g      = (const float*)d_in[1];
    const float* be     = (const float*)d_in[2];
    const float* w_slow = (const float*)d_in[3];
    const float* w_out  = (const float*)d_in[4];
    float* out = (float*)d_out;
    char* ws = (char*)d_ws;

    unsigned short* h    = (unsigned short*)(ws);
    unsigned short* outs = (unsigned short*)(ws);                 // alias h
    unsigned short* qn   = (unsigned short*)(ws + 33554432);
    unsigned short* wchk = (unsigned short*)(ws + 33554432);      // alias qn (dead after fwtiles)
    unsigned short* kn   = (unsigned short*)(ws + 67108864);
    unsigned short* vn   = (unsigned short*)(ws + 100663296);
    float*          bet  = (float*)         (ws + 134217728);
    unsigned short* wsT  = (unsigned short*)(ws + 135266304);     // 1792*512*2
    unsigned short* woT  = (unsigned short*)(ws + 137101312);
    unsigned short* tiles= (unsigned short*)(ws + 137625600);

    if (ws_size < 238288896) return;

    ln_kernel<<<8192, 256, 0, stream>>>(x, g, be, h);
    cvt_wslow<<<(NPAD2 * 512) / 256, 256, 0, stream>>>(w_slow, wsT);
    cvt_wout<<<(512 * 512) / 256, 256, 0, stream>>>(w_out, woT);
    gemm_qkv<<<dim3(7, MROWS / 256), 512, 0, stream>>>(h, wsT, qn, kn, vn, bet);
    fwtiles<<<BSZ * H_ * 16, 512, 0, stream>>>(qn, kn, vn, bet, tiles, outs);
    fwscan_w<<<BSZ * H_, 256, 0, stream>>>(tiles, wchk);
    fw_o<<<dim3(15, BSZ * H_), 256, 0, stream>>>(tiles, wchk, outs);
    gemm_out<<<dim3(2, MROWS / 256), 512, 0, stream>>>(outs, woT, x, out);
}